// Round 1
// baseline (2195.993 us; speedup 1.0000x reference)
//
#include <hip/hip_runtime.h>

#define HEADS 8
#define DHEAD 64
#define QSCALE 0.125f   // 64^-0.5
#define DIM 256
#define IMG 112
#define HW 12544        // 112*112
#define OS 16
#define NKV 256         // 16*16
#define INNER 512
#define KCONV 12544     // 256*49

// ---------------- K0: im2col gather (7x7 stride-7 VALID => non-overlapping reshape)
// P[b][k][pos], k = c*49 + kh*7 + kw, pos = oy*16 + ox
__global__ __launch_bounds__(256) void k0_gather(const float* __restrict__ x,
                                                 float* __restrict__ P) {
    int gid = blockIdx.x * 256 + threadIdx.x;  // float4 index
    int bk = gid >> 6;                         // b*KCONV + k
    int p4 = (gid & 63) << 2;
    int b = bk / KCONV;
    int k = bk - b * KCONV;
    int c = k / 49;
    int tap = k - c * 49;
    int kh = tap / 7;
    int kw = tap - kh * 7;
    const float* xs = x + ((b * DIM + c) * IMG) * IMG;
    float4 v;
    {
        int pos = p4 + 0; int oy = pos >> 4, ox = pos & 15;
        v.x = xs[(oy * 7 + kh) * IMG + ox * 7 + kw];
        pos = p4 + 1; oy = pos >> 4; ox = pos & 15;
        v.y = xs[(oy * 7 + kh) * IMG + ox * 7 + kw];
        pos = p4 + 2; oy = pos >> 4; ox = pos & 15;
        v.z = xs[(oy * 7 + kh) * IMG + ox * 7 + kw];
        pos = p4 + 3; oy = pos >> 4; ox = pos & 15;
        v.w = xs[(oy * 7 + kh) * IMG + ox * 7 + kw];
    }
    *(float4*)&P[bk * NKV + p4] = v;
}

// ---------------- K1: Q projection, writes q TRANSPOSED: qtokT[bh][d][n], scaled
__global__ __launch_bounds__(256) void k1_qproj(const float* __restrict__ x,
                                                const float* __restrict__ Wq,
                                                float* __restrict__ qtokT) {
    __shared__ float aT[64 * 68];  // [kk][oc], stride 68
    __shared__ float bv[64 * 64];  // [kk][n]
    int t = threadIdx.x;
    int n0 = blockIdx.x * 64;
    int h = blockIdx.y;
    int b = blockIdx.z;
    int to = t & 15, tn = t >> 4;  // to: 16 oc-groups, tn: 16 n-groups
    float acc[4][4] = {};
    const float* Arow = Wq + h * 64 * DIM;
    const float* Bbase = x + (b * DIM) * HW + n0;
    for (int k0 = 0; k0 < DIM; k0 += 64) {
        #pragma unroll
        for (int i = 0; i < 4; ++i) {
            int f4 = t + i * 256;
            int r = f4 >> 4, kvv = (f4 & 15) << 2;
            float4 a = *(const float4*)&Arow[r * DIM + k0 + kvv];
            aT[(kvv + 0) * 68 + r] = a.x;
            aT[(kvv + 1) * 68 + r] = a.y;
            aT[(kvv + 2) * 68 + r] = a.z;
            aT[(kvv + 3) * 68 + r] = a.w;
        }
        #pragma unroll
        for (int i = 0; i < 4; ++i) {
            int f4 = t + i * 256;
            int kk = f4 >> 4, nv = (f4 & 15) << 2;
            *(float4*)&bv[kk * 64 + nv] = *(const float4*)&Bbase[(k0 + kk) * HW + nv];
        }
        __syncthreads();
        #pragma unroll 8
        for (int kk = 0; kk < 64; ++kk) {
            float4 a4 = *(const float4*)&aT[kk * 68 + 4 * to];
            float4 b4 = *(const float4*)&bv[kk * 64 + 4 * tn];
            acc[0][0] += a4.x * b4.x; acc[0][1] += a4.x * b4.y; acc[0][2] += a4.x * b4.z; acc[0][3] += a4.x * b4.w;
            acc[1][0] += a4.y * b4.x; acc[1][1] += a4.y * b4.y; acc[1][2] += a4.y * b4.z; acc[1][3] += a4.y * b4.w;
            acc[2][0] += a4.z * b4.x; acc[2][1] += a4.z * b4.y; acc[2][2] += a4.z * b4.z; acc[2][3] += a4.z * b4.w;
            acc[3][0] += a4.w * b4.x; acc[3][1] += a4.w * b4.y; acc[3][2] += a4.w * b4.z; acc[3][3] += a4.w * b4.w;
        }
        __syncthreads();
    }
    // qtokT[(b*8+h)*64 + d][n0 + 4tn + j], d = 4to+i, fold in QSCALE
    float* outp = qtokT + ((b * HEADS + h) * DHEAD) * HW + n0 + 4 * tn;
    #pragma unroll
    for (int i = 0; i < 4; ++i) {
        float4 w = make_float4(acc[i][0] * QSCALE, acc[i][1] * QSCALE,
                               acc[i][2] * QSCALE, acc[i][3] * QSCALE);
        *(float4*)&outp[(4 * to + i) * HW] = w;
    }
}

// ---------------- K2: KV conv as GEMM over patches. K tokens transposed, V natural.
__global__ __launch_bounds__(256) void k2_kv(const float* __restrict__ Wkv,
                                             const float* __restrict__ P,
                                             float* __restrict__ ktokT,
                                             float* __restrict__ vtok) {
    __shared__ float aT[64 * 68];
    __shared__ float bv[64 * 64];
    int t = threadIdx.x;
    int n0 = blockIdx.x * 64;   // pos tile (0..3)
    int octile = blockIdx.y;    // 0..15
    int b = blockIdx.z;
    int to = t & 15, tn = t >> 4;
    float acc[4][4] = {};
    const float* Arow = Wkv + octile * 64 * KCONV;
    const float* Bbase = P + b * KCONV * NKV + n0;
    for (int k0 = 0; k0 < KCONV; k0 += 64) {
        #pragma unroll
        for (int i = 0; i < 4; ++i) {
            int f4 = t + i * 256;
            int r = f4 >> 4, kvv = (f4 & 15) << 2;
            float4 a = *(const float4*)&Arow[r * KCONV + k0 + kvv];
            aT[(kvv + 0) * 68 + r] = a.x;
            aT[(kvv + 1) * 68 + r] = a.y;
            aT[(kvv + 2) * 68 + r] = a.z;
            aT[(kvv + 3) * 68 + r] = a.w;
        }
        #pragma unroll
        for (int i = 0; i < 4; ++i) {
            int f4 = t + i * 256;
            int kk = f4 >> 4, nv = (f4 & 15) << 2;
            *(float4*)&bv[kk * 64 + nv] = *(const float4*)&Bbase[(k0 + kk) * NKV + nv];
        }
        __syncthreads();
        #pragma unroll 8
        for (int kk = 0; kk < 64; ++kk) {
            float4 a4 = *(const float4*)&aT[kk * 68 + 4 * to];
            float4 b4 = *(const float4*)&bv[kk * 64 + 4 * tn];
            acc[0][0] += a4.x * b4.x; acc[0][1] += a4.x * b4.y; acc[0][2] += a4.x * b4.z; acc[0][3] += a4.x * b4.w;
            acc[1][0] += a4.y * b4.x; acc[1][1] += a4.y * b4.y; acc[1][2] += a4.y * b4.z; acc[1][3] += a4.y * b4.w;
            acc[2][0] += a4.z * b4.x; acc[2][1] += a4.z * b4.y; acc[2][2] += a4.z * b4.z; acc[2][3] += a4.z * b4.w;
            acc[3][0] += a4.w * b4.x; acc[3][1] += a4.w * b4.y; acc[3][2] += a4.w * b4.z; acc[3][3] += a4.w * b4.w;
        }
        __syncthreads();
    }
    if (octile < 8) {
        // K tokens, transposed: ktokT[(b*8+h)*64 + d][pos]
        float* outp = ktokT + ((b * HEADS + octile) * DHEAD) * NKV + n0 + 4 * tn;
        #pragma unroll
        for (int i = 0; i < 4; ++i) {
            *(float4*)&outp[(4 * to + i) * NKV] =
                make_float4(acc[i][0], acc[i][1], acc[i][2], acc[i][3]);
        }
    } else {
        // V tokens, natural: vtok[(b*8+h)*256 + pos][d]
        float* outp = vtok + ((b * HEADS + (octile - 8)) * NKV + n0) * DHEAD;
        #pragma unroll
        for (int j = 0; j < 4; ++j) {
            *(float4*)&outp[(4 * tn + j) * DHEAD + 4 * to] =
                make_float4(acc[0][j], acc[1][j], acc[2][j], acc[3][j]);
        }
    }
}

// ---------------- K3: fused attention. One block = 32 queries of one (b,h).
// LDS: kT[64][260] (reused for V[256][64]) + qT[64][36] + S[32][260]
__global__ __launch_bounds__(256) void k3_attn(const float* __restrict__ qtokT,
                                               const float* __restrict__ ktokT,
                                               const float* __restrict__ vtok,
                                               float* __restrict__ otok) {
    extern __shared__ float smem[];
    float* kvb = smem;               // 64*260 = 16640 floats (>= 256*64 for V reuse)
    float* qT = smem + 64 * 260;     // 64*36 = 2304
    float* S = qT + 64 * 36;         // 32*260 = 8320
    int t = threadIdx.x;
    int q0 = blockIdx.x * 32;
    int bh = blockIdx.y;

    const float* kt = ktokT + bh * DHEAD * NKV;
    #pragma unroll
    for (int i = 0; i < 16; ++i) {
        int f4 = t + i * 256;
        int d = f4 >> 6, kx = (f4 & 63) << 2;
        *(float4*)&kvb[d * 260 + kx] = *(const float4*)&kt[d * NKV + kx];
    }
    const float* qt = qtokT + bh * DHEAD * HW + q0;
    #pragma unroll
    for (int i = 0; i < 2; ++i) {
        int f4 = t + i * 256;
        int d = f4 >> 3, qv = (f4 & 7) << 2;
        *(float4*)&qT[d * 36 + qv] = *(const float4*)&qt[d * HW + qv];
    }
    __syncthreads();

    // dots: thread (tq = t>>4, tk = t&15), rows {2tq, 2tq+1}, keys 64v + 4tk + u
    int tq = t >> 4, tk = t & 15;
    float accd[2][16];
    #pragma unroll
    for (int i = 0; i < 2; ++i)
        #pragma unroll
        for (int j = 0; j < 16; ++j) accd[i][j] = 0.0f;

    #pragma unroll 2
    for (int d = 0; d < 64; ++d) {
        float2 q2 = *(const float2*)&qT[d * 36 + 2 * tq];
        #pragma unroll
        for (int v = 0; v < 4; ++v) {
            float4 k4 = *(const float4*)&kvb[d * 260 + v * 64 + 4 * tk];
            int vv = 4 * v;
            accd[0][vv + 0] += q2.x * k4.x; accd[0][vv + 1] += q2.x * k4.y;
            accd[0][vv + 2] += q2.x * k4.z; accd[0][vv + 3] += q2.x * k4.w;
            accd[1][vv + 0] += q2.y * k4.x; accd[1][vv + 1] += q2.y * k4.y;
            accd[1][vv + 2] += q2.y * k4.z; accd[1][vv + 3] += q2.y * k4.w;
        }
    }

    // softmax per row (16 lanes per row-group; xor masks stay inside the group)
    #pragma unroll
    for (int i = 0; i < 2; ++i) {
        float m = accd[i][0];
        #pragma unroll
        for (int j = 1; j < 16; ++j) m = fmaxf(m, accd[i][j]);
        m = fmaxf(m, __shfl_xor(m, 1));
        m = fmaxf(m, __shfl_xor(m, 2));
        m = fmaxf(m, __shfl_xor(m, 4));
        m = fmaxf(m, __shfl_xor(m, 8));
        float s = 0.0f;
        #pragma unroll
        for (int j = 0; j < 16; ++j) {
            accd[i][j] = __expf(accd[i][j] - m);
            s += accd[i][j];
        }
        s += __shfl_xor(s, 1);
        s += __shfl_xor(s, 2);
        s += __shfl_xor(s, 4);
        s += __shfl_xor(s, 8);
        float inv = 1.0f / s;
        int r = 2 * tq + i;
        #pragma unroll
        for (int v = 0; v < 4; ++v) {
            *(float4*)&S[r * 260 + v * 64 + 4 * tk] =
                make_float4(accd[i][4 * v + 0] * inv, accd[i][4 * v + 1] * inv,
                            accd[i][4 * v + 2] * inv, accd[i][4 * v + 3] * inv);
        }
    }
    __syncthreads();   // all dots reads of kvb done; S fully written

    // stage V into kvb (natural [k][64] layout, identical to vtok)
    const float* vt = vtok + bh * NKV * DHEAD;
    #pragma unroll
    for (int i = 0; i < 16; ++i) {
        int f4 = t + i * 256;
        *(float4*)&kvb[f4 << 2] = *(const float4*)&vt[f4 << 2];
    }
    __syncthreads();

    // PV: thread (tq rows, td = t&15 -> dv = 4td..4td+3)
    int td = t & 15;
    float acco[2][4] = {};
    #pragma unroll 4
    for (int kq = 0; kq < 64; ++kq) {
        int k0 = kq * 4;
        float4 s0 = *(const float4*)&S[(2 * tq) * 260 + k0];
        float4 s1 = *(const float4*)&S[(2 * tq + 1) * 260 + k0];
        float4 v0 = *(const float4*)&kvb[(k0 + 0) * 64 + 4 * td];
        float4 v1 = *(const float4*)&kvb[(k0 + 1) * 64 + 4 * td];
        float4 v2 = *(const float4*)&kvb[(k0 + 2) * 64 + 4 * td];
        float4 v3 = *(const float4*)&kvb[(k0 + 3) * 64 + 4 * td];
        acco[0][0] += s0.x * v0.x + s0.y * v1.x + s0.z * v2.x + s0.w * v3.x;
        acco[0][1] += s0.x * v0.y + s0.y * v1.y + s0.z * v2.y + s0.w * v3.y;
        acco[0][2] += s0.x * v0.z + s0.y * v1.z + s0.z * v2.z + s0.w * v3.z;
        acco[0][3] += s0.x * v0.w + s0.y * v1.w + s0.z * v2.w + s0.w * v3.w;
        acco[1][0] += s1.x * v0.x + s1.y * v1.x + s1.z * v2.x + s1.w * v3.x;
        acco[1][1] += s1.x * v0.y + s1.y * v1.y + s1.z * v2.y + s1.w * v3.y;
        acco[1][2] += s1.x * v0.z + s1.y * v1.z + s1.z * v2.z + s1.w * v3.z;
        acco[1][3] += s1.x * v0.w + s1.y * v1.w + s1.z * v2.w + s1.w * v3.w;
    }
    float* ot = otok + (bh * HW + q0) * DHEAD;
    #pragma unroll
    for (int i = 0; i < 2; ++i) {
        int r = 2 * tq + i;
        *(float4*)&ot[r * DHEAD + 4 * td] =
            make_float4(acco[i][0], acco[i][1], acco[i][2], acco[i][3]);
    }
}

// ---------------- K4: output projection + bias
__global__ __launch_bounds__(256) void k4_outproj(const float* __restrict__ Wout,
                                                  const float* __restrict__ otok,
                                                  const float* __restrict__ bout,
                                                  float* __restrict__ outp) {
    __shared__ float aT[64 * 68];   // [kk][oc]
    __shared__ float bvt[64 * 68];  // [dv][n] transposed staging
    int t = threadIdx.x;
    int n0 = blockIdx.x * 64;
    int octile = blockIdx.y;  // 0..3
    int b = blockIdx.z;
    int to = t & 15, tn = t >> 4;
    float acc[4][4] = {};
    const float* Arow = Wout + octile * 64 * INNER;
    for (int h = 0; h < 8; ++h) {
        #pragma unroll
        for (int i = 0; i < 4; ++i) {
            int f4 = t + i * 256;
            int r = f4 >> 4, kvv = (f4 & 15) << 2;
            float4 a = *(const float4*)&Arow[r * INNER + h * 64 + kvv];
            aT[(kvv + 0) * 68 + r] = a.x;
            aT[(kvv + 1) * 68 + r] = a.y;
            aT[(kvv + 2) * 68 + r] = a.z;
            aT[(kvv + 3) * 68 + r] = a.w;
        }
        #pragma unroll
        for (int i = 0; i < 4; ++i) {
            int f4 = t + i * 256;
            int nn = f4 >> 4, dvv = (f4 & 15) << 2;
            float4 v = *(const float4*)&otok[((b * HEADS + h) * HW + n0 + nn) * DHEAD + dvv];
            bvt[(dvv + 0) * 68 + nn] = v.x;
            bvt[(dvv + 1) * 68 + nn] = v.y;
            bvt[(dvv + 2) * 68 + nn] = v.z;
            bvt[(dvv + 3) * 68 + nn] = v.w;
        }
        __syncthreads();
        #pragma unroll 8
        for (int kk = 0; kk < 64; ++kk) {
            float4 a4 = *(const float4*)&aT[kk * 68 + 4 * to];
            float4 b4 = *(const float4*)&bvt[kk * 68 + 4 * tn];
            acc[0][0] += a4.x * b4.x; acc[0][1] += a4.x * b4.y; acc[0][2] += a4.x * b4.z; acc[0][3] += a4.x * b4.w;
            acc[1][0] += a4.y * b4.x; acc[1][1] += a4.y * b4.y; acc[1][2] += a4.y * b4.z; acc[1][3] += a4.y * b4.w;
            acc[2][0] += a4.z * b4.x; acc[2][1] += a4.z * b4.y; acc[2][2] += a4.z * b4.z; acc[2][3] += a4.z * b4.w;
            acc[3][0] += a4.w * b4.x; acc[3][1] += a4.w * b4.y; acc[3][2] += a4.w * b4.z; acc[3][3] += a4.w * b4.w;
        }
        __syncthreads();
    }
    int oc0 = octile * 64;
    #pragma unroll
    for (int i = 0; i < 4; ++i) {
        int oc = oc0 + 4 * to + i;
        float bb = bout[oc];
        *(float4*)&outp[(b * DIM + oc) * HW + n0 + 4 * tn] =
            make_float4(acc[i][0] + bb, acc[i][1] + bb, acc[i][2] + bb, acc[i][3] + bb);
    }
}

extern "C" void kernel_launch(void* const* d_in, const int* in_sizes, int n_in,
                              void* d_out, int out_size, void* d_ws, size_t ws_size,
                              hipStream_t stream) {
    (void)in_sizes; (void)n_in; (void)out_size; (void)ws_size;
    const float* x = (const float*)d_in[0];
    const float* Wq = (const float*)d_in[1];
    const float* Wkv = (const float*)d_in[2];
    const float* Wout = (const float*)d_in[3];
    const float* bout = (const float*)d_in[4];
    float* outp = (float*)d_out;

    float* ws = (float*)d_ws;
    float* qtokT = ws;                       // 32*64*12544      = 25,690,112 floats
    float* ktokT = qtokT + 25690112;         // 32*64*256        = 524,288
    float* vtok = ktokT + 524288;            // 32*256*64        = 524,288
    float* regD = vtok + 524288;             // 25,690,112 floats: P (K0..K2) then otok (K3..K4)
    float* P = regD;
    float* otok = regD;

    hipFuncSetAttribute((const void*)k3_attn,
                        hipFuncAttributeMaxDynamicSharedMemorySize, 109056);

    k0_gather<<<dim3(12544), 256, 0, stream>>>(x, P);
    k1_qproj<<<dim3(196, 8, 4), 256, 0, stream>>>(x, Wq, qtokT);
    k2_kv<<<dim3(4, 16, 4), 256, 0, stream>>>(Wkv, P, ktokT, vtok);
    k3_attn<<<dim3(392, 32), 256, 109056, stream>>>(qtokT, ktokT, vtok, otok);
    k4_outproj<<<dim3(196, 4, 4), 256, 0, stream>>>(Wout, otok, bout, outp);
}

// Round 2
// 1973.986 us; speedup vs baseline: 1.1125x; 1.1125x over previous
//
#include <hip/hip_runtime.h>

#define HEADS 8
#define DHEAD 64
#define QSCALE 0.125f   // 64^-0.5
#define DIM 256
#define IMG 112
#define HW 12544        // 112*112
#define OS 16
#define NKV 256         // 16*16
#define INNER 512
#define KCONV 12544     // 256*49
#define KSPLIT 7
#define KCHUNK 1792     // 12544/7

// ---------------- K0: im2col gather (7x7 stride-7 VALID => non-overlapping reshape)
// P[b][k][pos], k = c*49 + kh*7 + kw, pos = oy*16 + ox
__global__ __launch_bounds__(256) void k0_gather(const float* __restrict__ x,
                                                 float* __restrict__ P) {
    int gid = blockIdx.x * 256 + threadIdx.x;  // float4 index
    int bk = gid >> 6;                         // b*KCONV + k
    int p4 = (gid & 63) << 2;
    int b = bk / KCONV;
    int k = bk - b * KCONV;
    int c = k / 49;
    int tap = k - c * 49;
    int kh = tap / 7;
    int kw = tap - kh * 7;
    const float* xs = x + ((b * DIM + c) * IMG) * IMG;
    float4 v;
    {
        int pos = p4 + 0; int oy = pos >> 4, ox = pos & 15;
        v.x = xs[(oy * 7 + kh) * IMG + ox * 7 + kw];
        pos = p4 + 1; oy = pos >> 4; ox = pos & 15;
        v.y = xs[(oy * 7 + kh) * IMG + ox * 7 + kw];
        pos = p4 + 2; oy = pos >> 4; ox = pos & 15;
        v.z = xs[(oy * 7 + kh) * IMG + ox * 7 + kw];
        pos = p4 + 3; oy = pos >> 4; ox = pos & 15;
        v.w = xs[(oy * 7 + kh) * IMG + ox * 7 + kw];
    }
    *(float4*)&P[(size_t)bk * NKV + p4] = v;
}

// ---------------- K2t: transpose Wkv [1024][12544] -> WkvT [12544][1024] (run once)
__global__ __launch_bounds__(256) void k2t(const float* __restrict__ Wkv,
                                           float* __restrict__ WkvT) {
    __shared__ float tile[64 * 68];
    int t = threadIdx.x;
    int kb = blockIdx.x * 64;   // k block (196)
    int ob = blockIdx.y * 64;   // oc block (16)
    #pragma unroll
    for (int i = 0; i < 4; ++i) {
        int f4 = t + i * 256;
        int r = f4 >> 4, c4 = (f4 & 15) << 2;
        float4 v = *(const float4*)&Wkv[(size_t)(ob + r) * KCONV + kb + c4];
        tile[(c4 + 0) * 68 + r] = v.x;
        tile[(c4 + 1) * 68 + r] = v.y;
        tile[(c4 + 2) * 68 + r] = v.z;
        tile[(c4 + 3) * 68 + r] = v.w;
    }
    __syncthreads();
    #pragma unroll
    for (int i = 0; i < 4; ++i) {
        int f4 = t + i * 256;
        int rr = f4 >> 4, cc4 = (f4 & 15) << 2;
        *(float4*)&WkvT[(size_t)(kb + rr) * 1024 + ob + cc4] =
            *(const float4*)&tile[rr * 68 + cc4];
    }
}

// ---------------- K1: Q projection, writes q TRANSPOSED: qtokT[bh][d][n], scaled
__global__ __launch_bounds__(256) void k1_qproj(const float* __restrict__ x,
                                                const float* __restrict__ Wq,
                                                float* __restrict__ qtokT) {
    __shared__ float aT[64 * 68];  // [kk][oc], stride 68
    __shared__ float bv[64 * 64];  // [kk][n]
    int t = threadIdx.x;
    int n0 = blockIdx.x * 64;
    int h = blockIdx.y;
    int b = blockIdx.z;
    int to = t & 15, tn = t >> 4;
    float acc[4][4] = {};
    const float* Arow = Wq + h * 64 * DIM;
    const float* Bbase = x + (size_t)(b * DIM) * HW + n0;
    for (int k0 = 0; k0 < DIM; k0 += 64) {
        #pragma unroll
        for (int i = 0; i < 4; ++i) {
            int f4 = t + i * 256;
            int r = f4 >> 4, kvv = (f4 & 15) << 2;
            float4 a = *(const float4*)&Arow[r * DIM + k0 + kvv];
            aT[(kvv + 0) * 68 + r] = a.x;
            aT[(kvv + 1) * 68 + r] = a.y;
            aT[(kvv + 2) * 68 + r] = a.z;
            aT[(kvv + 3) * 68 + r] = a.w;
        }
        #pragma unroll
        for (int i = 0; i < 4; ++i) {
            int f4 = t + i * 256;
            int kk = f4 >> 4, nv = (f4 & 15) << 2;
            *(float4*)&bv[kk * 64 + nv] = *(const float4*)&Bbase[(size_t)(k0 + kk) * HW + nv];
        }
        __syncthreads();
        #pragma unroll 8
        for (int kk = 0; kk < 64; ++kk) {
            float4 a4 = *(const float4*)&aT[kk * 68 + 4 * to];
            float4 b4 = *(const float4*)&bv[kk * 64 + 4 * tn];
            acc[0][0] += a4.x * b4.x; acc[0][1] += a4.x * b4.y; acc[0][2] += a4.x * b4.z; acc[0][3] += a4.x * b4.w;
            acc[1][0] += a4.y * b4.x; acc[1][1] += a4.y * b4.y; acc[1][2] += a4.y * b4.z; acc[1][3] += a4.y * b4.w;
            acc[2][0] += a4.z * b4.x; acc[2][1] += a4.z * b4.y; acc[2][2] += a4.z * b4.z; acc[2][3] += a4.z * b4.w;
            acc[3][0] += a4.w * b4.x; acc[3][1] += a4.w * b4.y; acc[3][2] += a4.w * b4.z; acc[3][3] += a4.w * b4.w;
        }
        __syncthreads();
    }
    float* outp = qtokT + ((size_t)(b * HEADS + h) * DHEAD) * HW + n0 + 4 * tn;
    #pragma unroll
    for (int i = 0; i < 4; ++i) {
        float4 w = make_float4(acc[i][0] * QSCALE, acc[i][1] * QSCALE,
                               acc[i][2] * QSCALE, acc[i][3] * QSCALE);
        *(float4*)&outp[(size_t)(4 * to + i) * HW] = w;
    }
}

// ---------------- K2: KV conv GEMM, split-K, no LDS. A from WkvT, B from P (both L1/L2-hot).
__global__ __launch_bounds__(256) void k2_kv(const float* __restrict__ WkvT,
                                             const float* __restrict__ P,
                                             float* __restrict__ partial) {
    int t = threadIdx.x;
    int to = t & 15, tn = t >> 4;
    int n0 = blockIdx.x * 64;
    int octile = blockIdx.y;
    int ks = blockIdx.z % KSPLIT;
    int b = blockIdx.z / KSPLIT;
    const float* Ab = WkvT + (size_t)(ks * KCHUNK) * 1024 + octile * 64 + 4 * to;
    const float* Bb = P + ((size_t)b * KCONV + ks * KCHUNK) * NKV + n0 + 4 * tn;
    float acc[4][4] = {};
    #pragma unroll 4
    for (int k = 0; k < KCHUNK; ++k) {
        float4 a4 = *(const float4*)&Ab[(size_t)k * 1024];
        float4 b4 = *(const float4*)&Bb[(size_t)k * NKV];
        acc[0][0] += a4.x * b4.x; acc[0][1] += a4.x * b4.y; acc[0][2] += a4.x * b4.z; acc[0][3] += a4.x * b4.w;
        acc[1][0] += a4.y * b4.x; acc[1][1] += a4.y * b4.y; acc[1][2] += a4.y * b4.z; acc[1][3] += a4.y * b4.w;
        acc[2][0] += a4.z * b4.x; acc[2][1] += a4.z * b4.y; acc[2][2] += a4.z * b4.z; acc[2][3] += a4.z * b4.w;
        acc[3][0] += a4.w * b4.x; acc[3][1] += a4.w * b4.y; acc[3][2] += a4.w * b4.z; acc[3][3] += a4.w * b4.w;
    }
    float* outp = partial + ((size_t)(ks * 4 + b) * 1024 + octile * 64) * 256 + n0 + 4 * tn;
    #pragma unroll
    for (int i = 0; i < 4; ++i) {
        *(float4*)&outp[(4 * to + i) * 256] =
            make_float4(acc[i][0], acc[i][1], acc[i][2], acc[i][3]);
    }
}

// ---------------- K2r: reduce split-K partials -> ktokT (transposed) + vtok (natural)
__global__ __launch_bounds__(256) void k2r(const float* __restrict__ partial,
                                           float* __restrict__ ktokT,
                                           float* __restrict__ vtok) {
    int t = threadIdx.x;
    int oc = blockIdx.x * 4 + (t >> 6);
    int b = blockIdx.y;
    int pos = (t & 63) * 4;
    const float* src = partial + ((size_t)b * 1024 + oc) * 256 + pos;
    float4 s = *(const float4*)src;
    #pragma unroll
    for (int ks = 1; ks < KSPLIT; ++ks) {
        float4 v = *(const float4*)(src + (size_t)ks * 1024 * 1024);
        s.x += v.x; s.y += v.y; s.z += v.z; s.w += v.w;
    }
    int h = (oc >> 6) & 7;
    int d = oc & 63;
    if (oc < 512) {
        *(float4*)&ktokT[((size_t)(b * HEADS + h) * DHEAD + d) * NKV + pos] = s;
    } else {
        float* vp = &vtok[((size_t)(b * HEADS + h) * NKV + pos) * DHEAD + d];
        vp[0] = s.x; vp[64] = s.y; vp[128] = s.z; vp[192] = s.w;
    }
}

// ---------------- K3: fused attention. One block = 32 queries of one (b,h).
// Only S in LDS (33 KB -> 4 blocks/CU). q, K, V read direct from global (L2-resident).
__global__ __launch_bounds__(256) void k3_attn(const float* __restrict__ qtokT,
                                               const float* __restrict__ ktokT,
                                               const float* __restrict__ vtok,
                                               float* __restrict__ otok) {
    __shared__ float S[32 * 260];
    int t = threadIdx.x;
    int q0 = blockIdx.x * 32;
    int bh = blockIdx.y;
    int tq = t >> 4, tk = t & 15;

    const float* qp = qtokT + (size_t)bh * DHEAD * HW + q0 + 2 * tq;
    const float* kt = ktokT + (size_t)bh * DHEAD * NKV + 4 * tk;

    float accd[2][16];
    #pragma unroll
    for (int i = 0; i < 2; ++i)
        #pragma unroll
        for (int j = 0; j < 16; ++j) accd[i][j] = 0.0f;

    #pragma unroll 4
    for (int d = 0; d < 64; ++d) {
        float2 q2 = *(const float2*)&qp[(size_t)d * HW];
        #pragma unroll
        for (int v = 0; v < 4; ++v) {
            float4 k4 = *(const float4*)&kt[d * NKV + v * 64];
            int vv = 4 * v;
            accd[0][vv + 0] += q2.x * k4.x; accd[0][vv + 1] += q2.x * k4.y;
            accd[0][vv + 2] += q2.x * k4.z; accd[0][vv + 3] += q2.x * k4.w;
            accd[1][vv + 0] += q2.y * k4.x; accd[1][vv + 1] += q2.y * k4.y;
            accd[1][vv + 2] += q2.y * k4.z; accd[1][vv + 3] += q2.y * k4.w;
        }
    }

    // softmax per row (16 lanes per row-group; xor masks stay inside the group)
    #pragma unroll
    for (int i = 0; i < 2; ++i) {
        float m = accd[i][0];
        #pragma unroll
        for (int j = 1; j < 16; ++j) m = fmaxf(m, accd[i][j]);
        m = fmaxf(m, __shfl_xor(m, 1));
        m = fmaxf(m, __shfl_xor(m, 2));
        m = fmaxf(m, __shfl_xor(m, 4));
        m = fmaxf(m, __shfl_xor(m, 8));
        float s = 0.0f;
        #pragma unroll
        for (int j = 0; j < 16; ++j) {
            accd[i][j] = __expf(accd[i][j] - m);
            s += accd[i][j];
        }
        s += __shfl_xor(s, 1);
        s += __shfl_xor(s, 2);
        s += __shfl_xor(s, 4);
        s += __shfl_xor(s, 8);
        float inv = 1.0f / s;
        int r = 2 * tq + i;
        #pragma unroll
        for (int v = 0; v < 4; ++v) {
            *(float4*)&S[r * 260 + v * 64 + 4 * tk] =
                make_float4(accd[i][4 * v + 0] * inv, accd[i][4 * v + 1] * inv,
                            accd[i][4 * v + 2] * inv, accd[i][4 * v + 3] * inv);
        }
    }
    __syncthreads();

    // PV: V direct from global; thread (tq rows, td = t&15 -> dv = 4td..4td+3)
    int td = t & 15;
    const float* vt = vtok + (size_t)bh * NKV * DHEAD + 4 * td;
    float acco[2][4] = {};
    #pragma unroll 2
    for (int kq = 0; kq < 64; ++kq) {
        int k0 = kq * 4;
        float4 s0 = *(const float4*)&S[(2 * tq) * 260 + k0];
        float4 s1 = *(const float4*)&S[(2 * tq + 1) * 260 + k0];
        float4 v0 = *(const float4*)&vt[(k0 + 0) * 64];
        float4 v1 = *(const float4*)&vt[(k0 + 1) * 64];
        float4 v2 = *(const float4*)&vt[(k0 + 2) * 64];
        float4 v3 = *(const float4*)&vt[(k0 + 3) * 64];
        acco[0][0] += s0.x * v0.x + s0.y * v1.x + s0.z * v2.x + s0.w * v3.x;
        acco[0][1] += s0.x * v0.y + s0.y * v1.y + s0.z * v2.y + s0.w * v3.y;
        acco[0][2] += s0.x * v0.z + s0.y * v1.z + s0.z * v2.z + s0.w * v3.z;
        acco[0][3] += s0.x * v0.w + s0.y * v1.w + s0.z * v2.w + s0.w * v3.w;
        acco[1][0] += s1.x * v0.x + s1.y * v1.x + s1.z * v2.x + s1.w * v3.x;
        acco[1][1] += s1.x * v0.y + s1.y * v1.y + s1.z * v2.y + s1.w * v3.y;
        acco[1][2] += s1.x * v0.z + s1.y * v1.z + s1.z * v2.z + s1.w * v3.z;
        acco[1][3] += s1.x * v0.w + s1.y * v1.w + s1.z * v2.w + s1.w * v3.w;
    }
    float* ot = otok + ((size_t)bh * HW + q0) * DHEAD;
    #pragma unroll
    for (int i = 0; i < 2; ++i) {
        int r = 2 * tq + i;
        *(float4*)&ot[r * DHEAD + 4 * td] =
            make_float4(acco[i][0], acco[i][1], acco[i][2], acco[i][3]);
    }
}

// ---------------- K4: output projection + bias
__global__ __launch_bounds__(256) void k4_outproj(const float* __restrict__ Wout,
                                                  const float* __restrict__ otok,
                                                  const float* __restrict__ bout,
                                                  float* __restrict__ outp) {
    __shared__ float aT[64 * 68];   // [kk][oc]
    __shared__ float bvt[64 * 68];  // [dv][n] transposed staging
    int t = threadIdx.x;
    int n0 = blockIdx.x * 64;
    int octile = blockIdx.y;  // 0..3
    int b = blockIdx.z;
    int to = t & 15, tn = t >> 4;
    float acc[4][4] = {};
    const float* Arow = Wout + octile * 64 * INNER;
    for (int h = 0; h < 8; ++h) {
        #pragma unroll
        for (int i = 0; i < 4; ++i) {
            int f4 = t + i * 256;
            int r = f4 >> 4, kvv = (f4 & 15) << 2;
            float4 a = *(const float4*)&Arow[r * INNER + h * 64 + kvv];
            aT[(kvv + 0) * 68 + r] = a.x;
            aT[(kvv + 1) * 68 + r] = a.y;
            aT[(kvv + 2) * 68 + r] = a.z;
            aT[(kvv + 3) * 68 + r] = a.w;
        }
        #pragma unroll
        for (int i = 0; i < 4; ++i) {
            int f4 = t + i * 256;
            int nn = f4 >> 4, dvv = (f4 & 15) << 2;
            float4 v = *(const float4*)&otok[((size_t)(b * HEADS + h) * HW + n0 + nn) * DHEAD + dvv];
            bvt[(dvv + 0) * 68 + nn] = v.x;
            bvt[(dvv + 1) * 68 + nn] = v.y;
            bvt[(dvv + 2) * 68 + nn] = v.z;
            bvt[(dvv + 3) * 68 + nn] = v.w;
        }
        __syncthreads();
        #pragma unroll 8
        for (int kk = 0; kk < 64; ++kk) {
            float4 a4 = *(const float4*)&aT[kk * 68 + 4 * to];
            float4 b4 = *(const float4*)&bvt[kk * 68 + 4 * tn];
            acc[0][0] += a4.x * b4.x; acc[0][1] += a4.x * b4.y; acc[0][2] += a4.x * b4.z; acc[0][3] += a4.x * b4.w;
            acc[1][0] += a4.y * b4.x; acc[1][1] += a4.y * b4.y; acc[1][2] += a4.y * b4.z; acc[1][3] += a4.y * b4.w;
            acc[2][0] += a4.z * b4.x; acc[2][1] += a4.z * b4.y; acc[2][2] += a4.z * b4.z; acc[2][3] += a4.z * b4.w;
            acc[3][0] += a4.w * b4.x; acc[3][1] += a4.w * b4.y; acc[3][2] += a4.w * b4.z; acc[3][3] += a4.w * b4.w;
        }
        __syncthreads();
    }
    int oc0 = octile * 64;
    #pragma unroll
    for (int i = 0; i < 4; ++i) {
        int oc = oc0 + 4 * to + i;
        float bb = bout[oc];
        *(float4*)&outp[(size_t)(b * DIM + oc) * HW + n0 + 4 * tn] =
            make_float4(acc[i][0] + bb, acc[i][1] + bb, acc[i][2] + bb, acc[i][3] + bb);
    }
}

extern "C" void kernel_launch(void* const* d_in, const int* in_sizes, int n_in,
                              void* d_out, int out_size, void* d_ws, size_t ws_size,
                              hipStream_t stream) {
    (void)in_sizes; (void)n_in; (void)out_size; (void)ws_size;
    const float* x = (const float*)d_in[0];
    const float* Wq = (const float*)d_in[1];
    const float* Wkv = (const float*)d_in[2];
    const float* Wout = (const float*)d_in[3];
    const float* bout = (const float*)d_in[4];
    float* outp = (float*)d_out;

    // Workspace (floats), total 52,428,800 = 209.7 MB (same as round 1):
    //   region A [0 .. 25,690,112): partial (7.34M) + WkvT (12.85M) during k2*;
    //                               then qtokT (25.69M) from k1 onward.
    //   ktokT  at 25,690,112 (0.52M)
    //   vtok   at 26,214,400 (0.52M)
    //   region B [26,738,688 .. 52,428,800): P during k0..k2; otok from k3 onward.
    float* ws = (float*)d_ws;
    float* partial = ws;                          // 7,340,032
    float* WkvT = ws + 7340032;                   // 12,845,056
    float* qtokT = ws;                            // 25,690,112 (after k2r)
    float* ktokT = ws + 25690112;                 // 524,288
    float* vtok = ws + 26214400;                  // 524,288
    float* P = ws + 26738688;                     // 25,690,112
    float* otok = P;                              // reuse after k2

    k0_gather<<<dim3(12544), 256, 0, stream>>>(x, P);
    k2t<<<dim3(196, 16), 256, 0, stream>>>(Wkv, WkvT);
    k2_kv<<<dim3(4, 16, 28), 256, 0, stream>>>(WkvT, P, partial);
    k2r<<<dim3(256, 4), 256, 0, stream>>>(partial, ktokT, vtok);
    k1_qproj<<<dim3(196, 8, 4), 256, 0, stream>>>(x, Wq, qtokT);
    k3_attn<<<dim3(392, 32), 256, 0, stream>>>(qtokT, ktokT, vtok, otok);
    k4_outproj<<<dim3(196, 4, 4), 256, 0, stream>>>(Wout, otok, bout, outp);
}

// Round 4
// 870.842 us; speedup vs baseline: 2.5217x; 2.2668x over previous
//
#include <hip/hip_runtime.h>

#define HEADS 8
#define DHEAD 64
#define QSCALE 0.125f   // 64^-0.5
#define DIM 256
#define IMG 112
#define HW 12544        // 112*112
#define NKV 256         // 16*16
#define INNER 512
#define KCONV 12544     // 256*49
#define KSPLIT 7
#define KCHUNK 1792     // 12544/7

typedef _Float16 half_t;
typedef _Float16 half8 __attribute__((ext_vector_type(8)));
typedef float f32x4 __attribute__((ext_vector_type(4)));

__device__ inline unsigned pk2(float a, float b) {
    union { half_t h[2]; unsigned u; } x;
    x.h[0] = (half_t)a; x.h[1] = (half_t)b;
    return x.u;
}

// ---------------- K0: im2col gather -> TRANSPOSED f16 patches Pt[b][pos][k]
__global__ __launch_bounds__(256) void k0_gather(const float* __restrict__ x,
                                                 half_t* __restrict__ Pt) {
    int gid = blockIdx.x * 256 + threadIdx.x;  // one 8-k chunk
    int bp = gid / 1568;                       // 1568 = 12544/8
    int k8 = gid - bp * 1568;
    int b = bp >> 8, pos = bp & 255;
    int oy = pos >> 4, ox = pos & 15;
    const float* xb = x + (size_t)b * DIM * HW + (size_t)(oy * 7) * IMG + ox * 7;
    int k0 = k8 * 8;
    half8 hv;
    #pragma unroll
    for (int j = 0; j < 8; ++j) {
        int k = k0 + j;
        int cch = k / 49;
        int tap = k - cch * 49;
        int kh = tap / 7;
        int kw = tap - kh * 7;
        hv[j] = (half_t)xb[(size_t)cch * HW + kh * IMG + kw];
    }
    *(half8*)&Pt[(size_t)bp * KCONV + k0] = hv;
}

// ---------------- Kcvt: Wkv f32 -> f16 (same [oc][k] layout)
__global__ __launch_bounds__(256) void k_cvt(const float* __restrict__ W,
                                             half_t* __restrict__ W16) {
    size_t i = ((size_t)blockIdx.x * 256 + threadIdx.x) * 8;
    float4 a = *(const float4*)&W[i];
    float4 b = *(const float4*)&W[i + 4];
    half8 h = { (half_t)a.x, (half_t)a.y, (half_t)a.z, (half_t)a.w,
                (half_t)b.x, (half_t)b.y, (half_t)b.z, (half_t)b.w };
    *(half8*)&W16[i] = h;
}

// ---------------- K1: Q projection (fp32 compute), writes qtok f16 [bh][n][d], scaled
__global__ __launch_bounds__(256) void k1_qproj(const float* __restrict__ x,
                                                const float* __restrict__ Wq,
                                                half_t* __restrict__ qtok) {
    __shared__ float aT[64 * 68];  // [kk][oc]
    __shared__ float bv[64 * 64];  // [kk][n]
    int t = threadIdx.x;
    int n0 = blockIdx.x * 64;
    int h = blockIdx.y;
    int b = blockIdx.z;
    int to = t & 15, tn = t >> 4;
    float acc[4][4] = {};
    const float* Arow = Wq + h * 64 * DIM;
    const float* Bbase = x + (size_t)(b * DIM) * HW + n0;
    for (int k0 = 0; k0 < DIM; k0 += 64) {
        #pragma unroll
        for (int i = 0; i < 4; ++i) {
            int f4 = t + i * 256;
            int r = f4 >> 4, kvv = (f4 & 15) << 2;
            float4 a = *(const float4*)&Arow[r * DIM + k0 + kvv];
            aT[(kvv + 0) * 68 + r] = a.x;
            aT[(kvv + 1) * 68 + r] = a.y;
            aT[(kvv + 2) * 68 + r] = a.z;
            aT[(kvv + 3) * 68 + r] = a.w;
        }
        #pragma unroll
        for (int i = 0; i < 4; ++i) {
            int f4 = t + i * 256;
            int kk = f4 >> 4, nv = (f4 & 15) << 2;
            *(float4*)&bv[kk * 64 + nv] = *(const float4*)&Bbase[(size_t)(k0 + kk) * HW + nv];
        }
        __syncthreads();
        #pragma unroll 8
        for (int kk = 0; kk < 64; ++kk) {
            float4 a4 = *(const float4*)&aT[kk * 68 + 4 * to];
            float4 b4 = *(const float4*)&bv[kk * 64 + 4 * tn];
            acc[0][0] += a4.x * b4.x; acc[0][1] += a4.x * b4.y; acc[0][2] += a4.x * b4.z; acc[0][3] += a4.x * b4.w;
            acc[1][0] += a4.y * b4.x; acc[1][1] += a4.y * b4.y; acc[1][2] += a4.y * b4.z; acc[1][3] += a4.y * b4.w;
            acc[2][0] += a4.z * b4.x; acc[2][1] += a4.z * b4.y; acc[2][2] += a4.z * b4.z; acc[2][3] += a4.z * b4.w;
            acc[3][0] += a4.w * b4.x; acc[3][1] += a4.w * b4.y; acc[3][2] += a4.w * b4.z; acc[3][3] += a4.w * b4.w;
        }
        __syncthreads();
    }
    // write [n][d] f16: row n = n0+4tn+j, cols 4to..4to+3 packed (8B per row)
    half_t* outp = qtok + ((size_t)(b * HEADS + h) * HW + n0 + 4 * tn) * 64 + 4 * to;
    #pragma unroll
    for (int j = 0; j < 4; ++j) {
        unsigned lo = pk2(acc[0][j] * QSCALE, acc[1][j] * QSCALE);
        unsigned hi = pk2(acc[2][j] * QSCALE, acc[3][j] * QSCALE);
        uint2 u = make_uint2(lo, hi);
        *(uint2*)&outp[(size_t)j * 64] = u;
    }
}

// ---------------- K2: KV conv GEMM via f16 MFMA, split-K=7, fp32 partials
__global__ __launch_bounds__(256) void k2_kv(const half_t* __restrict__ W16,
                                             const half_t* __restrict__ Pt,
                                             float* __restrict__ partial) {
    int t = threadIdx.x;
    int w = t >> 6, l = t & 63, g = l >> 4, c = l & 15;
    int octile = blockIdx.x;   // 0..15 (64 oc each)
    int ks = blockIdx.y;       // 0..6
    int b = blockIdx.z;
    const half_t* Ap = W16 + (size_t)(octile * 64 + w * 16 + c) * KCONV + ks * KCHUNK + g * 8;
    const half_t* Bp = Pt + ((size_t)b * 256 + c) * KCONV + ks * KCHUNK + g * 8;
    f32x4 sc[16];
    #pragma unroll
    for (int nt = 0; nt < 16; ++nt) sc[nt] = (f32x4){0.f, 0.f, 0.f, 0.f};
    for (int kk = 0; kk < KCHUNK / 32; ++kk) {
        half8 a = *(const half8*)(Ap + kk * 32);
        #pragma unroll
        for (int nt = 0; nt < 16; ++nt) {
            half8 bb = *(const half8*)(Bp + (size_t)nt * 16 * KCONV + kk * 32);
            sc[nt] = __builtin_amdgcn_mfma_f32_16x16x32_f16(a, bb, sc[nt], 0, 0, 0);
        }
    }
    float* op = partial + ((size_t)(ks * 4 + b) * 1024 + octile * 64 + w * 16) * 256;
    #pragma unroll
    for (int nt = 0; nt < 16; ++nt)
        #pragma unroll
        for (int r = 0; r < 4; ++r)
            op[(g * 4 + r) * 256 + nt * 16 + c] = sc[nt][r];
}

// ---------------- K2r: reduce partials -> ktok f16 [bh][kv][d], vtokT f16 [bh][d][kv]
// partial slice index is (ks*4 + b): per-ks stride = 4*1024*256 = 1,048,576 floats.
__global__ __launch_bounds__(256) void k2r(const float* __restrict__ partial,
                                           half_t* __restrict__ ktok,
                                           half_t* __restrict__ vtokT) {
    int pos = threadIdx.x;
    int oc0 = blockIdx.x * 8;
    int b = blockIdx.y;
    float v[8];
    #pragma unroll
    for (int j = 0; j < 8; ++j) {
        const float* src = partial + ((size_t)b * 1024 + oc0 + j) * 256 + pos;
        float s = 0.f;
        #pragma unroll
        for (int ksb = 0; ksb < KSPLIT; ++ksb) s += src[(size_t)ksb * 1048576];
        v[j] = s;
    }
    int h = (oc0 >> 6) & 7, d0 = oc0 & 63;
    if (oc0 < 512) {
        uint4 u = make_uint4(pk2(v[0], v[1]), pk2(v[2], v[3]),
                             pk2(v[4], v[5]), pk2(v[6], v[7]));
        *(uint4*)&ktok[((size_t)(b * HEADS + h) * NKV + pos) * 64 + d0] = u;
    } else {
        #pragma unroll
        for (int j = 0; j < 8; ++j)
            vtokT[((size_t)(b * HEADS + h) * 64 + d0 + j) * NKV + pos] = (half_t)v[j];
    }
}

// ---------------- K3: fused attention, f16 MFMA. Block = 64 q rows, wave = 16 q rows.
__global__ __launch_bounds__(256) void k3_attn(const half_t* __restrict__ qtok,
                                               const half_t* __restrict__ ktok,
                                               const half_t* __restrict__ vtokT,
                                               float* __restrict__ otok) {
    __shared__ unsigned S_lds[64 * 128];   // 64 rows x 256 f16 (swizzled), 32 KB
    int t = threadIdx.x;
    int w = t >> 6, l = t & 63, g = l >> 4, c = l & 15;
    int q0 = blockIdx.x * 64;
    int bh = blockIdx.y;

    // Q A-frags: A[m=c][k=d], d-contiguous in qtok[n][d]
    const half_t* qp = qtok + ((size_t)bh * HW + q0 + w * 16 + c) * 64 + g * 8;
    half8 aq0 = *(const half8*)(qp);
    half8 aq1 = *(const half8*)(qp + 32);

    // dots: 16 n-tiles over kv, K B-frags from ktok[kv][d]
    const half_t* kt = ktok + (size_t)bh * NKV * 64 + (size_t)c * 64 + g * 8;
    f32x4 sc[16];
    #pragma unroll
    for (int nt = 0; nt < 16; ++nt) {
        f32x4 acc = (f32x4){0.f, 0.f, 0.f, 0.f};
        half8 b0 = *(const half8*)(kt + nt * 16 * 64);
        half8 b1 = *(const half8*)(kt + nt * 16 * 64 + 32);
        acc = __builtin_amdgcn_mfma_f32_16x16x32_f16(aq0, b0, acc, 0, 0, 0);
        acc = __builtin_amdgcn_mfma_f32_16x16x32_f16(aq1, b1, acc, 0, 0, 0);
        sc[nt] = acc;
    }

    // softmax: lane holds rows w*16+g*4+r, col nt*16+c; 16-lane groups share rows
    #pragma unroll
    for (int r = 0; r < 4; ++r) {
        float m = sc[0][r];
        #pragma unroll
        for (int nt = 1; nt < 16; ++nt) m = fmaxf(m, sc[nt][r]);
        m = fmaxf(m, __shfl_xor(m, 1));
        m = fmaxf(m, __shfl_xor(m, 2));
        m = fmaxf(m, __shfl_xor(m, 4));
        m = fmaxf(m, __shfl_xor(m, 8));
        float s = 0.f;
        #pragma unroll
        for (int nt = 0; nt < 16; ++nt) {
            float e = __expf(sc[nt][r] - m);
            sc[nt][r] = e;
            s += e;
        }
        s += __shfl_xor(s, 1);
        s += __shfl_xor(s, 2);
        s += __shfl_xor(s, 4);
        s += __shfl_xor(s, 8);
        float inv = 1.f / s;
        #pragma unroll
        for (int nt = 0; nt < 16; ++nt) sc[nt][r] *= inv;
    }

    // pack f16 pairs (cols c^1 via shfl) -> swizzled S_lds[row][kv]
    int odd = l & 1;
    #pragma unroll
    for (int r = 0; r < 4; ++r) {
        int row = w * 16 + g * 4 + r;
        unsigned swz = (unsigned)((row & 7) << 4);
        int mine = (odd == (r >> 1));   // evens write r=0,1; odds write r=2,3
        #pragma unroll
        for (int nt = 0; nt < 16; ++nt) {
            float v = sc[nt][r];
            float p = __shfl_xor(v, 1);
            if (mine) {
                unsigned u = odd ? pk2(p, v) : pk2(v, p);
                int pi = nt * 8 + (c >> 1);
                S_lds[(row * 512 + (((unsigned)(pi * 4)) ^ swz)) >> 2] = u;
            }
        }
    }
    __syncthreads();

    // PV: A = S (from swizzled LDS), B = V from vtokT[d][kv]
    const half_t* vt = vtokT + (size_t)bh * 64 * NKV + (size_t)c * NKV + g * 8;
    f32x4 o[4];
    #pragma unroll
    for (int nt = 0; nt < 4; ++nt) o[nt] = (f32x4){0.f, 0.f, 0.f, 0.f};
    int arow = w * 16 + c;
    unsigned aswz = (unsigned)((arow & 7) << 4);
    #pragma unroll
    for (int ks = 0; ks < 8; ++ks) {
        half8 as = *(const half8*)((const char*)S_lds + arow * 512 +
                                   (((unsigned)(ks * 64 + g * 16)) ^ aswz));
        #pragma unroll
        for (int nt = 0; nt < 4; ++nt) {
            half8 bv = *(const half8*)(vt + nt * 16 * NKV + ks * 32);
            o[nt] = __builtin_amdgcn_mfma_f32_16x16x32_f16(as, bv, o[nt], 0, 0, 0);
        }
    }
    float* op = otok + ((size_t)bh * HW + q0 + w * 16) * 64;
    #pragma unroll
    for (int nt = 0; nt < 4; ++nt)
        #pragma unroll
        for (int r = 0; r < 4; ++r)
            op[(g * 4 + r) * 64 + nt * 16 + c] = o[nt][r];
}

// ---------------- K4: output projection + bias (fp32, unchanged)
__global__ __launch_bounds__(256) void k4_outproj(const float* __restrict__ Wout,
                                                  const float* __restrict__ otok,
                                                  const float* __restrict__ bout,
                                                  float* __restrict__ outp) {
    __shared__ float aT[64 * 68];
    __shared__ float bvt[64 * 68];
    int t = threadIdx.x;
    int n0 = blockIdx.x * 64;
    int octile = blockIdx.y;
    int b = blockIdx.z;
    int to = t & 15, tn = t >> 4;
    float acc[4][4] = {};
    const float* Arow = Wout + octile * 64 * INNER;
    for (int h = 0; h < 8; ++h) {
        #pragma unroll
        for (int i = 0; i < 4; ++i) {
            int f4 = t + i * 256;
            int r = f4 >> 4, kvv = (f4 & 15) << 2;
            float4 a = *(const float4*)&Arow[r * INNER + h * 64 + kvv];
            aT[(kvv + 0) * 68 + r] = a.x;
            aT[(kvv + 1) * 68 + r] = a.y;
            aT[(kvv + 2) * 68 + r] = a.z;
            aT[(kvv + 3) * 68 + r] = a.w;
        }
        #pragma unroll
        for (int i = 0; i < 4; ++i) {
            int f4 = t + i * 256;
            int nn = f4 >> 4, dvv = (f4 & 15) << 2;
            float4 v = *(const float4*)&otok[((size_t)(b * HEADS + h) * HW + n0 + nn) * 64 + dvv];
            bvt[(dvv + 0) * 68 + nn] = v.x;
            bvt[(dvv + 1) * 68 + nn] = v.y;
            bvt[(dvv + 2) * 68 + nn] = v.z;
            bvt[(dvv + 3) * 68 + nn] = v.w;
        }
        __syncthreads();
        #pragma unroll 8
        for (int kk = 0; kk < 64; ++kk) {
            float4 a4 = *(const float4*)&aT[kk * 68 + 4 * to];
            float4 b4 = *(const float4*)&bvt[kk * 68 + 4 * tn];
            acc[0][0] += a4.x * b4.x; acc[0][1] += a4.x * b4.y; acc[0][2] += a4.x * b4.z; acc[0][3] += a4.x * b4.w;
            acc[1][0] += a4.y * b4.x; acc[1][1] += a4.y * b4.y; acc[1][2] += a4.y * b4.z; acc[1][3] += a4.y * b4.w;
            acc[2][0] += a4.z * b4.x; acc[2][1] += a4.z * b4.y; acc[2][2] += a4.z * b4.z; acc[2][3] += a4.z * b4.w;
            acc[3][0] += a4.w * b4.x; acc[3][1] += a4.w * b4.y; acc[3][2] += a4.w * b4.z; acc[3][3] += a4.w * b4.w;
        }
        __syncthreads();
    }
    int oc0 = octile * 64;
    #pragma unroll
    for (int i = 0; i < 4; ++i) {
        int oc = oc0 + 4 * to + i;
        float bb = bout[oc];
        *(float4*)&outp[(size_t)(b * DIM + oc) * HW + n0 + 4 * tn] =
            make_float4(acc[i][0] + bb, acc[i][1] + bb, acc[i][2] + bb, acc[i][3] + bb);
    }
}

extern "C" void kernel_launch(void* const* d_in, const int* in_sizes, int n_in,
                              void* d_out, int out_size, void* d_ws, size_t ws_size,
                              hipStream_t stream) {
    (void)in_sizes; (void)n_in; (void)out_size; (void)ws_size;
    const float* x = (const float*)d_in[0];
    const float* Wq = (const float*)d_in[1];
    const float* Wkv = (const float*)d_in[2];
    const float* Wout = (const float*)d_in[3];
    const float* bout = (const float*)d_in[4];
    float* outp = (float*)d_out;

    // Workspace (f32 units, total footprint 39,976,960 < 52,428,800 used previously):
    //   partial f32 [0, 7,340,032)              (dead after k2r)
    //   Wkv16  f16  [7,340,032, 13,762,560)     (dead after k2)
    //   Pt     f16  [13,762,560, 26,607,616)    (dead after k2)
    //   qtok   f16  [0, 12,845,056)             (written by k1, after k2r)
    //   otok   f32  [13,762,560, 39,452,672)    (overlays Pt, written by k3)
    //   ktok   f16  [39,452,672, 39,714,816)
    //   vtokT  f16  [39,714,816, 39,976,960)
    float* ws = (float*)d_ws;
    float* partial = ws;
    half_t* Wkv16 = (half_t*)(ws + 7340032);
    half_t* Pt    = (half_t*)(ws + 13762560);
    half_t* qtok  = (half_t*)ws;
    float*  otok  = ws + 13762560;
    half_t* ktok  = (half_t*)(ws + 39452672);
    half_t* vtokT = (half_t*)(ws + 39714816);

    k0_gather<<<dim3(6272), 256, 0, stream>>>(x, Pt);
    k_cvt<<<dim3(6272), 256, 0, stream>>>(Wkv, Wkv16);
    k2_kv<<<dim3(16, KSPLIT, 4), 256, 0, stream>>>(Wkv16, Pt, partial);
    k2r<<<dim3(128, 4), 256, 0, stream>>>(partial, ktok, vtokT);
    k1_qproj<<<dim3(196, 8, 4), 256, 0, stream>>>(x, Wq, qtok);
    k3_attn<<<dim3(196, 32), 256, 0, stream>>>(qtok, ktok, vtokT, otok);
    k4_outproj<<<dim3(196, 4, 4), 256, 0, stream>>>(Wout, otok, bout, outp);
}

// Round 5
// 754.699 us; speedup vs baseline: 2.9098x; 1.1539x over previous
//
#include <hip/hip_runtime.h>

#define HEADS 8
#define DHEAD 64
#define QSCALE 0.125f   // 64^-0.5
#define DIM 256
#define IMG 112
#define HW 12544        // 112*112
#define NKV 256         // 16*16
#define INNER 512
#define KCONV 12544     // 256*49
#define KSPLIT 7
#define KCHUNK 1792     // 12544/7

typedef _Float16 half_t;
typedef _Float16 half8 __attribute__((ext_vector_type(8)));
typedef float f32x4 __attribute__((ext_vector_type(4)));

__device__ inline unsigned pk2(float a, float b) {
    union { half_t h[2]; unsigned u; } x;
    x.h[0] = (half_t)a; x.h[1] = (half_t)b;
    return x.u;
}

// ---------------- K0: im2col gather -> TRANSPOSED f16 patches Pt[b][pos][k]
__global__ __launch_bounds__(256) void k0_gather(const float* __restrict__ x,
                                                 half_t* __restrict__ Pt) {
    int gid = blockIdx.x * 256 + threadIdx.x;  // one 8-k chunk
    int bp = gid / 1568;                       // 1568 = 12544/8
    int k8 = gid - bp * 1568;
    int b = bp >> 8, pos = bp & 255;
    int oy = pos >> 4, ox = pos & 15;
    const float* xb = x + (size_t)b * DIM * HW + (size_t)(oy * 7) * IMG + ox * 7;
    int k0 = k8 * 8;
    half8 hv;
    #pragma unroll
    for (int j = 0; j < 8; ++j) {
        int k = k0 + j;
        int cch = k / 49;
        int tap = k - cch * 49;
        int kh = tap / 7;
        int kw = tap - kh * 7;
        hv[j] = (half_t)xb[(size_t)cch * HW + kh * IMG + kw];
    }
    *(half8*)&Pt[(size_t)bp * KCONV + k0] = hv;
}

// ---------------- Kcvt: f32 -> f16 with scale (2048 elements per block)
__global__ __launch_bounds__(256) void k_cvt(const float* __restrict__ W,
                                             half_t* __restrict__ W16,
                                             float scale) {
    size_t i = ((size_t)blockIdx.x * 256 + threadIdx.x) * 8;
    float4 a = *(const float4*)&W[i];
    float4 b = *(const float4*)&W[i + 4];
    half8 h = { (half_t)(a.x * scale), (half_t)(a.y * scale),
                (half_t)(a.z * scale), (half_t)(a.w * scale),
                (half_t)(b.x * scale), (half_t)(b.y * scale),
                (half_t)(b.z * scale), (half_t)(b.w * scale) };
    *(half8*)&W16[i] = h;
}

// ---------------- Kx: transpose x f32 [b][c][n] -> xT16 f16 [b][n][c]
__global__ __launch_bounds__(256) void kx_t(const float* __restrict__ x,
                                            half_t* __restrict__ xT16) {
    __shared__ float tile[64 * 68];   // [c][n], linear float4 writes
    int t = threadIdx.x;
    int n0 = blockIdx.x * 64, c0 = blockIdx.y * 64, b = blockIdx.z;
    #pragma unroll
    for (int i = 0; i < 4; ++i) {
        int f4 = t + i * 256;
        int r = f4 >> 4, c4 = (f4 & 15) << 2;
        *(float4*)&tile[r * 68 + c4] =
            *(const float4*)&x[((size_t)(b * DIM + c0 + r)) * HW + n0 + c4];
    }
    __syncthreads();
    #pragma unroll
    for (int i = 0; i < 2; ++i) {
        int idx = t + i * 256;
        int rr = idx >> 3, cc8 = (idx & 7) << 3;
        half8 h;
        #pragma unroll
        for (int j = 0; j < 8; ++j) h[j] = (half_t)tile[(cc8 + j) * 68 + rr];
        *(half8*)&xT16[((size_t)b * HW + n0 + rr) * DIM + c0 + cc8] = h;
    }
}

// ---------------- K1: Q projection via f16 MFMA. qtok f16 [bh][n][d] (QSCALE in Wq16s)
__global__ __launch_bounds__(256) void k1_qproj(const half_t* __restrict__ Wq16s,
                                                const half_t* __restrict__ xT16,
                                                half_t* __restrict__ qtok) {
    int t = threadIdx.x;
    int w = t >> 6, l = t & 63, g = l >> 4, c = l & 15;
    int n0 = blockIdx.x * 256;
    int h = blockIdx.y;
    int b = blockIdx.z;
    const half_t* Ap = Wq16s + (size_t)(h * 64 + w * 16 + c) * DIM + g * 8;
    const half_t* Bp = xT16 + ((size_t)b * HW + n0 + c) * DIM + g * 8;
    f32x4 sc[16];
    #pragma unroll
    for (int nt = 0; nt < 16; ++nt) sc[nt] = (f32x4){0.f, 0.f, 0.f, 0.f};
    for (int kk = 0; kk < DIM / 32; ++kk) {
        half8 a = *(const half8*)(Ap + kk * 32);
        #pragma unroll
        for (int nt = 0; nt < 16; ++nt) {
            half8 bb = *(const half8*)(Bp + (size_t)(nt * 16) * DIM + kk * 32);
            sc[nt] = __builtin_amdgcn_mfma_f32_16x16x32_f16(a, bb, sc[nt], 0, 0, 0);
        }
    }
    // store: n = n0 + nt*16 + c, d = w*16 + g*4 + r  (4 consecutive d -> uint2)
    half_t* op = qtok + ((size_t)(b * HEADS + h) * HW + n0 + c) * 64 + w * 16 + g * 4;
    #pragma unroll
    for (int nt = 0; nt < 16; ++nt) {
        uint2 u = make_uint2(pk2(sc[nt][0], sc[nt][1]), pk2(sc[nt][2], sc[nt][3]));
        *(uint2*)&op[(size_t)(nt * 16) * 64] = u;
    }
}

// ---------------- K2: KV conv GEMM via f16 MFMA, split-K=7, fp32 partials
__global__ __launch_bounds__(256) void k2_kv(const half_t* __restrict__ W16,
                                             const half_t* __restrict__ Pt,
                                             float* __restrict__ partial) {
    int t = threadIdx.x;
    int w = t >> 6, l = t & 63, g = l >> 4, c = l & 15;
    int octile = blockIdx.x;   // 0..15 (64 oc each)
    int ks = blockIdx.y;       // 0..6
    int b = blockIdx.z;
    const half_t* Ap = W16 + (size_t)(octile * 64 + w * 16 + c) * KCONV + ks * KCHUNK + g * 8;
    const half_t* Bp = Pt + ((size_t)b * 256 + c) * KCONV + ks * KCHUNK + g * 8;
    f32x4 sc[16];
    #pragma unroll
    for (int nt = 0; nt < 16; ++nt) sc[nt] = (f32x4){0.f, 0.f, 0.f, 0.f};
    for (int kk = 0; kk < KCHUNK / 32; ++kk) {
        half8 a = *(const half8*)(Ap + kk * 32);
        #pragma unroll
        for (int nt = 0; nt < 16; ++nt) {
            half8 bb = *(const half8*)(Bp + (size_t)nt * 16 * KCONV + kk * 32);
            sc[nt] = __builtin_amdgcn_mfma_f32_16x16x32_f16(a, bb, sc[nt], 0, 0, 0);
        }
    }
    float* op = partial + ((size_t)(ks * 4 + b) * 1024 + octile * 64 + w * 16) * 256;
    #pragma unroll
    for (int nt = 0; nt < 16; ++nt)
        #pragma unroll
        for (int r = 0; r < 4; ++r)
            op[(g * 4 + r) * 256 + nt * 16 + c] = sc[nt][r];
}

// ---------------- K2r: reduce partials -> ktok f16 [bh][kv][d], vtokT f16 [bh][d][kv]
// partial slice index is (ks*4 + b): per-ks stride = 4*1024*256 = 1,048,576 floats.
__global__ __launch_bounds__(256) void k2r(const float* __restrict__ partial,
                                           half_t* __restrict__ ktok,
                                           half_t* __restrict__ vtokT) {
    int pos = threadIdx.x;
    int oc0 = blockIdx.x * 8;
    int b = blockIdx.y;
    float v[8];
    #pragma unroll
    for (int j = 0; j < 8; ++j) {
        const float* src = partial + ((size_t)b * 1024 + oc0 + j) * 256 + pos;
        float s = 0.f;
        #pragma unroll
        for (int ksb = 0; ksb < KSPLIT; ++ksb) s += src[(size_t)ksb * 1048576];
        v[j] = s;
    }
    int h = (oc0 >> 6) & 7, d0 = oc0 & 63;
    if (oc0 < 512) {
        uint4 u = make_uint4(pk2(v[0], v[1]), pk2(v[2], v[3]),
                             pk2(v[4], v[5]), pk2(v[6], v[7]));
        *(uint4*)&ktok[((size_t)(b * HEADS + h) * NKV + pos) * 64 + d0] = u;
    } else {
        #pragma unroll
        for (int j = 0; j < 8; ++j)
            vtokT[((size_t)(b * HEADS + h) * 64 + d0 + j) * NKV + pos] = (half_t)v[j];
    }
}

// ---------------- K3: fused attention, f16 MFMA. Block = 64 q rows, wave = 16 q rows.
// Writes otok16 f16 [b][n][h*64+d] (k-contiguous for k4's B-fragments).
__global__ __launch_bounds__(256) void k3_attn(const half_t* __restrict__ qtok,
                                               const half_t* __restrict__ ktok,
                                               const half_t* __restrict__ vtokT,
                                               half_t* __restrict__ otok16) {
    __shared__ unsigned S_lds[64 * 128];   // 64 rows x 256 f16 (swizzled), 32 KB
    int t = threadIdx.x;
    int w = t >> 6, l = t & 63, g = l >> 4, c = l & 15;
    int q0 = blockIdx.x * 64;
    int bh = blockIdx.y;

    // Q A-frags: A[m=c][k=d], d-contiguous in qtok[n][d]
    const half_t* qp = qtok + ((size_t)bh * HW + q0 + w * 16 + c) * 64 + g * 8;
    half8 aq0 = *(const half8*)(qp);
    half8 aq1 = *(const half8*)(qp + 32);

    // dots: 16 n-tiles over kv, K B-frags from ktok[kv][d]
    const half_t* kt = ktok + (size_t)bh * NKV * 64 + (size_t)c * 64 + g * 8;
    f32x4 sc[16];
    #pragma unroll
    for (int nt = 0; nt < 16; ++nt) {
        f32x4 acc = (f32x4){0.f, 0.f, 0.f, 0.f};
        half8 b0 = *(const half8*)(kt + nt * 16 * 64);
        half8 b1 = *(const half8*)(kt + nt * 16 * 64 + 32);
        acc = __builtin_amdgcn_mfma_f32_16x16x32_f16(aq0, b0, acc, 0, 0, 0);
        acc = __builtin_amdgcn_mfma_f32_16x16x32_f16(aq1, b1, acc, 0, 0, 0);
        sc[nt] = acc;
    }

    // softmax: lane holds rows w*16+g*4+r, col nt*16+c; 16-lane groups share rows
    #pragma unroll
    for (int r = 0; r < 4; ++r) {
        float m = sc[0][r];
        #pragma unroll
        for (int nt = 1; nt < 16; ++nt) m = fmaxf(m, sc[nt][r]);
        m = fmaxf(m, __shfl_xor(m, 1));
        m = fmaxf(m, __shfl_xor(m, 2));
        m = fmaxf(m, __shfl_xor(m, 4));
        m = fmaxf(m, __shfl_xor(m, 8));
        float s = 0.f;
        #pragma unroll
        for (int nt = 0; nt < 16; ++nt) {
            float e = __expf(sc[nt][r] - m);
            sc[nt][r] = e;
            s += e;
        }
        s += __shfl_xor(s, 1);
        s += __shfl_xor(s, 2);
        s += __shfl_xor(s, 4);
        s += __shfl_xor(s, 8);
        float inv = 1.f / s;
        #pragma unroll
        for (int nt = 0; nt < 16; ++nt) sc[nt][r] *= inv;
    }

    // pack f16 pairs (cols c^1 via shfl) -> swizzled S_lds[row][kv]
    int odd = l & 1;
    #pragma unroll
    for (int r = 0; r < 4; ++r) {
        int row = w * 16 + g * 4 + r;
        unsigned swz = (unsigned)((row & 7) << 4);
        int mine = (odd == (r >> 1));   // evens write r=0,1; odds write r=2,3
        #pragma unroll
        for (int nt = 0; nt < 16; ++nt) {
            float v = sc[nt][r];
            float p = __shfl_xor(v, 1);
            if (mine) {
                unsigned u = odd ? pk2(p, v) : pk2(v, p);
                int pi = nt * 8 + (c >> 1);
                S_lds[(row * 512 + (((unsigned)(pi * 4)) ^ swz)) >> 2] = u;
            }
        }
    }
    __syncthreads();

    // PV: A = S (from swizzled LDS), B = V from vtokT[d][kv]
    const half_t* vt = vtokT + (size_t)bh * 64 * NKV + (size_t)c * NKV + g * 8;
    f32x4 o[4];
    #pragma unroll
    for (int nt = 0; nt < 4; ++nt) o[nt] = (f32x4){0.f, 0.f, 0.f, 0.f};
    int arow = w * 16 + c;
    unsigned aswz = (unsigned)((arow & 7) << 4);
    #pragma unroll
    for (int ks = 0; ks < 8; ++ks) {
        half8 as = *(const half8*)((const char*)S_lds + arow * 512 +
                                   (((unsigned)(ks * 64 + g * 16)) ^ aswz));
        #pragma unroll
        for (int nt = 0; nt < 4; ++nt) {
            half8 bv = *(const half8*)(vt + nt * 16 * NKV + ks * 32);
            o[nt] = __builtin_amdgcn_mfma_f32_16x16x32_f16(as, bv, o[nt], 0, 0, 0);
        }
    }
    // store f16: n = q0 + w*16 + g*4 + r, k = h*64 + nt*16 + c
    int b = bh >> 3, h = bh & 7;
    half_t* op = otok16 + ((size_t)b * HW + q0 + w * 16) * INNER + h * 64;
    #pragma unroll
    for (int nt = 0; nt < 4; ++nt)
        #pragma unroll
        for (int r = 0; r < 4; ++r)
            op[(size_t)(g * 4 + r) * INNER + nt * 16 + c] = (half_t)o[nt][r];
}

// ---------------- K4: output projection via f16 MFMA + bias
__global__ __launch_bounds__(256) void k4_outproj(const half_t* __restrict__ Wout16,
                                                  const half_t* __restrict__ otok16,
                                                  const float* __restrict__ bout,
                                                  float* __restrict__ outp) {
    int t = threadIdx.x;
    int w = t >> 6, l = t & 63, g = l >> 4, c = l & 15;
    int n0 = blockIdx.x * 256;
    int m0 = blockIdx.y * 64;
    int b = blockIdx.z;
    const half_t* Ap = Wout16 + (size_t)(m0 + w * 16 + c) * INNER + g * 8;
    const half_t* Bp = otok16 + ((size_t)b * HW + n0 + c) * INNER + g * 8;
    f32x4 sc[16];
    #pragma unroll
    for (int nt = 0; nt < 16; ++nt) sc[nt] = (f32x4){0.f, 0.f, 0.f, 0.f};
    for (int kk = 0; kk < INNER / 32; ++kk) {
        half8 a = *(const half8*)(Ap + kk * 32);
        #pragma unroll
        for (int nt = 0; nt < 16; ++nt) {
            half8 bb = *(const half8*)(Bp + (size_t)(nt * 16) * INNER + kk * 32);
            sc[nt] = __builtin_amdgcn_mfma_f32_16x16x32_f16(a, bb, sc[nt], 0, 0, 0);
        }
    }
    int ocb = m0 + w * 16 + g * 4;
    float b0 = bout[ocb], b1 = bout[ocb + 1], b2 = bout[ocb + 2], b3 = bout[ocb + 3];
    float* op = outp + ((size_t)b * DIM + ocb) * HW + n0 + c;
    #pragma unroll
    for (int nt = 0; nt < 16; ++nt) {
        op[(size_t)0 * HW + nt * 16] = sc[nt][0] + b0;
        op[(size_t)1 * HW + nt * 16] = sc[nt][1] + b1;
        op[(size_t)2 * HW + nt * 16] = sc[nt][2] + b2;
        op[(size_t)3 * HW + nt * 16] = sc[nt][3] + b3;
    }
}

extern "C" void kernel_launch(void* const* d_in, const int* in_sizes, int n_in,
                              void* d_out, int out_size, void* d_ws, size_t ws_size,
                              hipStream_t stream) {
    (void)in_sizes; (void)n_in; (void)out_size; (void)ws_size;
    const float* x = (const float*)d_in[0];
    const float* Wq = (const float*)d_in[1];
    const float* Wkv = (const float*)d_in[2];
    const float* Wout = (const float*)d_in[3];
    const float* bout = (const float*)d_in[4];
    float* outp = (float*)d_out;

    // Workspace layout (f32 units, total 40,112,640 = 160.5 MB; ws >= 209.7 MB known-safe):
    //   partial f32 [0, 7,340,032)                    (k2 out, dead after k2r)
    //   ktok   f16  [7,340,032, 7,602,176)
    //   vtokT  f16  [7,602,176, 7,864,320)
    //   Wq16s  f16  [7,864,320, 7,929,856)            (QSCALE folded)
    //   Wout16 f16  [7,929,856, 7,995,392)
    //   Wkv16  f16  [8,000,000, 14,422,528)           (dead after k2)
    //   Pt     f16  [14,422,528, 20,845,056)          (dead after k2)
    //   otok16 f16  [8,000,000, 20,845,056)+(.00)     (overlays Wkv16+Pt, written by k3)
    //   xT16   f16  [20,845,056, 27,267,584)          (dead after k1; tail may be clobbered by otok16 - ok)
    //   qtok   f16  [27,267,584, 40,112,640)
    float* ws = (float*)d_ws;
    float*  partial = ws;
    half_t* ktok    = (half_t*)(ws + 7340032);
    half_t* vtokT   = (half_t*)(ws + 7602176);
    half_t* Wq16s   = (half_t*)(ws + 7864320);
    half_t* Wout16  = (half_t*)(ws + 7929856);
    half_t* Wkv16   = (half_t*)(ws + 8000000);
    half_t* Pt      = (half_t*)(ws + 14422528);
    half_t* otok16  = (half_t*)(ws + 8000000);
    half_t* xT16    = (half_t*)(ws + 20845056);
    half_t* qtok    = (half_t*)(ws + 27267584);

    k_cvt<<<dim3(6272), 256, 0, stream>>>(Wkv, Wkv16, 1.0f);
    k_cvt<<<dim3(64), 256, 0, stream>>>(Wq, Wq16s, QSCALE);
    k_cvt<<<dim3(64), 256, 0, stream>>>(Wout, Wout16, 1.0f);
    kx_t<<<dim3(196, 4, 4), 256, 0, stream>>>(x, xT16);
    k0_gather<<<dim3(6272), 256, 0, stream>>>(x, Pt);
    k2_kv<<<dim3(16, KSPLIT, 4), 256, 0, stream>>>(Wkv16, Pt, partial);
    k2r<<<dim3(128, 4), 256, 0, stream>>>(partial, ktok, vtokT);
    k1_qproj<<<dim3(49, 8, 4), 256, 0, stream>>>(Wq16s, xT16, qtok);
    k3_attn<<<dim3(196, 32), 256, 0, stream>>>(qtok, ktok, vtokT, otok16);
    k4_outproj<<<dim3(49, 4, 4), 256, 0, stream>>>(Wout16, otok16, bout, outp);
}

// Round 6
// 523.684 us; speedup vs baseline: 4.1934x; 1.4411x over previous
//
#include <hip/hip_runtime.h>

#define HEADS 8
#define DHEAD 64
#define QSCALE 0.125f   // 64^-0.5
#define DIM 256
#define IMG 112
#define HW 12544        // 112*112
#define NKV 256         // 16*16
#define INNER 512
#define KCONV 12544     // 256*49
#define KSPLIT 14
#define KCHUNK 896      // 12544/14
#define K2STEPS 28      // KCHUNK/32

typedef _Float16 half_t;
typedef _Float16 half8 __attribute__((ext_vector_type(8)));
typedef float f32x4 __attribute__((ext_vector_type(4)));

__device__ inline unsigned pk2(float a, float b) {
    union { half_t h[2]; unsigned u; } x;
    x.h[0] = (half_t)a; x.h[1] = (half_t)b;
    return x.u;
}

// ---------------- K0: im2col gather -> TRANSPOSED f16 patches Pt[b][pos][k]
__global__ __launch_bounds__(256) void k0_gather(const float* __restrict__ x,
                                                 half_t* __restrict__ Pt) {
    int gid = blockIdx.x * 256 + threadIdx.x;  // one 8-k chunk
    int bp = gid / 1568;                       // 1568 = 12544/8
    int k8 = gid - bp * 1568;
    int b = bp >> 8, pos = bp & 255;
    int oy = pos >> 4, ox = pos & 15;
    const float* xb = x + (size_t)b * DIM * HW + (size_t)(oy * 7) * IMG + ox * 7;
    int k0 = k8 * 8;
    half8 hv;
    #pragma unroll
    for (int j = 0; j < 8; ++j) {
        int k = k0 + j;
        int cch = k / 49;
        int tap = k - cch * 49;
        int kh = tap / 7;
        int kw = tap - kh * 7;
        hv[j] = (half_t)xb[(size_t)cch * HW + kh * IMG + kw];
    }
    *(half8*)&Pt[(size_t)bp * KCONV + k0] = hv;
}

// ---------------- Kcvt: f32 -> f16 with scale
__global__ __launch_bounds__(256) void k_cvt(const float* __restrict__ W,
                                             half_t* __restrict__ W16,
                                             float scale) {
    size_t i = ((size_t)blockIdx.x * 256 + threadIdx.x) * 8;
    float4 a = *(const float4*)&W[i];
    float4 b = *(const float4*)&W[i + 4];
    half8 h = { (half_t)(a.x * scale), (half_t)(a.y * scale),
                (half_t)(a.z * scale), (half_t)(a.w * scale),
                (half_t)(b.x * scale), (half_t)(b.y * scale),
                (half_t)(b.z * scale), (half_t)(b.w * scale) };
    *(half8*)&W16[i] = h;
}

// ---------------- Kx: transpose x f32 [b][c][n] -> xT16 f16 [b][n][c]
__global__ __launch_bounds__(256) void kx_t(const float* __restrict__ x,
                                            half_t* __restrict__ xT16) {
    __shared__ float tile[64 * 68];
    int t = threadIdx.x;
    int n0 = blockIdx.x * 64, c0 = blockIdx.y * 64, b = blockIdx.z;
    #pragma unroll
    for (int i = 0; i < 4; ++i) {
        int f4 = t + i * 256;
        int r = f4 >> 4, c4 = (f4 & 15) << 2;
        *(float4*)&tile[r * 68 + c4] =
            *(const float4*)&x[((size_t)(b * DIM + c0 + r)) * HW + n0 + c4];
    }
    __syncthreads();
    #pragma unroll
    for (int i = 0; i < 2; ++i) {
        int idx = t + i * 256;
        int rr = idx >> 3, cc8 = (idx & 7) << 3;
        half8 h;
        #pragma unroll
        for (int j = 0; j < 8; ++j) h[j] = (half_t)tile[(cc8 + j) * 68 + rr];
        *(half8*)&xT16[((size_t)b * HW + n0 + rr) * DIM + c0 + cc8] = h;
    }
}

// ---------------- K1: Q projection via f16 MFMA. qtok f16 [bh][n][d] (QSCALE in Wq16s)
__global__ __launch_bounds__(256) void k1_qproj(const half_t* __restrict__ Wq16s,
                                                const half_t* __restrict__ xT16,
                                                half_t* __restrict__ qtok) {
    int t = threadIdx.x;
    int w = t >> 6, l = t & 63, g = l >> 4, c = l & 15;
    int n0 = blockIdx.x * 256;
    int h = blockIdx.y;
    int b = blockIdx.z;
    const half_t* Ap = Wq16s + (size_t)(h * 64 + w * 16 + c) * DIM + g * 8;
    const half_t* Bp = xT16 + ((size_t)b * HW + n0 + c) * DIM + g * 8;
    f32x4 sc[16];
    #pragma unroll
    for (int nt = 0; nt < 16; ++nt) sc[nt] = (f32x4){0.f, 0.f, 0.f, 0.f};
    for (int kk = 0; kk < DIM / 32; ++kk) {
        half8 a = *(const half8*)(Ap + kk * 32);
        #pragma unroll
        for (int nt = 0; nt < 16; ++nt) {
            half8 bb = *(const half8*)(Bp + (size_t)(nt * 16) * DIM + kk * 32);
            sc[nt] = __builtin_amdgcn_mfma_f32_16x16x32_f16(a, bb, sc[nt], 0, 0, 0);
        }
    }
    half_t* op = qtok + ((size_t)(b * HEADS + h) * HW + n0 + c) * 64 + w * 16 + g * 4;
    #pragma unroll
    for (int nt = 0; nt < 16; ++nt) {
        uint2 u = make_uint2(pk2(sc[nt][0], sc[nt][1]), pk2(sc[nt][2], sc[nt][3]));
        *(uint2*)&op[(size_t)(nt * 16) * 64] = u;
    }
}

// ---------------- K2: KV conv GEMM via f16 MFMA, split-K=14, LDS-staged B (dbuf)
__global__ __launch_bounds__(256) void k2_kv(const half_t* __restrict__ W16,
                                             const half_t* __restrict__ Pt,
                                             float* __restrict__ partial) {
    __shared__ char Bs[2][16384];   // [pos 256][k 32] f16, 16B-granule swizzled
    int t = threadIdx.x;
    int w = t >> 6, l = t & 63, g = l >> 4, c = l & 15;
    int octile = blockIdx.x;   // 0..15 (64 oc each)
    int ks = blockIdx.y;       // 0..13
    int b = blockIdx.z;
    const half_t* Ap = W16 + (size_t)(octile * 64 + w * 16 + c) * KCONV + ks * KCHUNK + g * 8;
    const half_t* Bbase = Pt + ((size_t)b * 256 + t) * KCONV + ks * KCHUNK;  // row t

    unsigned wsw = (unsigned)((t & 3) << 4);
    // prologue: stage step 0
    half8 st[4];
    #pragma unroll
    for (int j = 0; j < 4; ++j) st[j] = *(const half8*)(Bbase + j * 8);
    {
        char* wp = Bs[0] + t * 64;
        #pragma unroll
        for (int j = 0; j < 4; ++j) *(half8*)(wp + (((unsigned)(j * 16)) ^ wsw)) = st[j];
    }
    __syncthreads();

    f32x4 sc[16];
    #pragma unroll
    for (int nt = 0; nt < 16; ++nt) sc[nt] = (f32x4){0.f, 0.f, 0.f, 0.f};

    for (int kk = 0; kk < K2STEPS; ++kk) {
        char* cur = Bs[kk & 1];
        char* nxt = Bs[(kk & 1) ^ 1];
        if (kk < K2STEPS - 1) {   // issue next-step loads early (hide under MFMA)
            #pragma unroll
            for (int j = 0; j < 4; ++j)
                st[j] = *(const half8*)(Bbase + (kk + 1) * 32 + j * 8);
        }
        half8 a = *(const half8*)(Ap + kk * 32);
        __builtin_amdgcn_s_setprio(1);
        #pragma unroll
        for (int nt = 0; nt < 16; ++nt) {
            int row = nt * 16 + c;
            half8 bb = *(const half8*)(cur + row * 64 +
                                       (((unsigned)(g * 16)) ^ ((unsigned)((row & 3) << 4))));
            sc[nt] = __builtin_amdgcn_mfma_f32_16x16x32_f16(a, bb, sc[nt], 0, 0, 0);
        }
        __builtin_amdgcn_s_setprio(0);
        if (kk < K2STEPS - 1) {
            char* wp = nxt + t * 64;
            #pragma unroll
            for (int j = 0; j < 4; ++j) *(half8*)(wp + (((unsigned)(j * 16)) ^ wsw)) = st[j];
            __syncthreads();
        }
    }
    float* op = partial + ((size_t)(ks * 4 + b) * 1024 + octile * 64 + w * 16) * 256;
    #pragma unroll
    for (int nt = 0; nt < 16; ++nt)
        #pragma unroll
        for (int r = 0; r < 4; ++r)
            op[(g * 4 + r) * 256 + nt * 16 + c] = sc[nt][r];
}

// ---------------- K2r: reduce partials -> ktok f16 [bh][kv][d], vtokT f16 [bh][d][kv]
// partial slice index is (ks*4 + b): per-ks stride = 4*1024*256 = 1,048,576 floats.
__global__ __launch_bounds__(256) void k2r(const float* __restrict__ partial,
                                           half_t* __restrict__ ktok,
                                           half_t* __restrict__ vtokT) {
    int pos = threadIdx.x;
    int oc0 = blockIdx.x * 8;
    int b = blockIdx.y;
    float v[8];
    #pragma unroll
    for (int j = 0; j < 8; ++j) {
        const float* src = partial + ((size_t)b * 1024 + oc0 + j) * 256 + pos;
        float s = 0.f;
        #pragma unroll
        for (int ksb = 0; ksb < KSPLIT; ++ksb) s += src[(size_t)ksb * 1048576];
        v[j] = s;
    }
    int h = (oc0 >> 6) & 7, d0 = oc0 & 63;
    if (oc0 < 512) {
        uint4 u = make_uint4(pk2(v[0], v[1]), pk2(v[2], v[3]),
                             pk2(v[4], v[5]), pk2(v[6], v[7]));
        *(uint4*)&ktok[((size_t)(b * HEADS + h) * NKV + pos) * 64 + d0] = u;
    } else {
        #pragma unroll
        for (int j = 0; j < 8; ++j)
            vtokT[((size_t)(b * HEADS + h) * 64 + d0 + j) * NKV + pos] = (half_t)v[j];
    }
}

// ---------------- K3: fused attention, f16 MFMA. Block = 8 waves = 128 q rows.
// K (32KB) + V^T (32KB) staged in swizzled LDS once per block; S 64KB; total 128KB.
__global__ __launch_bounds__(512) void k3_attn(const half_t* __restrict__ qtok,
                                               const half_t* __restrict__ ktok,
                                               const half_t* __restrict__ vtokT,
                                               half_t* __restrict__ otok16) {
    extern __shared__ char lds[];
    char* K_lds = lds;                         // byte(kv,·) = kv*128 + (off ^ ((kv&7)<<4))
    char* V_lds = lds + 32768;                 // byte(d,·)  = d*512  + (off ^ ((d&7)<<4))
    unsigned* Sl = (unsigned*)(lds + 65536);   // 128 rows x 512B, existing swizzle
    int t = threadIdx.x;
    int w = t >> 6, l = t & 63, g = l >> 4, c = l & 15;
    int q0 = blockIdx.x * 128;
    int bh = blockIdx.y;

    // Q A-frags (global, issued before staging barrier)
    const half_t* qp = qtok + ((size_t)bh * HW + q0 + w * 16 + c) * 64 + g * 8;
    half8 aq0 = *(const half8*)(qp);
    half8 aq1 = *(const half8*)(qp + 32);

    // stage K: thread t covers kv = t>>1, 32 halfs at (t&1)*32
    {
        int kv = t >> 1;
        const half_t* kg = ktok + (size_t)bh * NKV * 64 + (size_t)kv * 64 + (t & 1) * 32;
        char* wp = K_lds + kv * 128;
        unsigned sw = (unsigned)((kv & 7) << 4);
        unsigned base = (unsigned)((t & 1) * 64);
        #pragma unroll
        for (int j = 0; j < 4; ++j)
            *(half8*)(wp + ((base + j * 16) ^ sw)) = *(const half8*)(kg + j * 8);
    }
    // stage V^T: thread t covers d = t>>3, 32 halfs at (t&7)*32
    {
        int d = t >> 3;
        const half_t* vg = vtokT + (size_t)bh * 64 * NKV + (size_t)d * NKV + (t & 7) * 32;
        char* wp = V_lds + d * 512;
        unsigned sw = (unsigned)((d & 7) << 4);
        unsigned base = (unsigned)((t & 7) * 64);
        #pragma unroll
        for (int j = 0; j < 4; ++j)
            *(half8*)(wp + ((base + j * 16) ^ sw)) = *(const half8*)(vg + j * 8);
    }
    __syncthreads();

    // dots from K_lds
    f32x4 sc[16];
    __builtin_amdgcn_s_setprio(1);
    #pragma unroll
    for (int nt = 0; nt < 16; ++nt) {
        int row = nt * 16 + c;
        const char* kp = K_lds + row * 128;
        unsigned sw = (unsigned)((row & 7) << 4);
        half8 b0 = *(const half8*)(kp + (((unsigned)(g * 16)) ^ sw));
        half8 b1 = *(const half8*)(kp + (((unsigned)(g * 16 + 64)) ^ sw));
        f32x4 acc = (f32x4){0.f, 0.f, 0.f, 0.f};
        acc = __builtin_amdgcn_mfma_f32_16x16x32_f16(aq0, b0, acc, 0, 0, 0);
        acc = __builtin_amdgcn_mfma_f32_16x16x32_f16(aq1, b1, acc, 0, 0, 0);
        sc[nt] = acc;
    }
    __builtin_amdgcn_s_setprio(0);

    // softmax: lane holds rows w*16+g*4+r, col nt*16+c
    #pragma unroll
    for (int r = 0; r < 4; ++r) {
        float m = sc[0][r];
        #pragma unroll
        for (int nt = 1; nt < 16; ++nt) m = fmaxf(m, sc[nt][r]);
        m = fmaxf(m, __shfl_xor(m, 1));
        m = fmaxf(m, __shfl_xor(m, 2));
        m = fmaxf(m, __shfl_xor(m, 4));
        m = fmaxf(m, __shfl_xor(m, 8));
        float s = 0.f;
        #pragma unroll
        for (int nt = 0; nt < 16; ++nt) {
            float e = __expf(sc[nt][r] - m);
            sc[nt][r] = e;
            s += e;
        }
        s += __shfl_xor(s, 1);
        s += __shfl_xor(s, 2);
        s += __shfl_xor(s, 4);
        s += __shfl_xor(s, 8);
        float inv = 1.f / s;
        #pragma unroll
        for (int nt = 0; nt < 16; ++nt) sc[nt][r] *= inv;
    }

    // pack f16 pairs (cols c^1 via shfl) -> swizzled S rows (wave-private: rows w*16..w*16+15)
    int odd = l & 1;
    #pragma unroll
    for (int r = 0; r < 4; ++r) {
        int row = w * 16 + g * 4 + r;
        unsigned swz = (unsigned)((row & 7) << 4);
        int mine = (odd == (r >> 1));
        #pragma unroll
        for (int nt = 0; nt < 16; ++nt) {
            float v = sc[nt][r];
            float p = __shfl_xor(v, 1);
            if (mine) {
                unsigned u = odd ? pk2(p, v) : pk2(v, p);
                int pi = nt * 8 + (c >> 1);
                Sl[(row * 512 + (((unsigned)(pi * 4)) ^ swz)) >> 2] = u;
            }
        }
    }
    // S write->read is wave-private: wave-local wait, no block barrier
    asm volatile("s_waitcnt lgkmcnt(0)" ::: "memory");
    __builtin_amdgcn_sched_barrier(0);

    // PV: A = S rows (LDS), B = V from V_lds
    f32x4 o[4];
    #pragma unroll
    for (int nt = 0; nt < 4; ++nt) o[nt] = (f32x4){0.f, 0.f, 0.f, 0.f};
    int arow = w * 16 + c;
    unsigned aswz = (unsigned)((arow & 7) << 4);
    __builtin_amdgcn_s_setprio(1);
    #pragma unroll
    for (int ks = 0; ks < 8; ++ks) {
        half8 as = *(const half8*)((const char*)Sl + arow * 512 +
                                   (((unsigned)(ks * 64 + g * 16)) ^ aswz));
        #pragma unroll
        for (int nt = 0; nt < 4; ++nt) {
            int d = nt * 16 + c;
            half8 bv = *(const half8*)(V_lds + d * 512 +
                                       (((unsigned)(ks * 64 + g * 16)) ^ ((unsigned)((d & 7) << 4))));
            o[nt] = __builtin_amdgcn_mfma_f32_16x16x32_f16(as, bv, o[nt], 0, 0, 0);
        }
    }
    __builtin_amdgcn_s_setprio(0);
    // store f16: n = q0 + w*16 + g*4 + r, k = h*64 + nt*16 + c
    int b = bh >> 3, h = bh & 7;
    half_t* op = otok16 + ((size_t)b * HW + q0 + w * 16) * INNER + h * 64;
    #pragma unroll
    for (int nt = 0; nt < 4; ++nt)
        #pragma unroll
        for (int r = 0; r < 4; ++r)
            op[(size_t)(g * 4 + r) * INNER + nt * 16 + c] = (half_t)o[nt][r];
}

// ---------------- K4: output projection via f16 MFMA + bias
__global__ __launch_bounds__(256) void k4_outproj(const half_t* __restrict__ Wout16,
                                                  const half_t* __restrict__ otok16,
                                                  const float* __restrict__ bout,
                                                  float* __restrict__ outp) {
    int t = threadIdx.x;
    int w = t >> 6, l = t & 63, g = l >> 4, c = l & 15;
    int n0 = blockIdx.x * 256;
    int m0 = blockIdx.y * 64;
    int b = blockIdx.z;
    const half_t* Ap = Wout16 + (size_t)(m0 + w * 16 + c) * INNER + g * 8;
    const half_t* Bp = otok16 + ((size_t)b * HW + n0 + c) * INNER + g * 8;
    f32x4 sc[16];
    #pragma unroll
    for (int nt = 0; nt < 16; ++nt) sc[nt] = (f32x4){0.f, 0.f, 0.f, 0.f};
    for (int kk = 0; kk < INNER / 32; ++kk) {
        half8 a = *(const half8*)(Ap + kk * 32);
        #pragma unroll
        for (int nt = 0; nt < 16; ++nt) {
            half8 bb = *(const half8*)(Bp + (size_t)(nt * 16) * INNER + kk * 32);
            sc[nt] = __builtin_amdgcn_mfma_f32_16x16x32_f16(a, bb, sc[nt], 0, 0, 0);
        }
    }
    int ocb = m0 + w * 16 + g * 4;
    float b0 = bout[ocb], b1 = bout[ocb + 1], b2 = bout[ocb + 2], b3 = bout[ocb + 3];
    float* op = outp + ((size_t)b * DIM + ocb) * HW + n0 + c;
    #pragma unroll
    for (int nt = 0; nt < 16; ++nt) {
        op[(size_t)0 * HW + nt * 16] = sc[nt][0] + b0;
        op[(size_t)1 * HW + nt * 16] = sc[nt][1] + b1;
        op[(size_t)2 * HW + nt * 16] = sc[nt][2] + b2;
        op[(size_t)3 * HW + nt * 16] = sc[nt][3] + b3;
    }
}

extern "C" void kernel_launch(void* const* d_in, const int* in_sizes, int n_in,
                              void* d_out, int out_size, void* d_ws, size_t ws_size,
                              hipStream_t stream) {
    (void)in_sizes; (void)n_in; (void)out_size; (void)ws_size;
    const float* x = (const float*)d_in[0];
    const float* Wq = (const float*)d_in[1];
    const float* Wkv = (const float*)d_in[2];
    const float* Wout = (const float*)d_in[3];
    const float* bout = (const float*)d_in[4];
    float* outp = (float*)d_out;

    // Workspace layout (f32 units, total 47,448,064 = 189.8 MB; 209.7 MB known-safe):
    //   partial f32 [0, 14,680,064)                   (56 slices, dead after k2r)
    //   ktok   f16  [14,680,064, 14,942,208)
    //   vtokT  f16  [14,942,208, 15,204,352)
    //   Wq16s  f16  [15,204,352, 15,269,888)          (QSCALE folded)
    //   Wout16 f16  [15,269,888, 15,335,424)
    //   Wkv16  f16  [15,335,424, 21,757,952)          (dead after k2)
    //   Pt     f16  [21,757,952, 28,180,480)          (dead after k2)
    //   otok16 f16  [15,335,424, 28,180,480)          (overlays Wkv16+Pt, written by k3)
    //   xT16   f16  [28,180,480, 34,603,008)          (dead after k1)
    //   qtok   f16  [34,603,008, 47,448,064)
    float* ws = (float*)d_ws;
    float*  partial = ws;
    half_t* ktok    = (half_t*)(ws + 14680064);
    half_t* vtokT   = (half_t*)(ws + 14942208);
    half_t* Wq16s   = (half_t*)(ws + 15204352);
    half_t* Wout16  = (half_t*)(ws + 15269888);
    half_t* Wkv16   = (half_t*)(ws + 15335424);
    half_t* Pt      = (half_t*)(ws + 21757952);
    half_t* otok16  = (half_t*)(ws + 15335424);
    half_t* xT16    = (half_t*)(ws + 28180480);
    half_t* qtok    = (half_t*)(ws + 34603008);

    hipFuncSetAttribute((const void*)k3_attn,
                        hipFuncAttributeMaxDynamicSharedMemorySize, 131072);

    k_cvt<<<dim3(6272), 256, 0, stream>>>(Wkv, Wkv16, 1.0f);
    k_cvt<<<dim3(64), 256, 0, stream>>>(Wq, Wq16s, QSCALE);
    k_cvt<<<dim3(64), 256, 0, stream>>>(Wout, Wout16, 1.0f);
    kx_t<<<dim3(196, 4, 4), 256, 0, stream>>>(x, xT16);
    k0_gather<<<dim3(6272), 256, 0, stream>>>(x, Pt);
    k2_kv<<<dim3(16, KSPLIT, 4), 256, 0, stream>>>(Wkv16, Pt, partial);
    k2r<<<dim3(128, 4), 256, 0, stream>>>(partial, ktok, vtokT);
    k1_qproj<<<dim3(49, 8, 4), 256, 0, stream>>>(Wq16s, xT16, qtok);
    k3_attn<<<dim3(98, 32), 512, 131072, stream>>>(qtok, ktok, vtokT, otok16);
    k4_outproj<<<dim3(49, 4, 4), 256, 0, stream>>>(Wout16, otok16, bout, outp);
}

// Round 7
// 376.119 us; speedup vs baseline: 5.8386x; 1.3923x over previous
//
#include <hip/hip_runtime.h>

#define HEADS 8
#define DHEAD 64
#define QSCALE 0.125f   // 64^-0.5
#define DIM 256
#define IMG 112
#define HW 12544        // 112*112
#define NKV 256         // 16*16
#define INNER 512
#define KCONV 12544     // 256*49
#define KSPLIT 14
#define KCHUNK 896      // 12544/14
#define K2STEPS 28      // KCHUNK/32

typedef _Float16 half_t;
typedef _Float16 half8 __attribute__((ext_vector_type(8)));
typedef float f32x4 __attribute__((ext_vector_type(4)));

__device__ inline unsigned pk2(float a, float b) {
    union { half_t h[2]; unsigned u; } x;
    x.h[0] = (half_t)a; x.h[1] = (half_t)b;
    return x.u;
}

// ---------------- K0: im2col gather -> TRANSPOSED f16 patches Pt[b][pos][k]
__global__ __launch_bounds__(256) void k0_gather(const float* __restrict__ x,
                                                 half_t* __restrict__ Pt) {
    int gid = blockIdx.x * 256 + threadIdx.x;  // one 8-k chunk
    int bp = gid / 1568;                       // 1568 = 12544/8
    int k8 = gid - bp * 1568;
    int b = bp >> 8, pos = bp & 255;
    int oy = pos >> 4, ox = pos & 15;
    const float* xb = x + (size_t)b * DIM * HW + (size_t)(oy * 7) * IMG + ox * 7;
    int k0 = k8 * 8;
    half8 hv;
    #pragma unroll
    for (int j = 0; j < 8; ++j) {
        int k = k0 + j;
        int cch = k / 49;
        int tap = k - cch * 49;
        int kh = tap / 7;
        int kw = tap - kh * 7;
        hv[j] = (half_t)xb[(size_t)cch * HW + kh * IMG + kw];
    }
    *(half8*)&Pt[(size_t)bp * KCONV + k0] = hv;
}

// ---------------- Kcvt: f32 -> f16 with scale
__global__ __launch_bounds__(256) void k_cvt(const float* __restrict__ W,
                                             half_t* __restrict__ W16,
                                             float scale) {
    size_t i = ((size_t)blockIdx.x * 256 + threadIdx.x) * 8;
    float4 a = *(const float4*)&W[i];
    float4 b = *(const float4*)&W[i + 4];
    half8 h = { (half_t)(a.x * scale), (half_t)(a.y * scale),
                (half_t)(a.z * scale), (half_t)(a.w * scale),
                (half_t)(b.x * scale), (half_t)(b.y * scale),
                (half_t)(b.z * scale), (half_t)(b.w * scale) };
    *(half8*)&W16[i] = h;
}

// ---------------- Kx: transpose x f32 [b][c][n] -> xT16 f16 [b][n][c]
__global__ __launch_bounds__(256) void kx_t(const float* __restrict__ x,
                                            half_t* __restrict__ xT16) {
    __shared__ float tile[64 * 68];
    int t = threadIdx.x;
    int n0 = blockIdx.x * 64, c0 = blockIdx.y * 64, b = blockIdx.z;
    #pragma unroll
    for (int i = 0; i < 4; ++i) {
        int f4 = t + i * 256;
        int r = f4 >> 4, c4 = (f4 & 15) << 2;
        *(float4*)&tile[r * 68 + c4] =
            *(const float4*)&x[((size_t)(b * DIM + c0 + r)) * HW + n0 + c4];
    }
    __syncthreads();
    #pragma unroll
    for (int i = 0; i < 2; ++i) {
        int idx = t + i * 256;
        int rr = idx >> 3, cc8 = (idx & 7) << 3;
        half8 h;
        #pragma unroll
        for (int j = 0; j < 8; ++j) h[j] = (half_t)tile[(cc8 + j) * 68 + rr];
        *(half8*)&xT16[((size_t)b * HW + n0 + rr) * DIM + c0 + cc8] = h;
    }
}

// ---------------- K1: Q projection via f16 MFMA, LDS-staged B (dbuf), XCD-clustered grid
__global__ __launch_bounds__(256) void k1_qproj(const half_t* __restrict__ Wq16s,
                                                const half_t* __restrict__ xT16,
                                                half_t* __restrict__ qtok) {
    __shared__ char Bs[2][16384];   // [n 256][k 32] f16, 16B-granule swizzled
    int t = threadIdx.x;
    int w = t >> 6, l = t & 63, g = l >> 4, c = l & 15;
    // grid 1568 = 8m x 49n x 4b; cluster the 8 m-sibs of one (n0,b) on one XCD
    int bid = blockIdx.x;
    int logical = (bid & 7) * 196 + (bid >> 3);
    int h = logical & 7;
    int rest = logical >> 3;
    int n0 = (rest % 49) * 256;
    int b = rest / 49;

    const half_t* Ap = Wq16s + (size_t)(h * 64 + w * 16 + c) * DIM + g * 8;
    const half_t* Bbase = xT16 + ((size_t)b * HW + n0 + t) * DIM;  // row t
    unsigned wsw = (unsigned)((t & 3) << 4);
    half8 st[4];
    #pragma unroll
    for (int j = 0; j < 4; ++j) st[j] = *(const half8*)(Bbase + j * 8);
    {
        char* wp = Bs[0] + t * 64;
        #pragma unroll
        for (int j = 0; j < 4; ++j) *(half8*)(wp + (((unsigned)(j * 16)) ^ wsw)) = st[j];
    }
    __syncthreads();

    f32x4 sc[16];
    #pragma unroll
    for (int nt = 0; nt < 16; ++nt) sc[nt] = (f32x4){0.f, 0.f, 0.f, 0.f};

    for (int kk = 0; kk < DIM / 32; ++kk) {
        char* cur = Bs[kk & 1];
        char* nxt = Bs[(kk & 1) ^ 1];
        if (kk < DIM / 32 - 1) {
            #pragma unroll
            for (int j = 0; j < 4; ++j)
                st[j] = *(const half8*)(Bbase + (kk + 1) * 32 + j * 8);
        }
        half8 a = *(const half8*)(Ap + kk * 32);
        __builtin_amdgcn_s_setprio(1);
        #pragma unroll
        for (int nt = 0; nt < 16; ++nt) {
            int row = nt * 16 + c;
            half8 bb = *(const half8*)(cur + row * 64 +
                                       (((unsigned)(g * 16)) ^ ((unsigned)((row & 3) << 4))));
            sc[nt] = __builtin_amdgcn_mfma_f32_16x16x32_f16(a, bb, sc[nt], 0, 0, 0);
        }
        __builtin_amdgcn_s_setprio(0);
        if (kk < DIM / 32 - 1) {
            char* wp = nxt + t * 64;
            #pragma unroll
            for (int j = 0; j < 4; ++j) *(half8*)(wp + (((unsigned)(j * 16)) ^ wsw)) = st[j];
            __syncthreads();
        }
    }
    half_t* op = qtok + ((size_t)(b * HEADS + h) * HW + n0 + c) * 64 + w * 16 + g * 4;
    #pragma unroll
    for (int nt = 0; nt < 16; ++nt) {
        uint2 u = make_uint2(pk2(sc[nt][0], sc[nt][1]), pk2(sc[nt][2], sc[nt][3]));
        *(uint2*)&op[(size_t)(nt * 16) * 64] = u;
    }
}

// ---------------- K2: KV conv GEMM via f16 MFMA, split-K=14, LDS-staged B (dbuf)
__global__ __launch_bounds__(256) void k2_kv(const half_t* __restrict__ W16,
                                             const half_t* __restrict__ Pt,
                                             float* __restrict__ partial) {
    __shared__ char Bs[2][16384];   // [pos 256][k 32] f16, 16B-granule swizzled
    int t = threadIdx.x;
    int w = t >> 6, l = t & 63, g = l >> 4, c = l & 15;
    int octile = blockIdx.x;   // 0..15 (64 oc each)
    int ks = blockIdx.y;       // 0..13
    int b = blockIdx.z;
    const half_t* Ap = W16 + (size_t)(octile * 64 + w * 16 + c) * KCONV + ks * KCHUNK + g * 8;
    const half_t* Bbase = Pt + ((size_t)b * 256 + t) * KCONV + ks * KCHUNK;  // row t

    unsigned wsw = (unsigned)((t & 3) << 4);
    half8 st[4];
    #pragma unroll
    for (int j = 0; j < 4; ++j) st[j] = *(const half8*)(Bbase + j * 8);
    {
        char* wp = Bs[0] + t * 64;
        #pragma unroll
        for (int j = 0; j < 4; ++j) *(half8*)(wp + (((unsigned)(j * 16)) ^ wsw)) = st[j];
    }
    __syncthreads();

    f32x4 sc[16];
    #pragma unroll
    for (int nt = 0; nt < 16; ++nt) sc[nt] = (f32x4){0.f, 0.f, 0.f, 0.f};

    for (int kk = 0; kk < K2STEPS; ++kk) {
        char* cur = Bs[kk & 1];
        char* nxt = Bs[(kk & 1) ^ 1];
        if (kk < K2STEPS - 1) {
            #pragma unroll
            for (int j = 0; j < 4; ++j)
                st[j] = *(const half8*)(Bbase + (kk + 1) * 32 + j * 8);
        }
        half8 a = *(const half8*)(Ap + kk * 32);
        __builtin_amdgcn_s_setprio(1);
        #pragma unroll
        for (int nt = 0; nt < 16; ++nt) {
            int row = nt * 16 + c;
            half8 bb = *(const half8*)(cur + row * 64 +
                                       (((unsigned)(g * 16)) ^ ((unsigned)((row & 3) << 4))));
            sc[nt] = __builtin_amdgcn_mfma_f32_16x16x32_f16(a, bb, sc[nt], 0, 0, 0);
        }
        __builtin_amdgcn_s_setprio(0);
        if (kk < K2STEPS - 1) {
            char* wp = nxt + t * 64;
            #pragma unroll
            for (int j = 0; j < 4; ++j) *(half8*)(wp + (((unsigned)(j * 16)) ^ wsw)) = st[j];
            __syncthreads();
        }
    }
    float* op = partial + ((size_t)(ks * 4 + b) * 1024 + octile * 64 + w * 16) * 256;
    #pragma unroll
    for (int nt = 0; nt < 16; ++nt)
        #pragma unroll
        for (int r = 0; r < 4; ++r)
            op[(g * 4 + r) * 256 + nt * 16 + c] = sc[nt][r];
}

// ---------------- K2r: reduce partials -> ktok f16 [bh][kv][d], vtokT f16 [bh][d][kv]
// partial slice index is (ks*4 + b): per-ks stride = 4*1024*256 = 1,048,576 floats.
__global__ __launch_bounds__(256) void k2r(const float* __restrict__ partial,
                                           half_t* __restrict__ ktok,
                                           half_t* __restrict__ vtokT) {
    int pos = threadIdx.x;
    int oc0 = blockIdx.x * 8;
    int b = blockIdx.y;
    float v[8];
    #pragma unroll
    for (int j = 0; j < 8; ++j) {
        const float* src = partial + ((size_t)b * 1024 + oc0 + j) * 256 + pos;
        float s = 0.f;
        #pragma unroll
        for (int ksb = 0; ksb < KSPLIT; ++ksb) s += src[(size_t)ksb * 1048576];
        v[j] = s;
    }
    int h = (oc0 >> 6) & 7, d0 = oc0 & 63;
    if (oc0 < 512) {
        uint4 u = make_uint4(pk2(v[0], v[1]), pk2(v[2], v[3]),
                             pk2(v[4], v[5]), pk2(v[6], v[7]));
        *(uint4*)&ktok[((size_t)(b * HEADS + h) * NKV + pos) * 64 + d0] = u;
    } else {
        #pragma unroll
        for (int j = 0; j < 8; ++j)
            vtokT[((size_t)(b * HEADS + h) * 64 + d0 + j) * NKV + pos] = (half_t)v[j];
    }
}

// ---------------- K3: fused attention, f16 MFMA. Block = 8 waves = 128 q rows.
// K (32KB) + V^T (32KB) staged in swizzled LDS once per block; S 64KB; total 128KB.
__global__ __launch_bounds__(512) void k3_attn(const half_t* __restrict__ qtok,
                                               const half_t* __restrict__ ktok,
                                               const half_t* __restrict__ vtokT,
                                               half_t* __restrict__ otok16) {
    extern __shared__ char lds[];
    char* K_lds = lds;                         // byte(kv,·) = kv*128 + (off ^ ((kv&7)<<4))
    char* V_lds = lds + 32768;                 // byte(d,·)  = d*512  + (off ^ ((d&7)<<4))
    unsigned* Sl = (unsigned*)(lds + 65536);   // 128 rows x 512B, existing swizzle
    int t = threadIdx.x;
    int w = t >> 6, l = t & 63, g = l >> 4, c = l & 15;
    int q0 = blockIdx.x * 128;
    int bh = blockIdx.y;

    // Q A-frags (global, issued before staging barrier)
    const half_t* qp = qtok + ((size_t)bh * HW + q0 + w * 16 + c) * 64 + g * 8;
    half8 aq0 = *(const half8*)(qp);
    half8 aq1 = *(const half8*)(qp + 32);

    // stage K: thread t covers kv = t>>1, 32 halfs at (t&1)*32
    {
        int kv = t >> 1;
        const half_t* kg = ktok + (size_t)bh * NKV * 64 + (size_t)kv * 64 + (t & 1) * 32;
        char* wp = K_lds + kv * 128;
        unsigned sw = (unsigned)((kv & 7) << 4);
        unsigned base = (unsigned)((t & 1) * 64);
        #pragma unroll
        for (int j = 0; j < 4; ++j)
            *(half8*)(wp + ((base + j * 16) ^ sw)) = *(const half8*)(kg + j * 8);
    }
    // stage V^T: thread t covers d = t>>3, 32 halfs at (t&7)*32
    {
        int d = t >> 3;
        const half_t* vg = vtokT + (size_t)bh * 64 * NKV + (size_t)d * NKV + (t & 7) * 32;
        char* wp = V_lds + d * 512;
        unsigned sw = (unsigned)((d & 7) << 4);
        unsigned base = (unsigned)((t & 7) * 64);
        #pragma unroll
        for (int j = 0; j < 4; ++j)
            *(half8*)(wp + ((base + j * 16) ^ sw)) = *(const half8*)(vg + j * 8);
    }
    __syncthreads();

    // dots from K_lds
    f32x4 sc[16];
    __builtin_amdgcn_s_setprio(1);
    #pragma unroll
    for (int nt = 0; nt < 16; ++nt) {
        int row = nt * 16 + c;
        const char* kp = K_lds + row * 128;
        unsigned sw = (unsigned)((row & 7) << 4);
        half8 b0 = *(const half8*)(kp + (((unsigned)(g * 16)) ^ sw));
        half8 b1 = *(const half8*)(kp + (((unsigned)(g * 16 + 64)) ^ sw));
        f32x4 acc = (f32x4){0.f, 0.f, 0.f, 0.f};
        acc = __builtin_amdgcn_mfma_f32_16x16x32_f16(aq0, b0, acc, 0, 0, 0);
        acc = __builtin_amdgcn_mfma_f32_16x16x32_f16(aq1, b1, acc, 0, 0, 0);
        sc[nt] = acc;
    }
    __builtin_amdgcn_s_setprio(0);

    // softmax: lane holds rows w*16+g*4+r, col nt*16+c
    #pragma unroll
    for (int r = 0; r < 4; ++r) {
        float m = sc[0][r];
        #pragma unroll
        for (int nt = 1; nt < 16; ++nt) m = fmaxf(m, sc[nt][r]);
        m = fmaxf(m, __shfl_xor(m, 1));
        m = fmaxf(m, __shfl_xor(m, 2));
        m = fmaxf(m, __shfl_xor(m, 4));
        m = fmaxf(m, __shfl_xor(m, 8));
        float s = 0.f;
        #pragma unroll
        for (int nt = 0; nt < 16; ++nt) {
            float e = __expf(sc[nt][r] - m);
            sc[nt][r] = e;
            s += e;
        }
        s += __shfl_xor(s, 1);
        s += __shfl_xor(s, 2);
        s += __shfl_xor(s, 4);
        s += __shfl_xor(s, 8);
        float inv = 1.f / s;
        #pragma unroll
        for (int nt = 0; nt < 16; ++nt) sc[nt][r] *= inv;
    }

    // pack f16 pairs (cols c^1 via shfl) -> swizzled S rows (wave-private)
    int odd = l & 1;
    #pragma unroll
    for (int r = 0; r < 4; ++r) {
        int row = w * 16 + g * 4 + r;
        unsigned swz = (unsigned)((row & 7) << 4);
        int mine = (odd == (r >> 1));
        #pragma unroll
        for (int nt = 0; nt < 16; ++nt) {
            float v = sc[nt][r];
            float p = __shfl_xor(v, 1);
            if (mine) {
                unsigned u = odd ? pk2(p, v) : pk2(v, p);
                int pi = nt * 8 + (c >> 1);
                Sl[(row * 512 + (((unsigned)(pi * 4)) ^ swz)) >> 2] = u;
            }
        }
    }
    // S write->read is wave-private: wave-local wait, no block barrier
    asm volatile("s_waitcnt lgkmcnt(0)" ::: "memory");
    __builtin_amdgcn_sched_barrier(0);

    // PV: A = S rows (LDS), B = V from V_lds
    f32x4 o[4];
    #pragma unroll
    for (int nt = 0; nt < 4; ++nt) o[nt] = (f32x4){0.f, 0.f, 0.f, 0.f};
    int arow = w * 16 + c;
    unsigned aswz = (unsigned)((arow & 7) << 4);
    __builtin_amdgcn_s_setprio(1);
    #pragma unroll
    for (int ks = 0; ks < 8; ++ks) {
        half8 as = *(const half8*)((const char*)Sl + arow * 512 +
                                   (((unsigned)(ks * 64 + g * 16)) ^ aswz));
        #pragma unroll
        for (int nt = 0; nt < 4; ++nt) {
            int d = nt * 16 + c;
            half8 bv = *(const half8*)(V_lds + d * 512 +
                                       (((unsigned)(ks * 64 + g * 16)) ^ ((unsigned)((d & 7) << 4))));
            o[nt] = __builtin_amdgcn_mfma_f32_16x16x32_f16(as, bv, o[nt], 0, 0, 0);
        }
    }
    __builtin_amdgcn_s_setprio(0);
    // store f16: n = q0 + w*16 + g*4 + r, k = h*64 + nt*16 + c
    int b = bh >> 3, h = bh & 7;
    half_t* op = otok16 + ((size_t)b * HW + q0 + w * 16) * INNER + h * 64;
    #pragma unroll
    for (int nt = 0; nt < 4; ++nt)
        #pragma unroll
        for (int r = 0; r < 4; ++r)
            op[(size_t)(g * 4 + r) * INNER + nt * 16 + c] = (half_t)o[nt][r];
}

// ---------------- K4: output projection via f16 MFMA + bias, LDS-staged B (dbuf)
__global__ __launch_bounds__(256) void k4_outproj(const half_t* __restrict__ Wout16,
                                                  const half_t* __restrict__ otok16,
                                                  const float* __restrict__ bout,
                                                  float* __restrict__ outp) {
    __shared__ char Bs[2][16384];   // [n 256][k 32] f16, 16B-granule swizzled
    int t = threadIdx.x;
    int w = t >> 6, l = t & 63, g = l >> 4, c = l & 15;
    // grid 784 = 4m x 49n x 4b; cluster the 4 m-sibs of one (n0,b) on one XCD
    int bid = blockIdx.x;
    int logical = (bid & 7) * 98 + (bid >> 3);
    int m0 = (logical & 3) * 64;
    int rest = logical >> 2;
    int n0 = (rest % 49) * 256;
    int b = rest / 49;

    const half_t* Ap = Wout16 + (size_t)(m0 + w * 16 + c) * INNER + g * 8;
    const half_t* Bbase = otok16 + ((size_t)b * HW + n0 + t) * INNER;  // row t
    unsigned wsw = (unsigned)((t & 3) << 4);
    half8 st[4];
    #pragma unroll
    for (int j = 0; j < 4; ++j) st[j] = *(const half8*)(Bbase + j * 8);
    {
        char* wp = Bs[0] + t * 64;
        #pragma unroll
        for (int j = 0; j < 4; ++j) *(half8*)(wp + (((unsigned)(j * 16)) ^ wsw)) = st[j];
    }
    __syncthreads();

    f32x4 sc[16];
    #pragma unroll
    for (int nt = 0; nt < 16; ++nt) sc[nt] = (f32x4){0.f, 0.f, 0.f, 0.f};

    for (int kk = 0; kk < INNER / 32; ++kk) {
        char* cur = Bs[kk & 1];
        char* nxt = Bs[(kk & 1) ^ 1];
        if (kk < INNER / 32 - 1) {
            #pragma unroll
            for (int j = 0; j < 4; ++j)
                st[j] = *(const half8*)(Bbase + (kk + 1) * 32 + j * 8);
        }
        half8 a = *(const half8*)(Ap + kk * 32);
        __builtin_amdgcn_s_setprio(1);
        #pragma unroll
        for (int nt = 0; nt < 16; ++nt) {
            int row = nt * 16 + c;
            half8 bb = *(const half8*)(cur + row * 64 +
                                       (((unsigned)(g * 16)) ^ ((unsigned)((row & 3) << 4))));
            sc[nt] = __builtin_amdgcn_mfma_f32_16x16x32_f16(a, bb, sc[nt], 0, 0, 0);
        }
        __builtin_amdgcn_s_setprio(0);
        if (kk < INNER / 32 - 1) {
            char* wp = nxt + t * 64;
            #pragma unroll
            for (int j = 0; j < 4; ++j) *(half8*)(wp + (((unsigned)(j * 16)) ^ wsw)) = st[j];
            __syncthreads();
        }
    }
    int ocb = m0 + w * 16 + g * 4;
    float b0 = bout[ocb], b1 = bout[ocb + 1], b2 = bout[ocb + 2], b3 = bout[ocb + 3];
    float* op = outp + ((size_t)b * DIM + ocb) * HW + n0 + c;
    #pragma unroll
    for (int nt = 0; nt < 16; ++nt) {
        op[(size_t)0 * HW + nt * 16] = sc[nt][0] + b0;
        op[(size_t)1 * HW + nt * 16] = sc[nt][1] + b1;
        op[(size_t)2 * HW + nt * 16] = sc[nt][2] + b2;
        op[(size_t)3 * HW + nt * 16] = sc[nt][3] + b3;
    }
}

extern "C" void kernel_launch(void* const* d_in, const int* in_sizes, int n_in,
                              void* d_out, int out_size, void* d_ws, size_t ws_size,
                              hipStream_t stream) {
    (void)in_sizes; (void)n_in; (void)out_size; (void)ws_size;
    const float* x = (const float*)d_in[0];
    const float* Wq = (const float*)d_in[1];
    const float* Wkv = (const float*)d_in[2];
    const float* Wout = (const float*)d_in[3];
    const float* bout = (const float*)d_in[4];
    float* outp = (float*)d_out;

    // Workspace layout (f32 units, total 47,448,064 = 189.8 MB; 209.7 MB known-safe):
    //   partial f32 [0, 14,680,064)                   (56 slices, dead after k2r)
    //   ktok   f16  [14,680,064, 14,942,208)
    //   vtokT  f16  [14,942,208, 15,204,352)
    //   Wq16s  f16  [15,204,352, 15,269,888)          (QSCALE folded)
    //   Wout16 f16  [15,269,888, 15,335,424)
    //   Wkv16  f16  [15,335,424, 21,757,952)          (dead after k2)
    //   Pt     f16  [21,757,952, 28,180,480)          (dead after k2)
    //   otok16 f16  [15,335,424, 28,180,480)          (overlays Wkv16+Pt, written by k3)
    //   xT16   f16  [28,180,480, 34,603,008)          (dead after k1)
    //   qtok   f16  [34,603,008, 47,448,064)
    float* ws = (float*)d_ws;
    float*  partial = ws;
    half_t* ktok    = (half_t*)(ws + 14680064);
    half_t* vtokT   = (half_t*)(ws + 14942208);
    half_t* Wq16s   = (half_t*)(ws + 15204352);
    half_t* Wout16  = (half_t*)(ws + 15269888);
    half_t* Wkv16   = (half_t*)(ws + 15335424);
    half_t* Pt      = (half_t*)(ws + 21757952);
    half_t* otok16  = (half_t*)(ws + 15335424);
    half_t* xT16    = (half_t*)(ws + 28180480);
    half_t* qtok    = (half_t*)(ws + 34603008);

    hipFuncSetAttribute((const void*)k3_attn,
                        hipFuncAttributeMaxDynamicSharedMemorySize, 131072);

    k_cvt<<<dim3(6272), 256, 0, stream>>>(Wkv, Wkv16, 1.0f);
    k_cvt<<<dim3(64), 256, 0, stream>>>(Wq, Wq16s, QSCALE);
    k_cvt<<<dim3(64), 256, 0, stream>>>(Wout, Wout16, 1.0f);
    kx_t<<<dim3(196, 4, 4), 256, 0, stream>>>(x, xT16);
    k0_gather<<<dim3(6272), 256, 0, stream>>>(x, Pt);
    k2_kv<<<dim3(16, KSPLIT, 4), 256, 0, stream>>>(Wkv16, Pt, partial);
    k2r<<<dim3(128, 4), 256, 0, stream>>>(partial, ktok, vtokT);
    k1_qproj<<<dim3(1568), 256, 0, stream>>>(Wq16s, xT16, qtok);
    k3_attn<<<dim3(98, 32), 512, 131072, stream>>>(qtok, ktok, vtokT, otok16);
    k4_outproj<<<dim3(784), 256, 0, stream>>>(Wout16, otok16, bout, outp);
}

// Round 8
// 306.145 us; speedup vs baseline: 7.1731x; 1.2286x over previous
//
#include <hip/hip_runtime.h>

#define HEADS 8
#define DHEAD 64
#define QSCALE 0.125f   // 64^-0.5
#define DIM 256
#define IMG 112
#define HW 12544        // 112*112
#define NKV 256         // 16*16
#define INNER 512
#define KCONV 12544     // 256*49
#define KSPLIT 14
#define KCHUNK 896      // 12544/14
#define K2STEPS 28      // KCHUNK/32

typedef _Float16 half_t;
typedef _Float16 half8 __attribute__((ext_vector_type(8)));
typedef float f32x4 __attribute__((ext_vector_type(4)));

__device__ inline unsigned pk2(float a, float b) {
    union { half_t h[2]; unsigned u; } x;
    x.h[0] = (half_t)a; x.h[1] = (half_t)b;
    return x.u;
}

// ---------------- K0: im2col gather -> TRANSPOSED f16 patches Pt[b][pos][k]
__global__ __launch_bounds__(256) void k0_gather(const float* __restrict__ x,
                                                 half_t* __restrict__ Pt) {
    int gid = blockIdx.x * 256 + threadIdx.x;  // one 8-k chunk
    int bp = gid / 1568;                       // 1568 = 12544/8
    int k8 = gid - bp * 1568;
    int b = bp >> 8, pos = bp & 255;
    int oy = pos >> 4, ox = pos & 15;
    const float* xb = x + (size_t)b * DIM * HW + (size_t)(oy * 7) * IMG + ox * 7;
    int k0 = k8 * 8;
    half8 hv;
    #pragma unroll
    for (int j = 0; j < 8; ++j) {
        int k = k0 + j;
        int cch = k / 49;
        int tap = k - cch * 49;
        int kh = tap / 7;
        int kw = tap - kh * 7;
        hv[j] = (half_t)xb[(size_t)cch * HW + kh * IMG + kw];
    }
    *(half8*)&Pt[(size_t)bp * KCONV + k0] = hv;
}

// ---------------- Kcvt: f32 -> f16 with scale
__global__ __launch_bounds__(256) void k_cvt(const float* __restrict__ W,
                                             half_t* __restrict__ W16,
                                             float scale) {
    size_t i = ((size_t)blockIdx.x * 256 + threadIdx.x) * 8;
    float4 a = *(const float4*)&W[i];
    float4 b = *(const float4*)&W[i + 4];
    half8 h = { (half_t)(a.x * scale), (half_t)(a.y * scale),
                (half_t)(a.z * scale), (half_t)(a.w * scale),
                (half_t)(b.x * scale), (half_t)(b.y * scale),
                (half_t)(b.z * scale), (half_t)(b.w * scale) };
    *(half8*)&W16[i] = h;
}

// ---------------- Kx: transpose x f32 [b][c][n] -> xT16 f16 [b][n][c]
__global__ __launch_bounds__(256) void kx_t(const float* __restrict__ x,
                                            half_t* __restrict__ xT16) {
    __shared__ float tile[64 * 68];
    int t = threadIdx.x;
    int n0 = blockIdx.x * 64, c0 = blockIdx.y * 64, b = blockIdx.z;
    #pragma unroll
    for (int i = 0; i < 4; ++i) {
        int f4 = t + i * 256;
        int r = f4 >> 4, c4 = (f4 & 15) << 2;
        *(float4*)&tile[r * 68 + c4] =
            *(const float4*)&x[((size_t)(b * DIM + c0 + r)) * HW + n0 + c4];
    }
    __syncthreads();
    #pragma unroll
    for (int i = 0; i < 2; ++i) {
        int idx = t + i * 256;
        int rr = idx >> 3, cc8 = (idx & 7) << 3;
        half8 h;
        #pragma unroll
        for (int j = 0; j < 8; ++j) h[j] = (half_t)tile[(cc8 + j) * 68 + rr];
        *(half8*)&xT16[((size_t)b * HW + n0 + rr) * DIM + c0 + cc8] = h;
    }
}

// ---------------- K1: Q projection via f16 MFMA, LDS-staged B (dbuf), XCD-clustered grid
__global__ __launch_bounds__(256) void k1_qproj(const half_t* __restrict__ Wq16s,
                                                const half_t* __restrict__ xT16,
                                                half_t* __restrict__ qtok) {
    __shared__ char Bs[2][16384];   // [n 256][k 32] f16, 16B-granule swizzled
    int t = threadIdx.x;
    int w = t >> 6, l = t & 63, g = l >> 4, c = l & 15;
    int bid = blockIdx.x;
    int logical = (bid & 7) * 196 + (bid >> 3);
    int h = logical & 7;
    int rest = logical >> 3;
    int n0 = (rest % 49) * 256;
    int b = rest / 49;

    const half_t* Ap = Wq16s + (size_t)(h * 64 + w * 16 + c) * DIM + g * 8;
    const half_t* Bbase = xT16 + ((size_t)b * HW + n0 + t) * DIM;  // row t
    unsigned wsw = (unsigned)((t & 3) << 4);
    half8 st[4];
    #pragma unroll
    for (int j = 0; j < 4; ++j) st[j] = *(const half8*)(Bbase + j * 8);
    {
        char* wp = Bs[0] + t * 64;
        #pragma unroll
        for (int j = 0; j < 4; ++j) *(half8*)(wp + (((unsigned)(j * 16)) ^ wsw)) = st[j];
    }
    __syncthreads();

    f32x4 sc[16];
    #pragma unroll
    for (int nt = 0; nt < 16; ++nt) sc[nt] = (f32x4){0.f, 0.f, 0.f, 0.f};

    for (int kk = 0; kk < DIM / 32; ++kk) {
        char* cur = Bs[kk & 1];
        char* nxt = Bs[(kk & 1) ^ 1];
        if (kk < DIM / 32 - 1) {
            #pragma unroll
            for (int j = 0; j < 4; ++j)
                st[j] = *(const half8*)(Bbase + (kk + 1) * 32 + j * 8);
        }
        half8 a = *(const half8*)(Ap + kk * 32);
        __builtin_amdgcn_s_setprio(1);
        #pragma unroll
        for (int nt = 0; nt < 16; ++nt) {
            int row = nt * 16 + c;
            half8 bb = *(const half8*)(cur + row * 64 +
                                       (((unsigned)(g * 16)) ^ ((unsigned)((row & 3) << 4))));
            sc[nt] = __builtin_amdgcn_mfma_f32_16x16x32_f16(a, bb, sc[nt], 0, 0, 0);
        }
        __builtin_amdgcn_s_setprio(0);
        if (kk < DIM / 32 - 1) {
            char* wp = nxt + t * 64;
            #pragma unroll
            for (int j = 0; j < 4; ++j) *(half8*)(wp + (((unsigned)(j * 16)) ^ wsw)) = st[j];
            __syncthreads();
        }
    }
    half_t* op = qtok + ((size_t)(b * HEADS + h) * HW + n0 + c) * 64 + w * 16 + g * 4;
    #pragma unroll
    for (int nt = 0; nt < 16; ++nt) {
        uint2 u = make_uint2(pk2(sc[nt][0], sc[nt][1]), pk2(sc[nt][2], sc[nt][3]));
        *(uint2*)&op[(size_t)(nt * 16) * 64] = u;
    }
}

// ---------------- K2: KV conv GEMM via f16 MFMA, split-K=14, LDS-staged B (dbuf)
__global__ __launch_bounds__(256) void k2_kv(const half_t* __restrict__ W16,
                                             const half_t* __restrict__ Pt,
                                             float* __restrict__ partial) {
    __shared__ char Bs[2][16384];   // [pos 256][k 32] f16, 16B-granule swizzled
    int t = threadIdx.x;
    int w = t >> 6, l = t & 63, g = l >> 4, c = l & 15;
    int octile = blockIdx.x;   // 0..15 (64 oc each)
    int ks = blockIdx.y;       // 0..13
    int b = blockIdx.z;
    const half_t* Ap = W16 + (size_t)(octile * 64 + w * 16 + c) * KCONV + ks * KCHUNK + g * 8;
    const half_t* Bbase = Pt + ((size_t)b * 256 + t) * KCONV + ks * KCHUNK;  // row t

    unsigned wsw = (unsigned)((t & 3) << 4);
    half8 st[4];
    #pragma unroll
    for (int j = 0; j < 4; ++j) st[j] = *(const half8*)(Bbase + j * 8);
    {
        char* wp = Bs[0] + t * 64;
        #pragma unroll
        for (int j = 0; j < 4; ++j) *(half8*)(wp + (((unsigned)(j * 16)) ^ wsw)) = st[j];
    }
    __syncthreads();

    f32x4 sc[16];
    #pragma unroll
    for (int nt = 0; nt < 16; ++nt) sc[nt] = (f32x4){0.f, 0.f, 0.f, 0.f};

    for (int kk = 0; kk < K2STEPS; ++kk) {
        char* cur = Bs[kk & 1];
        char* nxt = Bs[(kk & 1) ^ 1];
        if (kk < K2STEPS - 1) {
            #pragma unroll
            for (int j = 0; j < 4; ++j)
                st[j] = *(const half8*)(Bbase + (kk + 1) * 32 + j * 8);
        }
        half8 a = *(const half8*)(Ap + kk * 32);
        __builtin_amdgcn_s_setprio(1);
        #pragma unroll
        for (int nt = 0; nt < 16; ++nt) {
            int row = nt * 16 + c;
            half8 bb = *(const half8*)(cur + row * 64 +
                                       (((unsigned)(g * 16)) ^ ((unsigned)((row & 3) << 4))));
            sc[nt] = __builtin_amdgcn_mfma_f32_16x16x32_f16(a, bb, sc[nt], 0, 0, 0);
        }
        __builtin_amdgcn_s_setprio(0);
        if (kk < K2STEPS - 1) {
            char* wp = nxt + t * 64;
            #pragma unroll
            for (int j = 0; j < 4; ++j) *(half8*)(wp + (((unsigned)(j * 16)) ^ wsw)) = st[j];
            __syncthreads();
        }
    }
    float* op = partial + ((size_t)(ks * 4 + b) * 1024 + octile * 64 + w * 16) * 256;
    #pragma unroll
    for (int nt = 0; nt < 16; ++nt)
        #pragma unroll
        for (int r = 0; r < 4; ++r)
            op[(g * 4 + r) * 256 + nt * 16 + c] = sc[nt][r];
}

// ---------------- K2r: reduce partials -> ktok f16 [bh][kv][d], vtokT f16 [bh][d][kv']
// V columns written PERMUTED for k3's zero-shuffle PV:
//   kv = 32a+16b+4g+r  ->  k' = 32a+8g+4b+r
__global__ __launch_bounds__(256) void k2r(const float* __restrict__ partial,
                                           half_t* __restrict__ ktok,
                                           half_t* __restrict__ vtokT) {
    int pos = threadIdx.x;
    int oc0 = blockIdx.x * 8;
    int b = blockIdx.y;
    float v[8];
    #pragma unroll
    for (int j = 0; j < 8; ++j) {
        const float* src = partial + ((size_t)b * 1024 + oc0 + j) * 256 + pos;
        float s = 0.f;
        #pragma unroll
        for (int ksb = 0; ksb < KSPLIT; ++ksb) s += src[(size_t)ksb * 1048576];
        v[j] = s;
    }
    int h = (oc0 >> 6) & 7, d0 = oc0 & 63;
    if (oc0 < 512) {
        uint4 u = make_uint4(pk2(v[0], v[1]), pk2(v[2], v[3]),
                             pk2(v[4], v[5]), pk2(v[6], v[7]));
        *(uint4*)&ktok[((size_t)(b * HEADS + h) * NKV + pos) * 64 + d0] = u;
    } else {
        int posP = (pos & ~31) | (((pos >> 2) & 3) << 3) | (((pos >> 4) & 1) << 2) | (pos & 3);
        #pragma unroll
        for (int j = 0; j < 8; ++j)
            vtokT[((size_t)(b * HEADS + h) * 64 + d0 + j) * NKV + posP] = (half_t)v[j];
    }
}

// ---------------- K3: fused attention, swapped QK^T -> lane-local softmax, register PV.
// LDS: K (32KB) + permuted V^T (32KB) = 64KB -> 2 blocks/CU. No S buffer, no 2nd barrier.
__global__ __launch_bounds__(512) void k3_attn(const half_t* __restrict__ qtok,
                                               const half_t* __restrict__ ktok,
                                               const half_t* __restrict__ vtokT,
                                               half_t* __restrict__ otok16) {
    extern __shared__ char lds[];
    char* K_lds = lds;                         // byte(kv,·) = kv*128 + (off ^ ((kv&7)<<4))
    char* V_lds = lds + 32768;                 // byte(d,·)  = d*512  + (off ^ ((d&7)<<4))
    int t = threadIdx.x;
    int w = t >> 6, l = t & 63, g = l >> 4, c = l & 15;
    int q0 = blockIdx.x * 128;
    int bh = blockIdx.y;

    // Q fragments (B-operand of swapped QK^T): lane (c,g) holds Q[q=c][d=g*8+j]
    const half_t* qp = qtok + ((size_t)bh * HW + q0 + w * 16 + c) * 64 + g * 8;
    half8 bq0 = *(const half8*)(qp);
    half8 bq1 = *(const half8*)(qp + 32);

    // stage K: thread t covers kv = t>>1, 32 halfs at (t&1)*32
    {
        int kv = t >> 1;
        const half_t* kg = ktok + (size_t)bh * NKV * 64 + (size_t)kv * 64 + (t & 1) * 32;
        char* wp = K_lds + kv * 128;
        unsigned sw = (unsigned)((kv & 7) << 4);
        unsigned base = (unsigned)((t & 1) * 64);
        #pragma unroll
        for (int j = 0; j < 4; ++j)
            *(half8*)(wp + ((base + j * 16) ^ sw)) = *(const half8*)(kg + j * 8);
    }
    // stage V^T (already column-permuted by k2r): thread t covers d = t>>3
    {
        int d = t >> 3;
        const half_t* vg = vtokT + (size_t)bh * 64 * NKV + (size_t)d * NKV + (t & 7) * 32;
        char* wp = V_lds + d * 512;
        unsigned sw = (unsigned)((d & 7) << 4);
        unsigned base = (unsigned)((t & 7) * 64);
        #pragma unroll
        for (int j = 0; j < 4; ++j)
            *(half8*)(wp + ((base + j * 16) ^ sw)) = *(const half8*)(vg + j * 8);
    }
    __syncthreads();

    // swapped dots: sc[nt] = mfma(K_frag, Q_frag) -> lane holds S[q=c][kv=16nt+4g+r]
    f32x4 sc[16];
    __builtin_amdgcn_s_setprio(1);
    #pragma unroll
    for (int nt = 0; nt < 16; ++nt) {
        int row = nt * 16 + c;
        const char* kp = K_lds + row * 128;
        unsigned sw = (unsigned)((row & 7) << 4);
        half8 a0 = *(const half8*)(kp + (((unsigned)(g * 16)) ^ sw));
        half8 a1 = *(const half8*)(kp + (((unsigned)(g * 16 + 64)) ^ sw));
        f32x4 acc = (f32x4){0.f, 0.f, 0.f, 0.f};
        acc = __builtin_amdgcn_mfma_f32_16x16x32_f16(a0, bq0, acc, 0, 0, 0);
        acc = __builtin_amdgcn_mfma_f32_16x16x32_f16(a1, bq1, acc, 0, 0, 0);
        sc[nt] = acc;
    }
    __builtin_amdgcn_s_setprio(0);

    // softmax: in-lane over 64 values + 2 shfls (lanes c,c+16,c+32,c+48 share row q=c)
    float m = sc[0][0];
    #pragma unroll
    for (int nt = 0; nt < 16; ++nt)
        #pragma unroll
        for (int r = 0; r < 4; ++r) m = fmaxf(m, sc[nt][r]);
    m = fmaxf(m, __shfl_xor(m, 16));
    m = fmaxf(m, __shfl_xor(m, 32));
    float s = 0.f;
    #pragma unroll
    for (int nt = 0; nt < 16; ++nt)
        #pragma unroll
        for (int r = 0; r < 4; ++r) {
            float e = __expf(sc[nt][r] - m);
            sc[nt][r] = e;
            s += e;
        }
    s += __shfl_xor(s, 16);
    s += __shfl_xor(s, 32);
    float inv = 1.f / s;

    // PV: P packs in-lane into A-frags (kv order matches permuted V rows)
    f32x4 o[4];
    #pragma unroll
    for (int nt = 0; nt < 4; ++nt) o[nt] = (f32x4){0.f, 0.f, 0.f, 0.f};
    __builtin_amdgcn_s_setprio(1);
    #pragma unroll
    for (int ks = 0; ks < 8; ++ks) {
        union { unsigned u[4]; half8 h; } ap;
        ap.u[0] = pk2(sc[2 * ks][0] * inv, sc[2 * ks][1] * inv);
        ap.u[1] = pk2(sc[2 * ks][2] * inv, sc[2 * ks][3] * inv);
        ap.u[2] = pk2(sc[2 * ks + 1][0] * inv, sc[2 * ks + 1][1] * inv);
        ap.u[3] = pk2(sc[2 * ks + 1][2] * inv, sc[2 * ks + 1][3] * inv);
        #pragma unroll
        for (int nt = 0; nt < 4; ++nt) {
            int d = nt * 16 + c;
            half8 bv = *(const half8*)(V_lds + d * 512 +
                                       (((unsigned)(ks * 64 + g * 16)) ^ ((unsigned)((d & 7) << 4))));
            o[nt] = __builtin_amdgcn_mfma_f32_16x16x32_f16(ap.h, bv, o[nt], 0, 0, 0);
        }
    }
    __builtin_amdgcn_s_setprio(0);
    // store f16: n = q0 + w*16 + g*4 + r, k = h*64 + nt*16 + c
    int b = bh >> 3, h = bh & 7;
    half_t* op = otok16 + ((size_t)b * HW + q0 + w * 16) * INNER + h * 64;
    #pragma unroll
    for (int nt = 0; nt < 4; ++nt)
        #pragma unroll
        for (int r = 0; r < 4; ++r)
            op[(size_t)(g * 4 + r) * INNER + nt * 16 + c] = (half_t)o[nt][r];
}

// ---------------- K4: output projection via f16 MFMA + bias, LDS-staged B (dbuf)
__global__ __launch_bounds__(256) void k4_outproj(const half_t* __restrict__ Wout16,
                                                  const half_t* __restrict__ otok16,
                                                  const float* __restrict__ bout,
                                                  float* __restrict__ outp) {
    __shared__ char Bs[2][16384];   // [n 256][k 32] f16, 16B-granule swizzled
    int t = threadIdx.x;
    int w = t >> 6, l = t & 63, g = l >> 4, c = l & 15;
    int bid = blockIdx.x;
    int logical = (bid & 7) * 98 + (bid >> 3);
    int m0 = (logical & 3) * 64;
    int rest = logical >> 2;
    int n0 = (rest % 49) * 256;
    int b = rest / 49;

    const half_t* Ap = Wout16 + (size_t)(m0 + w * 16 + c) * INNER + g * 8;
    const half_t* Bbase = otok16 + ((size_t)b * HW + n0 + t) * INNER;  // row t
    unsigned wsw = (unsigned)((t & 3) << 4);
    half8 st[4];
    #pragma unroll
    for (int j = 0; j < 4; ++j) st[j] = *(const half8*)(Bbase + j * 8);
    {
        char* wp = Bs[0] + t * 64;
        #pragma unroll
        for (int j = 0; j < 4; ++j) *(half8*)(wp + (((unsigned)(j * 16)) ^ wsw)) = st[j];
    }
    __syncthreads();

    f32x4 sc[16];
    #pragma unroll
    for (int nt = 0; nt < 16; ++nt) sc[nt] = (f32x4){0.f, 0.f, 0.f, 0.f};

    for (int kk = 0; kk < INNER / 32; ++kk) {
        char* cur = Bs[kk & 1];
        char* nxt = Bs[(kk & 1) ^ 1];
        if (kk < INNER / 32 - 1) {
            #pragma unroll
            for (int j = 0; j < 4; ++j)
                st[j] = *(const half8*)(Bbase + (kk + 1) * 32 + j * 8);
        }
        half8 a = *(const half8*)(Ap + kk * 32);
        __builtin_amdgcn_s_setprio(1);
        #pragma unroll
        for (int nt = 0; nt < 16; ++nt) {
            int row = nt * 16 + c;
            half8 bb = *(const half8*)(cur + row * 64 +
                                       (((unsigned)(g * 16)) ^ ((unsigned)((row & 3) << 4))));
            sc[nt] = __builtin_amdgcn_mfma_f32_16x16x32_f16(a, bb, sc[nt], 0, 0, 0);
        }
        __builtin_amdgcn_s_setprio(0);
        if (kk < INNER / 32 - 1) {
            char* wp = nxt + t * 64;
            #pragma unroll
            for (int j = 0; j < 4; ++j) *(half8*)(wp + (((unsigned)(j * 16)) ^ wsw)) = st[j];
            __syncthreads();
        }
    }
    int ocb = m0 + w * 16 + g * 4;
    float b0 = bout[ocb], b1 = bout[ocb + 1], b2 = bout[ocb + 2], b3 = bout[ocb + 3];
    float* op = outp + ((size_t)b * DIM + ocb) * HW + n0 + c;
    #pragma unroll
    for (int nt = 0; nt < 16; ++nt) {
        op[(size_t)0 * HW + nt * 16] = sc[nt][0] + b0;
        op[(size_t)1 * HW + nt * 16] = sc[nt][1] + b1;
        op[(size_t)2 * HW + nt * 16] = sc[nt][2] + b2;
        op[(size_t)3 * HW + nt * 16] = sc[nt][3] + b3;
    }
}

extern "C" void kernel_launch(void* const* d_in, const int* in_sizes, int n_in,
                              void* d_out, int out_size, void* d_ws, size_t ws_size,
                              hipStream_t stream) {
    (void)in_sizes; (void)n_in; (void)out_size; (void)ws_size;
    const float* x = (const float*)d_in[0];
    const float* Wq = (const float*)d_in[1];
    const float* Wkv = (const float*)d_in[2];
    const float* Wout = (const float*)d_in[3];
    const float* bout = (const float*)d_in[4];
    float* outp = (float*)d_out;

    // Workspace layout (f32 units, total 47,448,064 = 189.8 MB; 209.7 MB known-safe):
    //   partial f32 [0, 14,680,064)                   (56 slices, dead after k2r)
    //   ktok   f16  [14,680,064, 14,942,208)
    //   vtokT  f16  [14,942,208, 15,204,352)          (column-permuted for k3)
    //   Wq16s  f16  [15,204,352, 15,269,888)          (QSCALE folded)
    //   Wout16 f16  [15,269,888, 15,335,424)
    //   Wkv16  f16  [15,335,424, 21,757,952)          (dead after k2)
    //   Pt     f16  [21,757,952, 28,180,480)          (dead after k2)
    //   otok16 f16  [15,335,424, 28,180,480)          (overlays Wkv16+Pt, written by k3)
    //   xT16   f16  [28,180,480, 34,603,008)          (dead after k1)
    //   qtok   f16  [34,603,008, 47,448,064)
    float* ws = (float*)d_ws;
    float*  partial = ws;
    half_t* ktok    = (half_t*)(ws + 14680064);
    half_t* vtokT   = (half_t*)(ws + 14942208);
    half_t* Wq16s   = (half_t*)(ws + 15204352);
    half_t* Wout16  = (half_t*)(ws + 15269888);
    half_t* Wkv16   = (half_t*)(ws + 15335424);
    half_t* Pt      = (half_t*)(ws + 21757952);
    half_t* otok16  = (half_t*)(ws + 15335424);
    half_t* xT16    = (half_t*)(ws + 28180480);
    half_t* qtok    = (half_t*)(ws + 34603008);

    hipFuncSetAttribute((const void*)k3_attn,
                        hipFuncAttributeMaxDynamicSharedMemorySize, 65536);

    k_cvt<<<dim3(6272), 256, 0, stream>>>(Wkv, Wkv16, 1.0f);
    k_cvt<<<dim3(64), 256, 0, stream>>>(Wq, Wq16s, QSCALE);
    k_cvt<<<dim3(64), 256, 0, stream>>>(Wout, Wout16, 1.0f);
    kx_t<<<dim3(196, 4, 4), 256, 0, stream>>>(x, xT16);
    k0_gather<<<dim3(6272), 256, 0, stream>>>(x, Pt);
    k2_kv<<<dim3(16, KSPLIT, 4), 256, 0, stream>>>(Wkv16, Pt, partial);
    k2r<<<dim3(128, 4), 256, 0, stream>>>(partial, ktok, vtokT);
    k1_qproj<<<dim3(1568), 256, 0, stream>>>(Wq16s, xT16, qtok);
    k3_attn<<<dim3(98, 32), 512, 65536, stream>>>(qtok, ktok, vtokT, otok16);
    k4_outproj<<<dim3(784), 256, 0, stream>>>(Wout16, otok16, bout, outp);
}

// Round 9
// 303.653 us; speedup vs baseline: 7.2319x; 1.0082x over previous
//
#include <hip/hip_runtime.h>

#define HEADS 8
#define DHEAD 64
#define QSCALE 0.125f   // 64^-0.5
#define DIM 256
#define IMG 112
#define HW 12544        // 112*112
#define NKV 256         // 16*16
#define INNER 512
#define KCONV 12544     // 256*49
#define KSPLIT 14
#define KCHUNK 896      // 12544/14
#define K2STEPS 28      // KCHUNK/32
#define BROW 80         // padded LDS row stride (bytes): balanced banks, no swizzle

typedef _Float16 half_t;
typedef _Float16 half8 __attribute__((ext_vector_type(8)));
typedef float f32x4 __attribute__((ext_vector_type(4)));

__device__ inline unsigned pk2(float a, float b) {
    union { half_t h[2]; unsigned u; } x;
    x.h[0] = (half_t)a; x.h[1] = (half_t)b;
    return x.u;
}

// ---------------- K0: im2col gather -> TRANSPOSED f16 patches Pt[b][pos][k]
__global__ __launch_bounds__(256) void k0_gather(const float* __restrict__ x,
                                                 half_t* __restrict__ Pt) {
    int gid = blockIdx.x * 256 + threadIdx.x;  // one 8-k chunk
    int bp = gid / 1568;                       // 1568 = 12544/8
    int k8 = gid - bp * 1568;
    int b = bp >> 8, pos = bp & 255;
    int oy = pos >> 4, ox = pos & 15;
    const float* xb = x + (size_t)b * DIM * HW + (size_t)(oy * 7) * IMG + ox * 7;
    int k0 = k8 * 8;
    half8 hv;
    #pragma unroll
    for (int j = 0; j < 8; ++j) {
        int k = k0 + j;
        int cch = k / 49;
        int tap = k - cch * 49;
        int kh = tap / 7;
        int kw = tap - kh * 7;
        hv[j] = (half_t)xb[(size_t)cch * HW + kh * IMG + kw];
    }
    *(half8*)&Pt[(size_t)bp * KCONV + k0] = hv;
}

// ---------------- Kcvt: f32 -> f16 with scale
__global__ __launch_bounds__(256) void k_cvt(const float* __restrict__ W,
                                             half_t* __restrict__ W16,
                                             float scale) {
    size_t i = ((size_t)blockIdx.x * 256 + threadIdx.x) * 8;
    float4 a = *(const float4*)&W[i];
    float4 b = *(const float4*)&W[i + 4];
    half8 h = { (half_t)(a.x * scale), (half_t)(a.y * scale),
                (half_t)(a.z * scale), (half_t)(a.w * scale),
                (half_t)(b.x * scale), (half_t)(b.y * scale),
                (half_t)(b.z * scale), (half_t)(b.w * scale) };
    *(half8*)&W16[i] = h;
}

// ---------------- Kx: transpose x f32 [b][c][n] -> xT16 f16 [b][n][c]
__global__ __launch_bounds__(256) void kx_t(const float* __restrict__ x,
                                            half_t* __restrict__ xT16) {
    __shared__ float tile[64 * 68];
    int t = threadIdx.x;
    int n0 = blockIdx.x * 64, c0 = blockIdx.y * 64, b = blockIdx.z;
    #pragma unroll
    for (int i = 0; i < 4; ++i) {
        int f4 = t + i * 256;
        int r = f4 >> 4, c4 = (f4 & 15) << 2;
        *(float4*)&tile[r * 68 + c4] =
            *(const float4*)&x[((size_t)(b * DIM + c0 + r)) * HW + n0 + c4];
    }
    __syncthreads();
    #pragma unroll
    for (int i = 0; i < 2; ++i) {
        int idx = t + i * 256;
        int rr = idx >> 3, cc8 = (idx & 7) << 3;
        half8 h;
        #pragma unroll
        for (int j = 0; j < 8; ++j) h[j] = (half_t)tile[(cc8 + j) * 68 + rr];
        *(half8*)&xT16[((size_t)b * HW + n0 + rr) * DIM + c0 + cc8] = h;
    }
}

// ---------------- K1: Q projection via f16 MFMA, padded LDS dbuf, XCD-clustered grid
__global__ __launch_bounds__(256) void k1_qproj(const half_t* __restrict__ Wq16s,
                                                const half_t* __restrict__ xT16,
                                                half_t* __restrict__ qtok) {
    __shared__ char Bs[2][256 * BROW];   // [n 256][80B], bank-balanced by padding
    int t = threadIdx.x;
    int w = t >> 6, l = t & 63, g = l >> 4, c = l & 15;
    int bid = blockIdx.x;
    int logical = (bid & 7) * 196 + (bid >> 3);
    int h = logical & 7;
    int rest = logical >> 3;
    int n0 = (rest % 49) * 256;
    int b = rest / 49;

    const half_t* Ap = Wq16s + (size_t)(h * 64 + w * 16 + c) * DIM + g * 8;
    const half_t* Bbase = xT16 + ((size_t)b * HW + n0 + t) * DIM;  // row t
    half8 st[4];
    #pragma unroll
    for (int j = 0; j < 4; ++j) st[j] = *(const half8*)(Bbase + j * 8);
    {
        char* wp = Bs[0] + t * BROW;
        #pragma unroll
        for (int j = 0; j < 4; ++j) *(half8*)(wp + j * 16) = st[j];
    }
    __syncthreads();

    f32x4 sc[16];
    #pragma unroll
    for (int nt = 0; nt < 16; ++nt) sc[nt] = (f32x4){0.f, 0.f, 0.f, 0.f};

    for (int kk = 0; kk < DIM / 32; ++kk) {
        char* cur = Bs[kk & 1];
        char* nxt = Bs[(kk & 1) ^ 1];
        if (kk < DIM / 32 - 1) {
            #pragma unroll
            for (int j = 0; j < 4; ++j)
                st[j] = *(const half8*)(Bbase + (kk + 1) * 32 + j * 8);
        }
        half8 a = *(const half8*)(Ap + kk * 32);
        __builtin_amdgcn_s_setprio(1);
        #pragma unroll
        for (int nt = 0; nt < 16; ++nt) {
            int row = nt * 16 + c;
            half8 bb = *(const half8*)(cur + row * BROW + g * 16);
            sc[nt] = __builtin_amdgcn_mfma_f32_16x16x32_f16(a, bb, sc[nt], 0, 0, 0);
        }
        __builtin_amdgcn_s_setprio(0);
        if (kk < DIM / 32 - 1) {
            char* wp = nxt + t * BROW;
            #pragma unroll
            for (int j = 0; j < 4; ++j) *(half8*)(wp + j * 16) = st[j];
            __syncthreads();
        }
    }
    half_t* op = qtok + ((size_t)(b * HEADS + h) * HW + n0 + c) * 64 + w * 16 + g * 4;
    #pragma unroll
    for (int nt = 0; nt < 16; ++nt) {
        uint2 u = make_uint2(pk2(sc[nt][0], sc[nt][1]), pk2(sc[nt][2], sc[nt][3]));
        *(uint2*)&op[(size_t)(nt * 16) * 64] = u;
    }
}

// ---------------- K2: KV conv GEMM, split-K=14, padded LDS dbuf, XCD-clustered grid
__global__ __launch_bounds__(256) void k2_kv(const half_t* __restrict__ W16,
                                             const half_t* __restrict__ Pt,
                                             float* __restrict__ partial) {
    __shared__ char Bs[2][256 * BROW];   // [pos 256][80B], bank-balanced by padding
    int t = threadIdx.x;
    int w = t >> 6, l = t & 63, g = l >> 4, c = l & 15;
    // flat grid 896 = 16 octile x 56 (ks,b); cluster the 16 B-sharing octile-sibs per XCD
    int bid = blockIdx.x;
    int logical = (bid & 7) * 112 + (bid >> 3);
    int octile = logical & 15;
    int grp = logical >> 4;      // = ks*4 + b
    int ks = grp >> 2;
    int b = grp & 3;

    const half_t* Ap = W16 + (size_t)(octile * 64 + w * 16 + c) * KCONV + ks * KCHUNK + g * 8;
    const half_t* Bbase = Pt + ((size_t)b * 256 + t) * KCONV + ks * KCHUNK;  // row t

    half8 st[4];
    #pragma unroll
    for (int j = 0; j < 4; ++j) st[j] = *(const half8*)(Bbase + j * 8);
    {
        char* wp = Bs[0] + t * BROW;
        #pragma unroll
        for (int j = 0; j < 4; ++j) *(half8*)(wp + j * 16) = st[j];
    }
    __syncthreads();

    f32x4 sc[16];
    #pragma unroll
    for (int nt = 0; nt < 16; ++nt) sc[nt] = (f32x4){0.f, 0.f, 0.f, 0.f};

    for (int kk = 0; kk < K2STEPS; ++kk) {
        char* cur = Bs[kk & 1];
        char* nxt = Bs[(kk & 1) ^ 1];
        if (kk < K2STEPS - 1) {
            #pragma unroll
            for (int j = 0; j < 4; ++j)
                st[j] = *(const half8*)(Bbase + (kk + 1) * 32 + j * 8);
        }
        half8 a = *(const half8*)(Ap + kk * 32);
        __builtin_amdgcn_s_setprio(1);
        #pragma unroll
        for (int nt = 0; nt < 16; ++nt) {
            int row = nt * 16 + c;
            half8 bb = *(const half8*)(cur + row * BROW + g * 16);
            sc[nt] = __builtin_amdgcn_mfma_f32_16x16x32_f16(a, bb, sc[nt], 0, 0, 0);
        }
        __builtin_amdgcn_s_setprio(0);
        if (kk < K2STEPS - 1) {
            char* wp = nxt + t * BROW;
            #pragma unroll
            for (int j = 0; j < 4; ++j) *(half8*)(wp + j * 16) = st[j];
            __syncthreads();
        }
    }
    float* op = partial + ((size_t)grp * 1024 + octile * 64 + w * 16) * 256;
    #pragma unroll
    for (int nt = 0; nt < 16; ++nt)
        #pragma unroll
        for (int r = 0; r < 4; ++r)
            op[(g * 4 + r) * 256 + nt * 16 + c] = sc[nt][r];
}

// ---------------- K2r: reduce partials -> ktok f16 [bh][kv][d], vtokT f16 [bh][d][kv']
// V columns written PERMUTED for k3's zero-shuffle PV:
//   kv = 32a+16b+4g+r  ->  k' = 32a+8g+4b+r
__global__ __launch_bounds__(256) void k2r(const float* __restrict__ partial,
                                           half_t* __restrict__ ktok,
                                           half_t* __restrict__ vtokT) {
    int pos = threadIdx.x;
    int oc0 = blockIdx.x * 8;
    int b = blockIdx.y;
    float v[8];
    #pragma unroll
    for (int j = 0; j < 8; ++j) {
        const float* src = partial + ((size_t)b * 1024 + oc0 + j) * 256 + pos;
        float s = 0.f;
        #pragma unroll
        for (int ksb = 0; ksb < KSPLIT; ++ksb) s += src[(size_t)ksb * 1048576];
        v[j] = s;
    }
    int h = (oc0 >> 6) & 7, d0 = oc0 & 63;
    if (oc0 < 512) {
        uint4 u = make_uint4(pk2(v[0], v[1]), pk2(v[2], v[3]),
                             pk2(v[4], v[5]), pk2(v[6], v[7]));
        *(uint4*)&ktok[((size_t)(b * HEADS + h) * NKV + pos) * 64 + d0] = u;
    } else {
        int posP = (pos & ~31) | (((pos >> 2) & 3) << 3) | (((pos >> 4) & 1) << 2) | (pos & 3);
        #pragma unroll
        for (int j = 0; j < 8; ++j)
            vtokT[((size_t)(b * HEADS + h) * 64 + d0 + j) * NKV + posP] = (half_t)v[j];
    }
}

// ---------------- K3: fused attention, swapped QK^T -> lane-local softmax, register PV.
// LDS: K (32KB) + permuted V^T (32KB) = 64KB -> 2 blocks/CU. No S buffer, no 2nd barrier.
__global__ __launch_bounds__(512) void k3_attn(const half_t* __restrict__ qtok,
                                               const half_t* __restrict__ ktok,
                                               const half_t* __restrict__ vtokT,
                                               half_t* __restrict__ otok16) {
    extern __shared__ char lds[];
    char* K_lds = lds;                         // byte(kv,·) = kv*128 + (off ^ ((kv&7)<<4))
    char* V_lds = lds + 32768;                 // byte(d,·)  = d*512  + (off ^ ((d&7)<<4))
    int t = threadIdx.x;
    int w = t >> 6, l = t & 63, g = l >> 4, c = l & 15;
    int q0 = blockIdx.x * 128;
    int bh = blockIdx.y;

    // Q fragments (B-operand of swapped QK^T): lane (c,g) holds Q[q=c][d=g*8+j]
    const half_t* qp = qtok + ((size_t)bh * HW + q0 + w * 16 + c) * 64 + g * 8;
    half8 bq0 = *(const half8*)(qp);
    half8 bq1 = *(const half8*)(qp + 32);

    // stage K: thread t covers kv = t>>1, 32 halfs at (t&1)*32
    {
        int kv = t >> 1;
        const half_t* kg = ktok + (size_t)bh * NKV * 64 + (size_t)kv * 64 + (t & 1) * 32;
        char* wp = K_lds + kv * 128;
        unsigned sw = (unsigned)((kv & 7) << 4);
        unsigned base = (unsigned)((t & 1) * 64);
        #pragma unroll
        for (int j = 0; j < 4; ++j)
            *(half8*)(wp + ((base + j * 16) ^ sw)) = *(const half8*)(kg + j * 8);
    }
    // stage V^T (already column-permuted by k2r): thread t covers d = t>>3
    {
        int d = t >> 3;
        const half_t* vg = vtokT + (size_t)bh * 64 * NKV + (size_t)d * NKV + (t & 7) * 32;
        char* wp = V_lds + d * 512;
        unsigned sw = (unsigned)((d & 7) << 4);
        unsigned base = (unsigned)((t & 7) * 32 * 2);
        #pragma unroll
        for (int j = 0; j < 4; ++j)
            *(half8*)(wp + ((base + j * 16) ^ sw)) = *(const half8*)(vg + j * 8);
    }
    __syncthreads();

    // swapped dots: sc[nt] = mfma(K_frag, Q_frag) -> lane holds S[q=c][kv=16nt+4g+r]
    f32x4 sc[16];
    __builtin_amdgcn_s_setprio(1);
    #pragma unroll
    for (int nt = 0; nt < 16; ++nt) {
        int row = nt * 16 + c;
        const char* kp = K_lds + row * 128;
        unsigned sw = (unsigned)((row & 7) << 4);
        half8 a0 = *(const half8*)(kp + (((unsigned)(g * 16)) ^ sw));
        half8 a1 = *(const half8*)(kp + (((unsigned)(g * 16 + 64)) ^ sw));
        f32x4 acc = (f32x4){0.f, 0.f, 0.f, 0.f};
        acc = __builtin_amdgcn_mfma_f32_16x16x32_f16(a0, bq0, acc, 0, 0, 0);
        acc = __builtin_amdgcn_mfma_f32_16x16x32_f16(a1, bq1, acc, 0, 0, 0);
        sc[nt] = acc;
    }
    __builtin_amdgcn_s_setprio(0);

    // softmax: in-lane over 64 values + 2 shfls (lanes c,c+16,c+32,c+48 share row q=c)
    float m = sc[0][0];
    #pragma unroll
    for (int nt = 0; nt < 16; ++nt)
        #pragma unroll
        for (int r = 0; r < 4; ++r) m = fmaxf(m, sc[nt][r]);
    m = fmaxf(m, __shfl_xor(m, 16));
    m = fmaxf(m, __shfl_xor(m, 32));
    float s = 0.f;
    #pragma unroll
    for (int nt = 0; nt < 16; ++nt)
        #pragma unroll
        for (int r = 0; r < 4; ++r) {
            float e = __expf(sc[nt][r] - m);
            sc[nt][r] = e;
            s += e;
        }
    s += __shfl_xor(s, 16);
    s += __shfl_xor(s, 32);
    float inv = 1.f / s;

    // PV: P packs in-lane into A-frags (kv order matches permuted V rows)
    f32x4 o[4];
    #pragma unroll
    for (int nt = 0; nt < 4; ++nt) o[nt] = (f32x4){0.f, 0.f, 0.f, 0.f};
    __builtin_amdgcn_s_setprio(1);
    #pragma unroll
    for (int ks = 0; ks < 8; ++ks) {
        union { unsigned u[4]; half8 h; } ap;
        ap.u[0] = pk2(sc[2 * ks][0] * inv, sc[2 * ks][1] * inv);
        ap.u[1] = pk2(sc[2 * ks][2] * inv, sc[2 * ks][3] * inv);
        ap.u[2] = pk2(sc[2 * ks + 1][0] * inv, sc[2 * ks + 1][1] * inv);
        ap.u[3] = pk2(sc[2 * ks + 1][2] * inv, sc[2 * ks + 1][3] * inv);
        #pragma unroll
        for (int nt = 0; nt < 4; ++nt) {
            int d = nt * 16 + c;
            half8 bv = *(const half8*)(V_lds + d * 512 +
                                       (((unsigned)(ks * 64 + g * 16)) ^ ((unsigned)((d & 7) << 4))));
            o[nt] = __builtin_amdgcn_mfma_f32_16x16x32_f16(ap.h, bv, o[nt], 0, 0, 0);
        }
    }
    __builtin_amdgcn_s_setprio(0);
    // store f16: n = q0 + w*16 + g*4 + r, k = h*64 + nt*16 + c
    int b = bh >> 3, h = bh & 7;
    half_t* op = otok16 + ((size_t)b * HW + q0 + w * 16) * INNER + h * 64;
    #pragma unroll
    for (int nt = 0; nt < 4; ++nt)
        #pragma unroll
        for (int r = 0; r < 4; ++r)
            op[(size_t)(g * 4 + r) * INNER + nt * 16 + c] = (half_t)o[nt][r];
}

// ---------------- K4: output projection via f16 MFMA + bias, padded LDS dbuf
__global__ __launch_bounds__(256) void k4_outproj(const half_t* __restrict__ Wout16,
                                                  const half_t* __restrict__ otok16,
                                                  const float* __restrict__ bout,
                                                  float* __restrict__ outp) {
    __shared__ char Bs[2][256 * BROW];   // [n 256][80B], bank-balanced by padding
    int t = threadIdx.x;
    int w = t >> 6, l = t & 63, g = l >> 4, c = l & 15;
    int bid = blockIdx.x;
    int logical = (bid & 7) * 98 + (bid >> 3);
    int m0 = (logical & 3) * 64;
    int rest = logical >> 2;
    int n0 = (rest % 49) * 256;
    int b = rest / 49;

    const half_t* Ap = Wout16 + (size_t)(m0 + w * 16 + c) * INNER + g * 8;
    const half_t* Bbase = otok16 + ((size_t)b * HW + n0 + t) * INNER;  // row t
    half8 st[4];
    #pragma unroll
    for (int j = 0; j < 4; ++j) st[j] = *(const half8*)(Bbase + j * 8);
    {
        char* wp = Bs[0] + t * BROW;
        #pragma unroll
        for (int j = 0; j < 4; ++j) *(half8*)(wp + j * 16) = st[j];
    }
    __syncthreads();

    f32x4 sc[16];
    #pragma unroll
    for (int nt = 0; nt < 16; ++nt) sc[nt] = (f32x4){0.f, 0.f, 0.f, 0.f};

    for (int kk = 0; kk < INNER / 32; ++kk) {
        char* cur = Bs[kk & 1];
        char* nxt = Bs[(kk & 1) ^ 1];
        if (kk < INNER / 32 - 1) {
            #pragma unroll
            for (int j = 0; j < 4; ++j)
                st[j] = *(const half8*)(Bbase + (kk + 1) * 32 + j * 8);
        }
        half8 a = *(const half8*)(Ap + kk * 32);
        __builtin_amdgcn_s_setprio(1);
        #pragma unroll
        for (int nt = 0; nt < 16; ++nt) {
            int row = nt * 16 + c;
            half8 bb = *(const half8*)(cur + row * BROW + g * 16);
            sc[nt] = __builtin_amdgcn_mfma_f32_16x16x32_f16(a, bb, sc[nt], 0, 0, 0);
        }
        __builtin_amdgcn_s_setprio(0);
        if (kk < INNER / 32 - 1) {
            char* wp = nxt + t * BROW;
            #pragma unroll
            for (int j = 0; j < 4; ++j) *(half8*)(wp + j * 16) = st[j];
            __syncthreads();
        }
    }
    int ocb = m0 + w * 16 + g * 4;
    float b0 = bout[ocb], b1 = bout[ocb + 1], b2 = bout[ocb + 2], b3 = bout[ocb + 3];
    float* op = outp + ((size_t)b * DIM + ocb) * HW + n0 + c;
    #pragma unroll
    for (int nt = 0; nt < 16; ++nt) {
        op[(size_t)0 * HW + nt * 16] = sc[nt][0] + b0;
        op[(size_t)1 * HW + nt * 16] = sc[nt][1] + b1;
        op[(size_t)2 * HW + nt * 16] = sc[nt][2] + b2;
        op[(size_t)3 * HW + nt * 16] = sc[nt][3] + b3;
    }
}

extern "C" void kernel_launch(void* const* d_in, const int* in_sizes, int n_in,
                              void* d_out, int out_size, void* d_ws, size_t ws_size,
                              hipStream_t stream) {
    (void)in_sizes; (void)n_in; (void)out_size; (void)ws_size;
    const float* x = (const float*)d_in[0];
    const float* Wq = (const float*)d_in[1];
    const float* Wkv = (const float*)d_in[2];
    const float* Wout = (const float*)d_in[3];
    const float* bout = (const float*)d_in[4];
    float* outp = (float*)d_out;

    // Workspace layout (f32 units, total 47,448,064 = 189.8 MB; 209.7 MB known-safe):
    //   partial f32 [0, 14,680,064)                   (56 slices, dead after k2r)
    //   ktok   f16  [14,680,064, 14,942,208)
    //   vtokT  f16  [14,942,208, 15,204,352)          (column-permuted for k3)
    //   Wq16s  f16  [15,204,352, 15,269,888)          (QSCALE folded)
    //   Wout16 f16  [15,269,888, 15,335,424)
    //   Wkv16  f16  [15,335,424, 21,757,952)          (dead after k2)
    //   Pt     f16  [21,757,952, 28,180,480)          (dead after k2)
    //   otok16 f16  [15,335,424, 28,180,480)          (overlays Wkv16+Pt, written by k3)
    //   xT16   f16  [28,180,480, 34,603,008)          (dead after k1)
    //   qtok   f16  [34,603,008, 47,448,064)
    float* ws = (float*)d_ws;
    float*  partial = ws;
    half_t* ktok    = (half_t*)(ws + 14680064);
    half_t* vtokT   = (half_t*)(ws + 14942208);
    half_t* Wq16s   = (half_t*)(ws + 15204352);
    half_t* Wout16  = (half_t*)(ws + 15269888);
    half_t* Wkv16   = (half_t*)(ws + 15335424);
    half_t* Pt      = (half_t*)(ws + 21757952);
    half_t* otok16  = (half_t*)(ws + 15335424);
    half_t* xT16    = (half_t*)(ws + 28180480);
    half_t* qtok    = (half_t*)(ws + 34603008);

    hipFuncSetAttribute((const void*)k3_attn,
                        hipFuncAttributeMaxDynamicSharedMemorySize, 65536);

    k_cvt<<<dim3(6272), 256, 0, stream>>>(Wkv, Wkv16, 1.0f);
    k_cvt<<<dim3(64), 256, 0, stream>>>(Wq, Wq16s, QSCALE);
    k_cvt<<<dim3(64), 256, 0, stream>>>(Wout, Wout16, 1.0f);
    kx_t<<<dim3(196, 4, 4), 256, 0, stream>>>(x, xT16);
    k0_gather<<<dim3(6272), 256, 0, stream>>>(x, Pt);
    k2_kv<<<dim3(896), 256, 0, stream>>>(Wkv16, Pt, partial);
    k2r<<<dim3(128, 4), 256, 0, stream>>>(partial, ktok, vtokT);
    k1_qproj<<<dim3(1568), 256, 0, stream>>>(Wq16s, xT16, qtok);
    k3_attn<<<dim3(98, 32), 512, 65536, stream>>>(qtok, ktok, vtokT, otok16);
    k4_outproj<<<dim3(784), 256, 0, stream>>>(Wout16, otok16, bout, outp);
}

// Round 10
// 260.998 us; speedup vs baseline: 8.4138x; 1.1634x over previous
//
#include <hip/hip_runtime.h>

#define HEADS 8
#define DHEAD 64
#define QSCALE 0.125f   // 64^-0.5
#define DIM 256
#define IMG 112
#define HW 12544        // 112*112
#define NKV 256         // 16*16
#define INNER 512
#define KCONV 12544     // 256*49
#define KSPLIT 14
#define KCHUNK 896      // 12544/14
#define K2STEPS 28      // KCHUNK/32

typedef _Float16 half_t;
typedef _Float16 half8 __attribute__((ext_vector_type(8)));
typedef float f32x4 __attribute__((ext_vector_type(4)));

__device__ inline unsigned pk2(float a, float b) {
    union { half_t h[2]; unsigned u; } x;
    x.h[0] = (half_t)a; x.h[1] = (half_t)b;
    return x.u;
}

// ---------------- K0: im2col gather -> fragment-ready Pt'[b][kk 392][pos 256][g 4][8]
__global__ __launch_bounds__(256) void k0_gather(const float* __restrict__ x,
                                                 half_t* __restrict__ Pt) {
    int gid = blockIdx.x * 256 + threadIdx.x;  // one 8-k chunk
    int bp = gid / 1568;                       // 1568 = 12544/8
    int k8 = gid - bp * 1568;
    int b = bp >> 8, pos = bp & 255;
    int oy = pos >> 4, ox = pos & 15;
    const float* xb = x + (size_t)b * DIM * HW + (size_t)(oy * 7) * IMG + ox * 7;
    int k0 = k8 * 8;
    half8 hv;
    #pragma unroll
    for (int j = 0; j < 8; ++j) {
        int k = k0 + j;
        int cch = k / 49;
        int tap = k - cch * 49;
        int kh = tap / 7;
        int kw = tap - kh * 7;
        hv[j] = (half_t)xb[(size_t)cch * HW + kh * IMG + kw];
    }
    *(half8*)&Pt[((((size_t)b * 392 + (k0 >> 5)) * 256 + pos) * 4 + ((k0 >> 3) & 3)) * 8] = hv;
}

// ---------------- Kcvt: f32 [OC][K] -> fragment-ready f16 W'[kk][OC][g][8], scaled
__global__ __launch_bounds__(256) void k_cvt(const float* __restrict__ W,
                                             half_t* __restrict__ W16,
                                             float scale, int OC, int K) {
    int gid = blockIdx.x * 256 + threadIdx.x;
    int perRow = K >> 3;
    int oc = gid / perRow;
    int k0 = (gid - oc * perRow) * 8;
    const float* src = W + (size_t)oc * K + k0;
    float4 a = *(const float4*)src;
    float4 b = *(const float4*)(src + 4);
    half8 h = { (half_t)(a.x * scale), (half_t)(a.y * scale),
                (half_t)(a.z * scale), (half_t)(a.w * scale),
                (half_t)(b.x * scale), (half_t)(b.y * scale),
                (half_t)(b.z * scale), (half_t)(b.w * scale) };
    *(half8*)&W16[(((size_t)(k0 >> 5) * OC + oc) * 4 + ((k0 >> 3) & 3)) * 8] = h;
}

// ---------------- Kx: transpose x f32 [b][c][n] -> x' f16 [b][kk 8][n][g][8]
__global__ __launch_bounds__(256) void kx_t(const float* __restrict__ x,
                                            half_t* __restrict__ xT16) {
    __shared__ float tile[64 * 68];
    int t = threadIdx.x;
    int n0 = blockIdx.x * 64, c0 = blockIdx.y * 64, b = blockIdx.z;
    #pragma unroll
    for (int i = 0; i < 4; ++i) {
        int f4 = t + i * 256;
        int r = f4 >> 4, c4 = (f4 & 15) << 2;
        *(float4*)&tile[r * 68 + c4] =
            *(const float4*)&x[((size_t)(b * DIM + c0 + r)) * HW + n0 + c4];
    }
    __syncthreads();
    #pragma unroll
    for (int i = 0; i < 2; ++i) {
        int idx = t + i * 256;
        int rr = idx >> 3, cc8 = (idx & 7) << 3;
        half8 h;
        #pragma unroll
        for (int j = 0; j < 8; ++j) h[j] = (half_t)tile[(cc8 + j) * 68 + rr];
        int ch = c0 + cc8;
        *(half8*)&xT16[((((size_t)b * 8 + (ch >> 5)) * HW + n0 + rr) * 4 + ((ch >> 3) & 3)) * 8] = h;
    }
}

// ---------------- K1: Q projection, no LDS: wave w owns n 64w..64w+63, all 64 d
__global__ __launch_bounds__(256) void k1_qproj(const half_t* __restrict__ Wq16s,
                                                const half_t* __restrict__ xT16,
                                                half_t* __restrict__ qtok) {
    int t = threadIdx.x;
    int w = t >> 6, l = t & 63, g = l >> 4, c = l & 15;
    int bid = blockIdx.x;
    int logical = (bid & 7) * 196 + (bid >> 3);
    int h = logical & 7;
    int rest = logical >> 3;
    int n0 = (rest % 49) * 256;
    int b = rest / 49;

    const half_t* Ab = Wq16s + (size_t)(h * 64 + c) * 32 + g * 8;          // +kk*16384 +a*512
    const half_t* Bb = xT16 + ((size_t)b * 8 * HW + n0 + w * 64 + c) * 32 + g * 8;  // +kk*401408 +nt*512

    f32x4 sc[4][4];
    #pragma unroll
    for (int a = 0; a < 4; ++a)
        #pragma unroll
        for (int nt = 0; nt < 4; ++nt) sc[a][nt] = (f32x4){0.f, 0.f, 0.f, 0.f};

    half8 A0[4], B0[4], A1[4], B1[4];
    #pragma unroll
    for (int a = 0; a < 4; ++a) A0[a] = *(const half8*)(Ab + a * 512);
    #pragma unroll
    for (int nt = 0; nt < 4; ++nt) B0[nt] = *(const half8*)(Bb + nt * 512);

    for (int kk = 0; kk < 8; kk += 2) {
        #pragma unroll
        for (int a = 0; a < 4; ++a) A1[a] = *(const half8*)(Ab + (size_t)(kk + 1) * 16384 + a * 512);
        #pragma unroll
        for (int nt = 0; nt < 4; ++nt) B1[nt] = *(const half8*)(Bb + (size_t)(kk + 1) * 401408 + nt * 512);
        __builtin_amdgcn_s_setprio(1);
        #pragma unroll
        for (int a = 0; a < 4; ++a)
            #pragma unroll
            for (int nt = 0; nt < 4; ++nt)
                sc[a][nt] = __builtin_amdgcn_mfma_f32_16x16x32_f16(A0[a], B0[nt], sc[a][nt], 0, 0, 0);
        __builtin_amdgcn_s_setprio(0);
        if (kk + 2 < 8) {
            #pragma unroll
            for (int a = 0; a < 4; ++a) A0[a] = *(const half8*)(Ab + (size_t)(kk + 2) * 16384 + a * 512);
            #pragma unroll
            for (int nt = 0; nt < 4; ++nt) B0[nt] = *(const half8*)(Bb + (size_t)(kk + 2) * 401408 + nt * 512);
        }
        __builtin_amdgcn_s_setprio(1);
        #pragma unroll
        for (int a = 0; a < 4; ++a)
            #pragma unroll
            for (int nt = 0; nt < 4; ++nt)
                sc[a][nt] = __builtin_amdgcn_mfma_f32_16x16x32_f16(A1[a], B1[nt], sc[a][nt], 0, 0, 0);
        __builtin_amdgcn_s_setprio(0);
    }
    // store: n = n0+64w+16nt+c, d = a*16 + g*4 + r (4 halfs -> uint2)
    half_t* op = qtok + ((size_t)(b * HEADS + h) * HW + n0 + w * 64 + c) * 64 + g * 4;
    #pragma unroll
    for (int a = 0; a < 4; ++a)
        #pragma unroll
        for (int nt = 0; nt < 4; ++nt) {
            uint2 u = make_uint2(pk2(sc[a][nt][0], sc[a][nt][1]),
                                 pk2(sc[a][nt][2], sc[a][nt][3]));
            *(uint2*)&op[(size_t)(nt * 16) * 64 + a * 16] = u;
        }
}

// ---------------- K2: KV conv GEMM, no LDS, split-K=14, XCD-clustered grid
__global__ __launch_bounds__(256) void k2_kv(const half_t* __restrict__ W16,
                                             const half_t* __restrict__ Pt,
                                             float* __restrict__ partial) {
    int t = threadIdx.x;
    int w = t >> 6, l = t & 63, g = l >> 4, c = l & 15;
    int bid = blockIdx.x;
    int logical = (bid & 7) * 112 + (bid >> 3);
    int octile = logical & 15;
    int grp = logical >> 4;      // = ks*4 + b
    int ks = grp >> 2;
    int b = grp & 3;

    const half_t* Ab = W16 + ((size_t)(ks * 28) * 1024 + octile * 64 + c) * 32 + g * 8;  // +kk*32768 +a*512
    const half_t* Bb = Pt + (((size_t)b * 392 + ks * 28) * 256 + w * 64 + c) * 32 + g * 8;  // +kk*8192 +nt*512

    f32x4 sc[4][4];
    #pragma unroll
    for (int a = 0; a < 4; ++a)
        #pragma unroll
        for (int nt = 0; nt < 4; ++nt) sc[a][nt] = (f32x4){0.f, 0.f, 0.f, 0.f};

    half8 A0[4], B0[4], A1[4], B1[4];
    #pragma unroll
    for (int a = 0; a < 4; ++a) A0[a] = *(const half8*)(Ab + a * 512);
    #pragma unroll
    for (int nt = 0; nt < 4; ++nt) B0[nt] = *(const half8*)(Bb + nt * 512);

    for (int kk = 0; kk < K2STEPS; kk += 2) {
        #pragma unroll
        for (int a = 0; a < 4; ++a) A1[a] = *(const half8*)(Ab + (size_t)(kk + 1) * 32768 + a * 512);
        #pragma unroll
        for (int nt = 0; nt < 4; ++nt) B1[nt] = *(const half8*)(Bb + (size_t)(kk + 1) * 8192 + nt * 512);
        __builtin_amdgcn_s_setprio(1);
        #pragma unroll
        for (int a = 0; a < 4; ++a)
            #pragma unroll
            for (int nt = 0; nt < 4; ++nt)
                sc[a][nt] = __builtin_amdgcn_mfma_f32_16x16x32_f16(A0[a], B0[nt], sc[a][nt], 0, 0, 0);
        __builtin_amdgcn_s_setprio(0);
        if (kk + 2 < K2STEPS) {
            #pragma unroll
            for (int a = 0; a < 4; ++a) A0[a] = *(const half8*)(Ab + (size_t)(kk + 2) * 32768 + a * 512);
            #pragma unroll
            for (int nt = 0; nt < 4; ++nt) B0[nt] = *(const half8*)(Bb + (size_t)(kk + 2) * 8192 + nt * 512);
        }
        __builtin_amdgcn_s_setprio(1);
        #pragma unroll
        for (int a = 0; a < 4; ++a)
            #pragma unroll
            for (int nt = 0; nt < 4; ++nt)
                sc[a][nt] = __builtin_amdgcn_mfma_f32_16x16x32_f16(A1[a], B1[nt], sc[a][nt], 0, 0, 0);
        __builtin_amdgcn_s_setprio(0);
    }
    // store: row oc = octile*64 + a*16 + g*4 + r, col pos = 64w + nt*16 + c
    float* op = partial + ((size_t)grp * 1024 + octile * 64 + g * 4) * 256 + w * 64 + c;
    #pragma unroll
    for (int a = 0; a < 4; ++a)
        #pragma unroll
        for (int nt = 0; nt < 4; ++nt)
            #pragma unroll
            for (int r = 0; r < 4; ++r)
                op[(size_t)(a * 16 + r) * 256 + nt * 16] = sc[a][nt][r];
}

// ---------------- K2r: reduce partials -> ktok f16 [bh][kv][d], vtokT f16 [bh][d][kv']
// V columns written PERMUTED for k3's zero-shuffle PV:
//   kv = 32a+16b+4g+r  ->  k' = 32a+8g+4b+r
__global__ __launch_bounds__(256) void k2r(const float* __restrict__ partial,
                                           half_t* __restrict__ ktok,
                                           half_t* __restrict__ vtokT) {
    int pos = threadIdx.x;
    int oc0 = blockIdx.x * 8;
    int b = blockIdx.y;
    float v[8];
    #pragma unroll
    for (int j = 0; j < 8; ++j) {
        const float* src = partial + ((size_t)b * 1024 + oc0 + j) * 256 + pos;
        float s = 0.f;
        #pragma unroll
        for (int ksb = 0; ksb < KSPLIT; ++ksb) s += src[(size_t)ksb * 1048576];
        v[j] = s;
    }
    int h = (oc0 >> 6) & 7, d0 = oc0 & 63;
    if (oc0 < 512) {
        uint4 u = make_uint4(pk2(v[0], v[1]), pk2(v[2], v[3]),
                             pk2(v[4], v[5]), pk2(v[6], v[7]));
        *(uint4*)&ktok[((size_t)(b * HEADS + h) * NKV + pos) * 64 + d0] = u;
    } else {
        int posP = (pos & ~31) | (((pos >> 2) & 3) << 3) | (((pos >> 4) & 1) << 2) | (pos & 3);
        #pragma unroll
        for (int j = 0; j < 8; ++j)
            vtokT[((size_t)(b * HEADS + h) * 64 + d0 + j) * NKV + posP] = (half_t)v[j];
    }
}

// ---------------- K3: fused attention, swapped QK^T -> lane-local softmax, register PV.
// LDS: K (32KB) + permuted V^T (32KB) = 64KB. Writes fragment-ready o'[b][kk 16][n][g][8].
__global__ __launch_bounds__(512) void k3_attn(const half_t* __restrict__ qtok,
                                               const half_t* __restrict__ ktok,
                                               const half_t* __restrict__ vtokT,
                                               half_t* __restrict__ otok16) {
    extern __shared__ char lds[];
    char* K_lds = lds;                         // byte(kv,·) = kv*128 + (off ^ ((kv&7)<<4))
    char* V_lds = lds + 32768;                 // byte(d,·)  = d*512  + (off ^ ((d&7)<<4))
    int t = threadIdx.x;
    int w = t >> 6, l = t & 63, g = l >> 4, c = l & 15;
    int q0 = blockIdx.x * 128;
    int bh = blockIdx.y;

    // Q fragments (B-operand of swapped QK^T): lane (c,g) holds Q[q=c][d=g*8+j]
    const half_t* qp = qtok + ((size_t)bh * HW + q0 + w * 16 + c) * 64 + g * 8;
    half8 bq0 = *(const half8*)(qp);
    half8 bq1 = *(const half8*)(qp + 32);

    // stage K: thread t covers kv = t>>1, 32 halfs at (t&1)*32
    {
        int kv = t >> 1;
        const half_t* kg = ktok + (size_t)bh * NKV * 64 + (size_t)kv * 64 + (t & 1) * 32;
        char* wp = K_lds + kv * 128;
        unsigned sw = (unsigned)((kv & 7) << 4);
        unsigned base = (unsigned)((t & 1) * 64);
        #pragma unroll
        for (int j = 0; j < 4; ++j)
            *(half8*)(wp + ((base + j * 16) ^ sw)) = *(const half8*)(kg + j * 8);
    }
    // stage V^T (already column-permuted by k2r): thread t covers d = t>>3
    {
        int d = t >> 3;
        const half_t* vg = vtokT + (size_t)bh * 64 * NKV + (size_t)d * NKV + (t & 7) * 32;
        char* wp = V_lds + d * 512;
        unsigned sw = (unsigned)((d & 7) << 4);
        unsigned base = (unsigned)((t & 7) * 64);
        #pragma unroll
        for (int j = 0; j < 4; ++j)
            *(half8*)(wp + ((base + j * 16) ^ sw)) = *(const half8*)(vg + j * 8);
    }
    __syncthreads();

    // swapped dots: sc[nt] = mfma(K_frag, Q_frag) -> lane holds S[q=c][kv=16nt+4g+r]
    f32x4 sc[16];
    __builtin_amdgcn_s_setprio(1);
    #pragma unroll
    for (int nt = 0; nt < 16; ++nt) {
        int row = nt * 16 + c;
        const char* kp = K_lds + row * 128;
        unsigned sw = (unsigned)((row & 7) << 4);
        half8 a0 = *(const half8*)(kp + (((unsigned)(g * 16)) ^ sw));
        half8 a1 = *(const half8*)(kp + (((unsigned)(g * 16 + 64)) ^ sw));
        f32x4 acc = (f32x4){0.f, 0.f, 0.f, 0.f};
        acc = __builtin_amdgcn_mfma_f32_16x16x32_f16(a0, bq0, acc, 0, 0, 0);
        acc = __builtin_amdgcn_mfma_f32_16x16x32_f16(a1, bq1, acc, 0, 0, 0);
        sc[nt] = acc;
    }
    __builtin_amdgcn_s_setprio(0);

    // softmax: in-lane over 64 values + 2 shfls (lanes c,c+16,c+32,c+48 share row q=c)
    float m = sc[0][0];
    #pragma unroll
    for (int nt = 0; nt < 16; ++nt)
        #pragma unroll
        for (int r = 0; r < 4; ++r) m = fmaxf(m, sc[nt][r]);
    m = fmaxf(m, __shfl_xor(m, 16));
    m = fmaxf(m, __shfl_xor(m, 32));
    float s = 0.f;
    #pragma unroll
    for (int nt = 0; nt < 16; ++nt)
        #pragma unroll
        for (int r = 0; r < 4; ++r) {
            float e = __expf(sc[nt][r] - m);
            sc[nt][r] = e;
            s += e;
        }
    s += __shfl_xor(s, 16);
    s += __shfl_xor(s, 32);
    float inv = 1.f / s;

    // PV: P packs in-lane into A-frags (kv order matches permuted V rows)
    f32x4 o[4];
    #pragma unroll
    for (int nt = 0; nt < 4; ++nt) o[nt] = (f32x4){0.f, 0.f, 0.f, 0.f};
    __builtin_amdgcn_s_setprio(1);
    #pragma unroll
    for (int ks = 0; ks < 8; ++ks) {
        union { unsigned u[4]; half8 h; } ap;
        ap.u[0] = pk2(sc[2 * ks][0] * inv, sc[2 * ks][1] * inv);
        ap.u[1] = pk2(sc[2 * ks][2] * inv, sc[2 * ks][3] * inv);
        ap.u[2] = pk2(sc[2 * ks + 1][0] * inv, sc[2 * ks + 1][1] * inv);
        ap.u[3] = pk2(sc[2 * ks + 1][2] * inv, sc[2 * ks + 1][3] * inv);
        #pragma unroll
        for (int nt = 0; nt < 4; ++nt) {
            int d = nt * 16 + c;
            half8 bv = *(const half8*)(V_lds + d * 512 +
                                       (((unsigned)(ks * 64 + g * 16)) ^ ((unsigned)((d & 7) << 4))));
            o[nt] = __builtin_amdgcn_mfma_f32_16x16x32_f16(ap.h, bv, o[nt], 0, 0, 0);
        }
    }
    __builtin_amdgcn_s_setprio(0);
    // store fragment-ready: n = q0+w*16+g*4+r, k(INNER) = h*64+nt*16+c ->
    //   kk = h*2 + (nt>>1), granule = (nt&1)*2 + (c>>3), elem = c&7
    int b = bh >> 3, h = bh & 7;
    #pragma unroll
    for (int nt = 0; nt < 4; ++nt) {
        size_t base = (((size_t)b * 16 + h * 2 + (nt >> 1)) * HW + q0 + w * 16 + g * 4) * 32
                      + ((nt & 1) * 2 + (c >> 3)) * 8 + (c & 7);
        #pragma unroll
        for (int r = 0; r < 4; ++r)
            otok16[base + (size_t)r * 32] = (half_t)o[nt][r];
    }
}

// ---------------- K4: output projection + bias, no LDS
__global__ __launch_bounds__(256) void k4_outproj(const half_t* __restrict__ Wout16,
                                                  const half_t* __restrict__ otok16,
                                                  const float* __restrict__ bout,
                                                  float* __restrict__ outp) {
    int t = threadIdx.x;
    int w = t >> 6, l = t & 63, g = l >> 4, c = l & 15;
    int bid = blockIdx.x;
    int logical = (bid & 7) * 98 + (bid >> 3);
    int m0 = (logical & 3) * 64;
    int rest = logical >> 2;
    int n0 = (rest % 49) * 256;
    int b = rest / 49;

    const half_t* Ab = Wout16 + (size_t)(m0 + c) * 32 + g * 8;                      // +kk*8192 +a*512
    const half_t* Bb = otok16 + ((size_t)b * 16 * HW + n0 + w * 64 + c) * 32 + g * 8;  // +kk*401408 +nt*512

    f32x4 sc[4][4];
    #pragma unroll
    for (int a = 0; a < 4; ++a)
        #pragma unroll
        for (int nt = 0; nt < 4; ++nt) sc[a][nt] = (f32x4){0.f, 0.f, 0.f, 0.f};

    half8 A0[4], B0[4], A1[4], B1[4];
    #pragma unroll
    for (int a = 0; a < 4; ++a) A0[a] = *(const half8*)(Ab + a * 512);
    #pragma unroll
    for (int nt = 0; nt < 4; ++nt) B0[nt] = *(const half8*)(Bb + nt * 512);

    for (int kk = 0; kk < 16; kk += 2) {
        #pragma unroll
        for (int a = 0; a < 4; ++a) A1[a] = *(const half8*)(Ab + (size_t)(kk + 1) * 8192 + a * 512);
        #pragma unroll
        for (int nt = 0; nt < 4; ++nt) B1[nt] = *(const half8*)(Bb + (size_t)(kk + 1) * 401408 + nt * 512);
        __builtin_amdgcn_s_setprio(1);
        #pragma unroll
        for (int a = 0; a < 4; ++a)
            #pragma unroll
            for (int nt = 0; nt < 4; ++nt)
                sc[a][nt] = __builtin_amdgcn_mfma_f32_16x16x32_f16(A0[a], B0[nt], sc[a][nt], 0, 0, 0);
        __builtin_amdgcn_s_setprio(0);
        if (kk + 2 < 16) {
            #pragma unroll
            for (int a = 0; a < 4; ++a) A0[a] = *(const half8*)(Ab + (size_t)(kk + 2) * 8192 + a * 512);
            #pragma unroll
            for (int nt = 0; nt < 4; ++nt) B0[nt] = *(const half8*)(Bb + (size_t)(kk + 2) * 401408 + nt * 512);
        }
        __builtin_amdgcn_s_setprio(1);
        #pragma unroll
        for (int a = 0; a < 4; ++a)
            #pragma unroll
            for (int nt = 0; nt < 4; ++nt)
                sc[a][nt] = __builtin_amdgcn_mfma_f32_16x16x32_f16(A1[a], B1[nt], sc[a][nt], 0, 0, 0);
        __builtin_amdgcn_s_setprio(0);
    }
    #pragma unroll
    for (int a = 0; a < 4; ++a) {
        int ocb = m0 + a * 16 + g * 4;
        float b0 = bout[ocb], b1 = bout[ocb + 1], b2 = bout[ocb + 2], b3 = bout[ocb + 3];
        float* op = outp + ((size_t)b * DIM + ocb) * HW + n0 + w * 64 + c;
        #pragma unroll
        for (int nt = 0; nt < 4; ++nt) {
            op[(size_t)0 * HW + nt * 16] = sc[a][nt][0] + b0;
            op[(size_t)1 * HW + nt * 16] = sc[a][nt][1] + b1;
            op[(size_t)2 * HW + nt * 16] = sc[a][nt][2] + b2;
            op[(size_t)3 * HW + nt * 16] = sc[a][nt][3] + b3;
        }
    }
}

extern "C" void kernel_launch(void* const* d_in, const int* in_sizes, int n_in,
                              void* d_out, int out_size, void* d_ws, size_t ws_size,
                              hipStream_t stream) {
    (void)in_sizes; (void)n_in; (void)out_size; (void)ws_size;
    const float* x = (const float*)d_in[0];
    const float* Wq = (const float*)d_in[1];
    const float* Wkv = (const float*)d_in[2];
    const float* Wout = (const float*)d_in[3];
    const float* bout = (const float*)d_in[4];
    float* outp = (float*)d_out;

    // Workspace layout (f32 units, total 47,448,064 = 189.8 MB; 209.7 MB known-safe):
    //   partial f32 [0, 14,680,064)                   (56 slices, dead after k2r)
    //   ktok   f16  [14,680,064, 14,942,208)
    //   vtokT  f16  [14,942,208, 15,204,352)          (column-permuted for k3)
    //   Wq16s  f16  [15,204,352, 15,269,888)          (frag-ready, QSCALE folded)
    //   Wout16 f16  [15,269,888, 15,335,424)          (frag-ready)
    //   Wkv16  f16  [15,335,424, 21,757,952)          (frag-ready, dead after k2)
    //   Pt     f16  [21,757,952, 28,180,480)          (frag-ready, dead after k2)
    //   otok16 f16  [15,335,424, 28,180,480)          (frag-ready, overlays Wkv16+Pt)
    //   xT16   f16  [28,180,480, 34,603,008)          (frag-ready, dead after k1)
    //   qtok   f16  [34,603,008, 47,448,064)
    float* ws = (float*)d_ws;
    float*  partial = ws;
    half_t* ktok    = (half_t*)(ws + 14680064);
    half_t* vtokT   = (half_t*)(ws + 14942208);
    half_t* Wq16s   = (half_t*)(ws + 15204352);
    half_t* Wout16  = (half_t*)(ws + 15269888);
    half_t* Wkv16   = (half_t*)(ws + 15335424);
    half_t* Pt      = (half_t*)(ws + 21757952);
    half_t* otok16  = (half_t*)(ws + 15335424);
    half_t* xT16    = (half_t*)(ws + 28180480);
    half_t* qtok    = (half_t*)(ws + 34603008);

    hipFuncSetAttribute((const void*)k3_attn,
                        hipFuncAttributeMaxDynamicSharedMemorySize, 65536);

    k_cvt<<<dim3(6272), 256, 0, stream>>>(Wkv, Wkv16, 1.0f, 1024, KCONV);
    k_cvt<<<dim3(64), 256, 0, stream>>>(Wq, Wq16s, QSCALE, 512, DIM);
    k_cvt<<<dim3(64), 256, 0, stream>>>(Wout, Wout16, 1.0f, 256, INNER);
    kx_t<<<dim3(196, 4, 4), 256, 0, stream>>>(x, xT16);
    k0_gather<<<dim3(6272), 256, 0, stream>>>(x, Pt);
    k2_kv<<<dim3(896), 256, 0, stream>>>(Wkv16, Pt, partial);
    k2r<<<dim3(128, 4), 256, 0, stream>>>(partial, ktok, vtokT);
    k1_qproj<<<dim3(1568), 256, 0, stream>>>(Wq16s, xT16, qtok);
    k3_attn<<<dim3(98, 32), 512, 65536, stream>>>(qtok, ktok, vtokT, otok16);
    k4_outproj<<<dim3(784), 256, 0, stream>>>(Wout16, otok16, bout, outp);
}